// Round 8
// baseline (708.871 us; speedup 1.0000x reference)
//
#include <hip/hip_runtime.h>
#include <math.h>

#define B    4
#define T    16384
#define A    256
#define K    256
#define PAD  128
#define TP   (T + 2*PAD)      // 16640
#define TOUT (TP - K + 1)     // 16385
#define ITERS 16
#define CHUNK 512
#define NCHUNK 33
#define NCP  36               // (fallback) padded per-atom chunk stride
#define TILE 2048
#define NTILE 9
#define NBLK 512              // grid (both paths)
#define BPB2 128              // blocks per batch (coop path)
#define HBASE 8192            // half split point (outputs & rp base)
#define RPSTORE 8448          // stored rp floats per block (8192 + 256 overlap)
#define RPN 8704              // LDS rp floats incl. zero pad for masked over-reads
#define BARSTRIDE 64
#define DLDS 40960            // dynamic LDS request -> 2 blocks/CU (80KB/CU)

#define TAP(acc, s0,s1,s2,s3, dq) { acc = fmaf(s0,(dq).x,acc); acc = fmaf(s1,(dq).y,acc); \
                                    acc = fmaf(s2,(dq).z,acc); acc = fmaf(s3,(dq).w,acc); }

__device__ __forceinline__ void wave_amax(float& bv, int& bi) {
    #pragma unroll
    for (int off = 32; off; off >>= 1) {
        float ov = __shfl_down(bv, off);
        int   oi = __shfl_down(bi, off);
        if (ov > bv || (ov == bv && oi < bi)) { bv = ov; bi = oi; }
    }
}

// ===================== LDS-resident HALVES path =====================
// Block (b, h, g): rp[h*8192 .. h*8192+8448) resident in LDS + 4 atoms' taps.
// 512 blocks -> 2 blocks/CU -> 2 waves/SIMD (R7's 1-wave/SIMD latency exposure
// was the regression; traffic stays R7-minimal). out = x - rp_final.
struct KSmem {
    float  rp[RPN];           // 34816 B ([8448..8704) zero pad, never written)
    float4 dn4[4][64];        // own 4 atoms' taps, 4096 B
    float  chv[4][34];        // per-atom chunk maxima (global chunk ids)
    int    chi[4][34];
    float  wv[16]; int wi[16];
    float  fv; int fi;
};

// Per-batch barrier (128 arrivals). Barrier flavor was bare-time-invariant
// across R4/R5/R6 -> simplest form.
__device__ __forceinline__ void gbar(unsigned* c, unsigned target, int tid) {
    __syncthreads();
    if (tid == 0) {
        __hip_atomic_fetch_add(c, 1u, __ATOMIC_RELEASE, __HIP_MEMORY_SCOPE_AGENT);
        while (__hip_atomic_load(c, __ATOMIC_RELAXED, __HIP_MEMORY_SCOPE_AGENT) < target)
            __builtin_amdgcn_s_sleep(2);
    }
    __syncthreads();
    __builtin_amdgcn_fence(__ATOMIC_ACQUIRE, "agent");
}

// Compute conv outputs for up to two 512-chunks (cA -> threads 0..127,
// cB -> threads 128..255; -1 = inactive) for the block's 4 atoms, from LDS rp.
// REPLACES chv/chi entries for the valid chunks. Chunk ids are GLOBAL (0..32).
__device__ void chunks_update(KSmem& sm, int baseF, int cA, int cB, int aBase, int tid) {
    const int lane = tid & 63, w = tid >> 6;
    const int grp = tid >> 7;
    const int cg = grp ? cB : cA;
    const int lt = cg*512 + (tid & 127)*4;    // global output t (j=0); cg>=0 only
    float c0[4] = {0,0,0,0}, c1[4] = {0,0,0,0}, c2[4] = {0,0,0,0}, c3[4] = {0,0,0,0};
    if (cg >= 0) {
        const float4* srp4 = (const float4*)sm.rp;
        int ol4 = (lt - baseF) >> 2;
        float4 p = srp4[ol4];
        #pragma unroll 4
        for (int kq = 0; kq < 64; kq++) {
            float4 d0 = sm.dn4[0][kq];
            float4 d1 = sm.dn4[1][kq];
            float4 d2 = sm.dn4[2][kq];
            float4 d3 = sm.dn4[3][kq];
            float4 pn = srp4[ol4 + kq + 1];
            TAP(c0[0], p.x,p.y,p.z,p.w, d0); TAP(c0[1], p.y,p.z,p.w,pn.x, d0);
            TAP(c0[2], p.z,p.w,pn.x,pn.y, d0); TAP(c0[3], p.w,pn.x,pn.y,pn.z, d0);
            TAP(c1[0], p.x,p.y,p.z,p.w, d1); TAP(c1[1], p.y,p.z,p.w,pn.x, d1);
            TAP(c1[2], p.z,p.w,pn.x,pn.y, d1); TAP(c1[3], p.w,pn.x,pn.y,pn.z, d1);
            TAP(c2[0], p.x,p.y,p.z,p.w, d2); TAP(c2[1], p.y,p.z,p.w,pn.x, d2);
            TAP(c2[2], p.z,p.w,pn.x,pn.y, d2); TAP(c2[3], p.w,pn.x,pn.y,pn.z, d2);
            TAP(c3[0], p.x,p.y,p.z,p.w, d3); TAP(c3[1], p.y,p.z,p.w,pn.x, d3);
            TAP(c3[2], p.z,p.w,pn.x,pn.y, d3); TAP(c3[3], p.w,pn.x,pn.y,pn.z, d3);
            p = pn;
        }
    }
    float bv0 = -INFINITY, bv1 = -INFINITY, bv2 = -INFINITY, bv3 = -INFINITY;
    int bi0 = 0x7fffffff, bi1 = 0x7fffffff, bi2 = 0x7fffffff, bi3 = 0x7fffffff;
    if (cg >= 0) {
        #pragma unroll
        for (int j = 0; j < 4; j++) {
            int t = lt + j;
            if (t < TOUT) {
                if (c0[j] > bv0) { bv0 = c0[j]; bi0 = (aBase+0)*TOUT + t; }
                if (c1[j] > bv1) { bv1 = c1[j]; bi1 = (aBase+1)*TOUT + t; }
                if (c2[j] > bv2) { bv2 = c2[j]; bi2 = (aBase+2)*TOUT + t; }
                if (c3[j] > bv3) { bv3 = c3[j]; bi3 = (aBase+3)*TOUT + t; }
            }
        }
    }
    wave_amax(bv0, bi0); wave_amax(bv1, bi1); wave_amax(bv2, bi2); wave_amax(bv3, bi3);
    if (lane == 0) {
        sm.wv[0*4+w] = bv0; sm.wi[0*4+w] = bi0;
        sm.wv[1*4+w] = bv1; sm.wi[1*4+w] = bi1;
        sm.wv[2*4+w] = bv2; sm.wi[2*4+w] = bi2;
        sm.wv[3*4+w] = bv3; sm.wi[3*4+w] = bi3;
    }
    __syncthreads();
    // combine wave pairs: waves {0,1} -> cA, {2,3} -> cB
    if (tid < 8) {
        int a = tid >> 1, hh = tid & 1;
        int chunk = hh ? cB : cA;
        if (chunk >= 0) {
            float v0 = sm.wv[a*4 + 2*hh];   int i0 = sm.wi[a*4 + 2*hh];
            float v1 = sm.wv[a*4 + 2*hh+1]; int i1 = sm.wi[a*4 + 2*hh+1];
            if (v1 > v0 || (v1 == v0 && i1 < i0)) { v0 = v1; i0 = i1; }
            sm.chv[a][chunk] = v0; sm.chi[a][chunk] = i0;
        }
    }
    __syncthreads();
}

// Per-atom best over the block's chunk range -> exchange slot [b][h][atom].
__device__ __forceinline__ void best_write(KSmem& sm, int a0, int b, int h, int tid,
                                           float* __restrict__ abv, int* __restrict__ abi) {
    const int lane = tid & 63, w = tid >> 6;  // wave w -> atom w
    int cstart = h ? 16 : 0, nch = h ? 17 : 16;
    float bv = -INFINITY; int bi = 0x7fffffff;
    if (lane < nch) { bv = sm.chv[w][cstart + lane]; bi = sm.chi[w][cstart + lane]; }
    wave_amax(bv, bi);
    if (lane == 0) {
        int s = b*2*A + h*A + a0*4 + w;
        abv[s] = bv; abi[s] = bi;
    }
}

// Batch-wide argmax over 2*A exchange entries (2 halves per atom).
__device__ __forceinline__ void pick(KSmem& sm, int b, int tid,
                                     const float* __restrict__ avc, const int* __restrict__ aic) {
    const int lane = tid & 63, w = tid >> 6;
    int s0 = b*2*A + tid;
    float v0 = avc[s0];     int i0 = aic[s0];
    float v1 = avc[s0 + A]; int i1 = aic[s0 + A];
    if (v1 > v0 || (v1 == v0 && i1 < i0)) { v0 = v1; i0 = i1; }
    wave_amax(v0, i0);
    if (lane == 0) { sm.wv[w] = v0; sm.wi[w] = i0; }
    __syncthreads();
    if (tid == 0) {
        float bv = sm.wv[0]; int bi = sm.wi[0];
        for (int j = 1; j < 4; j++)
            if (sm.wv[j] > bv || (sm.wv[j] == bv && sm.wi[j] < bi)) { bv = sm.wv[j]; bi = sm.wi[j]; }
        sm.fv = bv; sm.fi = bi;
    }
    __syncthreads();
}

__global__ void __launch_bounds__(256, 2)
k_coop(const float* __restrict__ x, const float* __restrict__ d, float* __restrict__ out,
       float* __restrict__ dn,
       float* __restrict__ abv0, int* __restrict__ abi0,
       float* __restrict__ abv1, int* __restrict__ abi1, unsigned* __restrict__ bar) {
    extern __shared__ char raw[];
    KSmem& sm = *(KSmem*)raw;
    const int bid = blockIdx.x, tid = threadIdx.x;
    const int b = bid >> 7, r = bid & 127;
    const int h = r >> 6, a0 = r & 63;       // half, atom-group (4 atoms)
    const int lane = tid & 63, w = tid >> 6;
    const int baseF = h * HBASE;
    const int cstart = h ? 16 : 0, cend = h ? 33 : 16;
    unsigned* cb = bar + b*BARSTRIDE;

    // ---- init: x -> LDS rp window (padded domain), zero tail ----
    {
        const float4* x4 = (const float4*)(x + (size_t)b*T);
        float4* rp4w = (float4*)sm.rp;
        int b4 = baseF >> 2;
        for (int i = tid; i < RPN/4; i += 256) {
            int g4 = b4 + i;
            float4 v = {0.f,0.f,0.f,0.f};
            if (i < RPSTORE/4 && g4 >= PAD/4 && g4 < (PAD+T)/4) v = x4[g4 - PAD/4];
            rp4w[i] = v;
        }
    }
    // ---- normalize own 4 atoms into LDS + global dn (redundant identical writes) ----
    #pragma unroll
    for (int s = 0; s < 4; s++) {
        int atom = a0*4 + s;
        float v = d[atom*K + tid];
        float sq = v*v;
        #pragma unroll
        for (int off = 32; off; off >>= 1) sq += __shfl_down(sq, off);
        if (lane == 0) sm.wv[w] = sq;
        __syncthreads();
        float norm = sqrtf(sm.wv[0] + sm.wv[1] + sm.wv[2] + sm.wv[3]) + 1e-12f;
        float nv = v / norm;
        ((float*)&sm.dn4[s][0])[tid] = nv;
        dn[atom*K + tid] = nv;
        __syncthreads();
    }
    // ---- initial conv over own half (8 or 9 chunk-pair passes) ----
    {
        int npass = h ? 9 : 8;
        for (int p = 0; p < npass; p++) {
            int ca = cstart + 2*p;
            int cb2 = (ca + 1 < cend) ? ca + 1 : -1;
            chunks_update(sm, baseF, ca, cb2, a0*4, tid);
        }
    }
    best_write(sm, a0, b, h, tid, abv0, abi0);
    unsigned gen = 1; gbar(cb, gen*BPB2, tid);

    const float* avc = abv0; const int* aic = abi0;
    float* avn = abv1; int* ain = abi1;
    for (int it = 0; it < ITERS-1; it++) {
        pick(sm, b, tid, avc, aic);
        float val = sm.fv; int idx = sm.fi;
        int atom = idx / TOUT, pos = idx - atom*TOUT;
        float ds = dn[atom*K + tid];            // winning atom taps (hot L2)
        int li = pos + tid - baseF;             // local residual update (if in range)
        if (li >= 0 && li < RPSTORE) sm.rp[li] -= val * ds;
        __syncthreads();
        int lo = pos - (K-1); if (lo < 0) lo = 0;
        int g0 = lo >> 9, g1 = g0 + 1;          // the 2 affected global chunks
        bool in0 = (g0 >= cstart && g0 < cend);
        bool in1 = (g1 >= cstart && g1 < cend);
        int ca = in0 ? g0 : (in1 ? g1 : -1);
        int cb2 = (in0 && in1) ? g1 : -1;
        if (ca >= 0) chunks_update(sm, baseF, ca, cb2, a0*4, tid);
        best_write(sm, a0, b, h, tid, avn, ain);  // chv always current -> always refresh
        { const float* t1 = avc; avc = avn; avn = (float*)t1; }
        { const int*   t2 = aic; aic = ain; ain = (int*)t2; }
        gen++; gbar(cb, gen*BPB2, tid);
    }
    // ---- final pick + update + out (one writer block per (batch, half)) ----
    if (a0 == 0) {
        pick(sm, b, tid, avc, aic);
        float val = sm.fv; int idx = sm.fi;
        int atom = idx / TOUT, pos = idx - atom*TOUT;
        float ds = dn[atom*K + tid];
        int li = pos + tid - baseF;
        if (li >= 0 && li < RPSTORE) sm.rp[li] -= val * ds;
        __syncthreads();
        // out[b][o] = x[b][o] - rp[o+PAD]; h=0 covers o in [0,8064), h=1 [8064,16384)
        int o_lo4 = h ? (HBASE - PAD)/4 : 0;
        int o_hi4 = h ? T/4 : (HBASE - PAD)/4;
        const float4* xb4 = (const float4*)(x + (size_t)b*T);
        float4* o4 = (float4*)(out + (size_t)b*T);
        for (int i4 = o_lo4 + tid; i4 < o_hi4; i4 += 256) {
            float4 xv = xb4[i4];
            float4 rv = *(const float4*)&sm.rp[i4*4 + PAD - baseF];
            float4 ov; ov.x = xv.x - rv.x; ov.y = xv.y - rv.y;
            ov.z = xv.z - rv.z; ov.w = xv.w - rv.w;
            o4[i4] = ov;
        }
    }
}

// ===================== fallback path (R6, race-free, unchanged) =====================
struct Smem {
    float rp[TILE + K + 16];
    float dnA[K];
    float dnB[K];
    float dnsel[K];
    float wv[16]; int wi[16];
    float fv; int fi;
};

__device__ __forceinline__ void dev_norm(int a0, int tid, const float* __restrict__ d,
                                         float* __restrict__ dn, Smem& sm) {
    int lane = tid & 63, w = tid >> 6;
    #pragma unroll
    for (int s = 0; s < 2; s++) {
        int atom = a0*2 + s;
        float v = d[atom*K + tid];
        float sq = v*v;
        #pragma unroll
        for (int off = 32; off; off >>= 1) sq += __shfl_down(sq, off);
        if (lane == 0) sm.wv[w] = sq;
        __syncthreads();
        float norm = sqrtf(sm.wv[0] + sm.wv[1] + sm.wv[2] + sm.wv[3]) + 1e-12f;
        dn[atom*K + tid] = v / norm;
        __syncthreads();
    }
}

__device__ __forceinline__ void dev_init(int a0, int b, int tid, const float* __restrict__ x,
                                         float* __restrict__ rp, float* __restrict__ recon) {
    int i = a0*256 + tid;
    if (i < TP) {
        float v = (i >= PAD && i < PAD + T) ? x[b*T + (i - PAD)] : 0.f;
        rp[(size_t)b*TP + i] = v;
        recon[(size_t)b*TP + i] = 0.f;
    }
}

__device__ void dev_conv(int a0, int b, int tid, const float* __restrict__ rp,
                         const float* __restrict__ dn,
                         float* __restrict__ segval, int* __restrict__ segidx,
                         float* __restrict__ abv, int* __restrict__ abi, Smem& sm) {
    const int aA = a0*2, aB = a0*2 + 1;
    const int lane = tid & 63, w = tid >> 6;
    sm.dnA[tid] = dn[aA*K + tid];
    sm.dnB[tid] = dn[aB*K + tid];
    const float4* rp4 = (const float4*)(rp + (size_t)b*TP);

    for (int tile = 0; tile < NTILE; tile++) {
        int t0 = tile * TILE;
        __syncthreads();
        float4* s4 = (float4*)sm.rp;
        for (int i = tid; i < 580; i += 256) {
            int g = t0/4 + i;
            float4 v = {0.f,0.f,0.f,0.f};
            if (g*4 < TP) v = rp4[g];
            s4[i] = v;
        }
        __syncthreads();
        const float4* srp4 = (const float4*)sm.rp;
        const float4* dA4  = (const float4*)sm.dnA;
        const float4* dB4  = (const float4*)sm.dnB;
        float accA0[4] = {0,0,0,0}, accA1[4] = {0,0,0,0};
        float accB0[4] = {0,0,0,0}, accB1[4] = {0,0,0,0};
        float4 p = srp4[tid];
        float4 q = srp4[tid + 256];
        #pragma unroll 4
        for (int kq = 0; kq < 64; kq++) {
            float4 dA = dA4[kq];
            float4 dB = dB4[kq];
            float4 pn = srp4[tid + kq + 1];
            float4 qn = srp4[tid + 256 + kq + 1];
            TAP(accA0[0], p.x,p.y,p.z,p.w, dA); TAP(accA0[1], p.y,p.z,p.w,pn.x, dA);
            TAP(accA0[2], p.z,p.w,pn.x,pn.y, dA); TAP(accA0[3], p.w,pn.x,pn.y,pn.z, dA);
            TAP(accB0[0], p.x,p.y,p.z,p.w, dB); TAP(accB0[1], p.y,p.z,p.w,pn.x, dB);
            TAP(accB0[2], p.z,p.w,pn.x,pn.y, dB); TAP(accB0[3], p.w,pn.x,pn.y,pn.z, dB);
            TAP(accA1[0], q.x,q.y,q.z,q.w, dA); TAP(accA1[1], q.y,q.z,q.w,qn.x, dA);
            TAP(accA1[2], q.z,q.w,qn.x,qn.y, dA); TAP(accA1[3], q.w,qn.x,qn.y,qn.z, dA);
            TAP(accB1[0], q.x,q.y,q.z,q.w, dB); TAP(accB1[1], q.y,q.z,q.w,qn.x, dB);
            TAP(accB1[2], q.z,q.w,qn.x,qn.y, dB); TAP(accB1[3], q.w,qn.x,qn.y,qn.z, dB);
            p = pn; q = qn;
        }
        int lt = tid * 4;
        float bvA0 = -INFINITY, bvA1 = -INFINITY, bvB0 = -INFINITY, bvB1 = -INFINITY;
        int biA0 = 0x7fffffff, biA1 = 0x7fffffff, biB0 = 0x7fffffff, biB1 = 0x7fffffff;
        #pragma unroll
        for (int j = 0; j < 4; j++) {
            int t = t0 + lt + j;
            if (t < TOUT) {
                if (accA0[j] > bvA0) { bvA0 = accA0[j]; biA0 = aA*TOUT + t; }
                if (accB0[j] > bvB0) { bvB0 = accB0[j]; biB0 = aB*TOUT + t; }
            }
            int t1 = t0 + 1024 + lt + j;
            if (t1 < TOUT) {
                if (accA1[j] > bvA1) { bvA1 = accA1[j]; biA1 = aA*TOUT + t1; }
                if (accB1[j] > bvB1) { bvB1 = accB1[j]; biB1 = aB*TOUT + t1; }
            }
        }
        wave_amax(bvA0, biA0); wave_amax(bvA1, biA1);
        wave_amax(bvB0, biB0); wave_amax(bvB1, biB1);
        if (lane == 0) {
            sm.wv[w]    = bvA0; sm.wi[w]    = biA0;
            sm.wv[4+w]  = bvA1; sm.wi[4+w]  = biA1;
            sm.wv[8+w]  = bvB0; sm.wi[8+w]  = biB0;
            sm.wv[12+w] = bvB1; sm.wi[12+w] = biB1;
        }
        __syncthreads();
        if (tid < 4) {
            float v0 = sm.wv[2*tid];   int i0 = sm.wi[2*tid];
            float v1 = sm.wv[2*tid+1]; int i1 = sm.wi[2*tid+1];
            if (v1 > v0 || (v1 == v0 && i1 < i0)) { v0 = v1; i0 = i1; }
            int chunk = tile*4 + tid;
            if (chunk < NCHUNK) {
                segval[((size_t)b*A + aA)*NCP + chunk] = v0;
                segidx[((size_t)b*A + aA)*NCP + chunk] = i0;
            }
        } else if (tid >= 64 && tid < 68) {
            int c = tid - 64;
            float v0 = sm.wv[8+2*c];   int i0 = sm.wi[8+2*c];
            float v1 = sm.wv[8+2*c+1]; int i1 = sm.wi[8+2*c+1];
            if (v1 > v0 || (v1 == v0 && i1 < i0)) { v0 = v1; i0 = i1; }
            int chunk = tile*4 + c;
            if (chunk < NCHUNK) {
                segval[((size_t)b*A + aB)*NCP + chunk] = v0;
                segidx[((size_t)b*A + aB)*NCP + chunk] = i0;
            }
        }
    }
    __syncthreads();
    if (w < 2) {
        int atom = (w == 0) ? aA : aB;
        float bv = -INFINITY; int bi = 0x7fffffff;
        if (lane < NCHUNK) {
            bv = segval[((size_t)b*A + atom)*NCP + lane];
            bi = segidx[((size_t)b*A + atom)*NCP + lane];
        }
        wave_amax(bv, bi);
        if (lane == 0) { abv[b*A + atom] = bv; abi[b*A + atom] = bi; }
    }
}

__device__ void dev_iter(int a0, int b, int tid, int last,
                         const float* __restrict__ avc, const int* __restrict__ aic,
                         float* __restrict__ avn, int* __restrict__ ain,
                         const float* __restrict__ rin, float* __restrict__ rout,
                         float* __restrict__ recon, const float* __restrict__ dn,
                         float* __restrict__ segval, int* __restrict__ segidx, Smem& sm) {
    const int aA = a0*2, aB = a0*2 + 1;
    const int lane = tid & 63, w = tid >> 6;

    float bv0 = avc[b*A + tid]; int bi0 = aic[b*A + tid];
    const float4* rin4 = (const float4*)(rin + (size_t)b*TP);
    const int icopy = a0*256 + tid;
    const bool docopy = (!last) && (icopy < TP/4);
    float4 vcopy = {0.f,0.f,0.f,0.f};
    if (docopy) vcopy = rin4[icopy];
    sm.dnA[tid] = dn[aA*K + tid];
    sm.dnB[tid] = dn[aB*K + tid];

    {
        float bv = bv0; int bi = bi0;
        wave_amax(bv, bi);
        if (lane == 0) { sm.wv[w] = bv; sm.wi[w] = bi; }
        __syncthreads();
        if (tid == 0) {
            bv = sm.wv[0]; bi = sm.wi[0];
            for (int j = 1; j < 4; j++)
                if (sm.wv[j] > bv || (sm.wv[j] == bv && sm.wi[j] < bi)) { bv = sm.wv[j]; bi = sm.wi[j]; }
            sm.fv = bv; sm.fi = bi;
        }
        __syncthreads();
    }
    float val = sm.fv; int idx = sm.fi;
    int atom = idx / TOUT, pos = idx - atom*TOUT;
    sm.dnsel[tid] = dn[atom*K + tid];

    int lo = pos - (K-1); if (lo < 0) lo = 0;
    int c_lo = lo >> 9;
    int tbase = c_lo * CHUNK;

    if (!last) {
        float4* s4 = (float4*)sm.rp;
        for (int i = tid; i < 324; i += 256) {
            int g = tbase/4 + i;
            float4 v = {0.f,0.f,0.f,0.f};
            if (g*4 < TP) v = rin4[g];
            s4[i] = v;
        }
    }
    __syncthreads();
    if (docopy) {
        float4* rout4 = (float4*)(rout + (size_t)b*TP);
        float4 v = vcopy;
        int o = icopy*4 - pos;
        if (o > -4 && o < K) {
            if (o+0 >= 0 && o+0 < K) v.x -= val * sm.dnsel[o+0];
            if (o+1 >= 0 && o+1 < K) v.y -= val * sm.dnsel[o+1];
            if (o+2 >= 0 && o+2 < K) v.z -= val * sm.dnsel[o+2];
            if (o+3 >= 0 && o+3 < K) v.w -= val * sm.dnsel[o+3];
        }
        rout4[icopy] = v;
    }
    if (a0 == 0) {
        recon[(size_t)b*TP + pos + tid] += val * sm.dnsel[tid];
    }
    if (last) return;

    sm.rp[pos + tid - tbase] -= val * sm.dnsel[tid];
    __syncthreads();

    const float4* srp4 = (const float4*)sm.rp;
    const float4* dA4  = (const float4*)sm.dnA;
    const float4* dB4  = (const float4*)sm.dnB;
    float cA[4] = {0,0,0,0}, cB[4] = {0,0,0,0};
    float4 p = srp4[tid];
    #pragma unroll 4
    for (int kq = 0; kq < 64; kq++) {
        float4 dA = dA4[kq];
        float4 dB = dB4[kq];
        float4 pn = srp4[tid + kq + 1];
        TAP(cA[0], p.x,p.y,p.z,p.w, dA); TAP(cA[1], p.y,p.z,p.w,pn.x, dA);
        TAP(cA[2], p.z,p.w,pn.x,pn.y, dA); TAP(cA[3], p.w,pn.x,pn.y,pn.z, dA);
        TAP(cB[0], p.x,p.y,p.z,p.w, dB); TAP(cB[1], p.y,p.z,p.w,pn.x, dB);
        TAP(cB[2], p.z,p.w,pn.x,pn.y, dB); TAP(cB[3], p.w,pn.x,pn.y,pn.z, dB);
        p = pn;
    }
    int lt = tid * 4;
    float bvA = -INFINITY, bvB = -INFINITY;
    int biA = 0x7fffffff, biB = 0x7fffffff;
    #pragma unroll
    for (int j = 0; j < 4; j++) {
        int t = tbase + lt + j;
        if (t < TOUT) {
            if (cA[j] > bvA) { bvA = cA[j]; biA = aA*TOUT + t; }
            if (cB[j] > bvB) { bvB = cB[j]; biB = aB*TOUT + t; }
        }
    }
    wave_amax(bvA, biA); wave_amax(bvB, biB);
    if (lane == 0) { sm.wv[w] = bvA; sm.wi[w] = biA; sm.wv[8+w] = bvB; sm.wi[8+w] = biB; }
    __syncthreads();
    if (tid < 2) {
        float v0 = sm.wv[2*tid];   int i0 = sm.wi[2*tid];
        float v1 = sm.wv[2*tid+1]; int i1 = sm.wi[2*tid+1];
        if (v1 > v0 || (v1 == v0 && i1 < i0)) { v0 = v1; i0 = i1; }
        int chunk = c_lo + tid;
        if (chunk < NCHUNK) {
            segval[((size_t)b*A + aA)*NCP + chunk] = v0;
            segidx[((size_t)b*A + aA)*NCP + chunk] = i0;
        }
    } else if (tid >= 64 && tid < 66) {
        int c = tid - 64;
        float v0 = sm.wv[8+2*c];   int i0 = sm.wi[8+2*c];
        float v1 = sm.wv[8+2*c+1]; int i1 = sm.wi[8+2*c+1];
        if (v1 > v0 || (v1 == v0 && i1 < i0)) { v0 = v1; i0 = i1; }
        int chunk = c_lo + c;
        if (chunk < NCHUNK) {
            segval[((size_t)b*A + aB)*NCP + chunk] = v0;
            segidx[((size_t)b*A + aB)*NCP + chunk] = i0;
        }
    }
    __syncthreads();
    if (w < 2) {
        int at = (w == 0) ? aA : aB;
        float bv = -INFINITY; int bi = 0x7fffffff;
        if (lane < NCHUNK) {
            bv = segval[((size_t)b*A + at)*NCP + lane];
            bi = segidx[((size_t)b*A + at)*NCP + lane];
        }
        wave_amax(bv, bi);
        if (lane == 0) { avn[b*A + at] = bv; ain[b*A + at] = bi; }
    }
}

__global__ void __launch_bounds__(256) k_f_norm_init(const float* x, const float* d,
                                                     float* dn, float* rp0, float* recon) {
    __shared__ Smem sm;
    dev_norm(blockIdx.x & 127, threadIdx.x, d, dn, sm);
    dev_init(blockIdx.x & 127, blockIdx.x >> 7, threadIdx.x, x, rp0, recon);
}
__global__ void __launch_bounds__(256, 2) k_f_conv(const float* rp, const float* dn,
                                                   float* segval, int* segidx,
                                                   float* abv, int* abi) {
    __shared__ Smem sm;
    dev_conv(blockIdx.x & 127, blockIdx.x >> 7, threadIdx.x, rp, dn, segval, segidx, abv, abi, sm);
}
__global__ void __launch_bounds__(256, 2) k_f_iter(int last,
                                                   const float* avc, const int* aic,
                                                   float* avn, int* ain,
                                                   const float* rin, float* rout,
                                                   float* recon, const float* dn,
                                                   float* segval, int* segidx) {
    __shared__ Smem sm;
    dev_iter(blockIdx.x & 127, blockIdx.x >> 7, threadIdx.x, last,
             avc, aic, avn, ain, rin, rout, recon, dn, segval, segidx, sm);
}
__global__ void k_f_out(const float* recon, float* out) {
    int i = blockIdx.x * blockDim.x + threadIdx.x;
    if (i >= B*T) return;
    int b = i / T, t = i - b*T;
    out[i] = recon[(size_t)b*TP + PAD + t];
}

extern "C" void kernel_launch(void* const* d_in, const int* in_sizes, int n_in,
                              void* d_out, int out_size, void* d_ws, size_t ws_size,
                              hipStream_t stream) {
    const float* x = (const float*)d_in[0];
    const float* d = (const float*)d_in[1];
    float* out = (float*)d_out;

    float* ws     = (float*)d_ws;
    float* dn     = ws;                                   // A*K
    float* rp0    = dn  + (size_t)A*K;                    // B*TP (fallback)
    float* rp1    = rp0 + (size_t)B*TP;                   // B*TP (fallback)
    float* recon  = rp1 + (size_t)B*TP;                   // B*TP (fallback)
    float* segval = recon + (size_t)B*TP;                 // B*A*NCP (fallback)
    int*   segidx = (int*)(segval + (size_t)B*A*NCP);     // B*A*NCP (fallback)
    float* abv0   = (float*)(segidx + (size_t)B*A*NCP);   // B*2*A
    float* abv1   = abv0 + (size_t)B*2*A;                 // B*2*A
    int*   abi0   = (int*)(abv1 + (size_t)B*2*A);         // B*2*A
    int*   abi1   = abi0 + (size_t)B*2*A;                 // B*2*A
    unsigned* bar = (unsigned*)(abi1 + (size_t)B*2*A);    // per-batch counters

    // Coop-path feasibility: 512 co-resident blocks at DLDS dynamic LDS
    // (2 blocks/CU). Host queries only.
    (void)hipFuncSetAttribute((const void*)k_coop,
                              hipFuncAttributeMaxDynamicSharedMemorySize, DLDS);
    int nb = 0, ncu = 0;
    hipError_t e1 = hipOccupancyMaxActiveBlocksPerMultiprocessor(&nb, (const void*)k_coop,
                                                                 256, DLDS);
    hipError_t e2 = hipDeviceGetAttribute(&ncu, hipDeviceAttributeMultiprocessorCount, 0);
    bool coop = (e1 == hipSuccess && e2 == hipSuccess && nb > 0 && ncu > 0 &&
                 (long)nb * ncu >= NBLK);
    if (coop) {
        (void)hipMemsetAsync(bar, 0, B*BARSTRIDE*sizeof(unsigned), stream);
        hipLaunchKernelGGL(k_coop, dim3(NBLK), dim3(256), DLDS, stream,
                           x, d, out, dn, abv0, abi0, abv1, abi1, bar);
        return;
    }
    // fallback: separate launches, double-buffered (race-free)
    k_f_norm_init<<<NBLK, 256, 0, stream>>>(x, d, dn, rp0, recon);
    k_f_conv<<<NBLK, 256, 0, stream>>>(rp0, dn, segval, segidx, abv0, abi0);
    float* rbuf[2] = {rp0, rp1};
    float* av[2]   = {abv0, abv1};
    int*   ai[2]   = {abi0, abi1};
    for (int it = 0; it < ITERS; it++) {
        k_f_iter<<<NBLK, 256, 0, stream>>>(it == ITERS-1 ? 1 : 0,
                                           av[it & 1], ai[it & 1],
                                           av[(it + 1) & 1], ai[(it + 1) & 1],
                                           rbuf[it & 1], rbuf[(it + 1) & 1],
                                           recon, dn, segval, segidx);
    }
    k_f_out<<<(B*T + 255)/256, 256, 0, stream>>>(recon, out);
}

// Round 9
// 540.942 us; speedup vs baseline: 1.3104x; 1.3104x over previous
//
#include <hip/hip_runtime.h>
#include <math.h>

#define B    4
#define T    16384
#define A    256
#define K    256
#define PAD  128
#define TP   (T + 2*PAD)      // 16640
#define TOUT (TP - K + 1)     // 16385
#define ITERS 16
#define CHUNK 512
#define NCHUNK 33
#define NCP  36               // (fallback) padded per-atom chunk stride
#define TILE 2048
#define NTILE 9
#define NBLK 512              // grid (both paths)
#define BPB2 128              // blocks per batch (coop path)
#define HBASE 8192            // half split point (outputs & rp base)
#define RPSTORE 8448          // stored rp floats per block (8192 + 256 overlap)
#define RPN 8704              // LDS rp floats incl. zero pad for masked over-reads
#define BARSTRIDE 64
#define DLDS 40960            // dynamic LDS request -> 2 blocks/CU (80KB/CU)

#define TAP(acc, s0,s1,s2,s3, dq) { acc = fmaf(s0,(dq).x,acc); acc = fmaf(s1,(dq).y,acc); \
                                    acc = fmaf(s2,(dq).z,acc); acc = fmaf(s3,(dq).w,acc); }

__device__ __forceinline__ void wave_amax(float& bv, int& bi) {
    #pragma unroll
    for (int off = 32; off; off >>= 1) {
        float ov = __shfl_down(bv, off);
        int   oi = __shfl_down(bi, off);
        if (ov > bv || (ov == bv && oi < bi)) { bv = ov; bi = oi; }
    }
}

// ===================== LDS-resident HALVES path (fence-free iterations) =====================
// R4-R8 lesson: bare time was invariant to barrier arrival mechanics (R4/5/6)
// and to occupancy (R7/8). Shared cost: agent release/acquire FENCES at every
// barrier => per-iteration L2 writeback + L1/L2 invalidate on every block
// (64 redundant L2 flushes per XCD per epoch) + post-barrier cold re-fetch.
// Fix: ALL cross-block data (the tiny best-exchange) goes through RELAXED
// agent-scope atomics (coherence-point ops, no cache staleness), so iteration
// barriers carry NO fences. One full-fence barrier (gen 1) publishes the
// immutable dn; after it dn stays L1-hot.
struct KSmem {
    float  rp[RPN];           // 34816 B ([8448..8704) zero pad, never written)
    float4 dn4[4][64];        // own 4 atoms' taps, 4096 B
    float  chv[4][34];        // per-atom chunk maxima (global chunk ids)
    int    chi[4][34];
    float  wv[16]; int wi[16];
    float  fv; int fi;
};

// Full-fence barrier: used ONCE (after init/norm/conv) to publish plain-memory
// dn writes (release->L2 wb) and invalidate readers' stale caches (acquire).
__device__ __forceinline__ void gbar_full(unsigned* c, unsigned target, int tid) {
    __syncthreads();
    if (tid == 0) {
        __hip_atomic_fetch_add(c, 1u, __ATOMIC_RELEASE, __HIP_MEMORY_SCOPE_AGENT);
        while (__hip_atomic_load(c, __ATOMIC_RELAXED, __HIP_MEMORY_SCOPE_AGENT) < target)
            __builtin_amdgcn_s_sleep(2);
    }
    __syncthreads();
    __builtin_amdgcn_fence(__ATOMIC_ACQUIRE, "agent");
}

// Fence-free iteration barrier. Prior exchange stores are relaxed agent
// atomics already acked at the coherence point (s_waitcnt vmcnt(0) in
// best_write); arrival RMW is relaxed; poll is relaxed; per-wave in-order
// issue + __syncthreads order the subsequent atomic exchange reads.
// NO buffer_wbl2 / buffer_inv anywhere in the loop.
__device__ __forceinline__ void gbar_nf(unsigned* c, unsigned target, int tid) {
    __syncthreads();
    if (tid == 0) {
        __hip_atomic_fetch_add(c, 1u, __ATOMIC_RELAXED, __HIP_MEMORY_SCOPE_AGENT);
        while (__hip_atomic_load(c, __ATOMIC_RELAXED, __HIP_MEMORY_SCOPE_AGENT) < target)
            __builtin_amdgcn_s_sleep(1);
    }
    __syncthreads();
}

// Compute conv outputs for up to two 512-chunks (cA -> threads 0..127,
// cB -> threads 128..255; -1 = inactive) for the block's 4 atoms, from LDS rp.
// REPLACES chv/chi entries for the valid chunks. Chunk ids are GLOBAL (0..32).
__device__ void chunks_update(KSmem& sm, int baseF, int cA, int cB, int aBase, int tid) {
    const int lane = tid & 63, w = tid >> 6;
    const int grp = tid >> 7;
    const int cg = grp ? cB : cA;
    const int lt = cg*512 + (tid & 127)*4;    // global output t (j=0); cg>=0 only
    float c0[4] = {0,0,0,0}, c1[4] = {0,0,0,0}, c2[4] = {0,0,0,0}, c3[4] = {0,0,0,0};
    if (cg >= 0) {
        const float4* srp4 = (const float4*)sm.rp;
        int ol4 = (lt - baseF) >> 2;
        float4 p = srp4[ol4];
        #pragma unroll 4
        for (int kq = 0; kq < 64; kq++) {
            float4 d0 = sm.dn4[0][kq];
            float4 d1 = sm.dn4[1][kq];
            float4 d2 = sm.dn4[2][kq];
            float4 d3 = sm.dn4[3][kq];
            float4 pn = srp4[ol4 + kq + 1];
            TAP(c0[0], p.x,p.y,p.z,p.w, d0); TAP(c0[1], p.y,p.z,p.w,pn.x, d0);
            TAP(c0[2], p.z,p.w,pn.x,pn.y, d0); TAP(c0[3], p.w,pn.x,pn.y,pn.z, d0);
            TAP(c1[0], p.x,p.y,p.z,p.w, d1); TAP(c1[1], p.y,p.z,p.w,pn.x, d1);
            TAP(c1[2], p.z,p.w,pn.x,pn.y, d1); TAP(c1[3], p.w,pn.x,pn.y,pn.z, d1);
            TAP(c2[0], p.x,p.y,p.z,p.w, d2); TAP(c2[1], p.y,p.z,p.w,pn.x, d2);
            TAP(c2[2], p.z,p.w,pn.x,pn.y, d2); TAP(c2[3], p.w,pn.x,pn.y,pn.z, d2);
            TAP(c3[0], p.x,p.y,p.z,p.w, d3); TAP(c3[1], p.y,p.z,p.w,pn.x, d3);
            TAP(c3[2], p.z,p.w,pn.x,pn.y, d3); TAP(c3[3], p.w,pn.x,pn.y,pn.z, d3);
            p = pn;
        }
    }
    float bv0 = -INFINITY, bv1 = -INFINITY, bv2 = -INFINITY, bv3 = -INFINITY;
    int bi0 = 0x7fffffff, bi1 = 0x7fffffff, bi2 = 0x7fffffff, bi3 = 0x7fffffff;
    if (cg >= 0) {
        #pragma unroll
        for (int j = 0; j < 4; j++) {
            int t = lt + j;
            if (t < TOUT) {
                if (c0[j] > bv0) { bv0 = c0[j]; bi0 = (aBase+0)*TOUT + t; }
                if (c1[j] > bv1) { bv1 = c1[j]; bi1 = (aBase+1)*TOUT + t; }
                if (c2[j] > bv2) { bv2 = c2[j]; bi2 = (aBase+2)*TOUT + t; }
                if (c3[j] > bv3) { bv3 = c3[j]; bi3 = (aBase+3)*TOUT + t; }
            }
        }
    }
    wave_amax(bv0, bi0); wave_amax(bv1, bi1); wave_amax(bv2, bi2); wave_amax(bv3, bi3);
    if (lane == 0) {
        sm.wv[0*4+w] = bv0; sm.wi[0*4+w] = bi0;
        sm.wv[1*4+w] = bv1; sm.wi[1*4+w] = bi1;
        sm.wv[2*4+w] = bv2; sm.wi[2*4+w] = bi2;
        sm.wv[3*4+w] = bv3; sm.wi[3*4+w] = bi3;
    }
    __syncthreads();
    // combine wave pairs: waves {0,1} -> cA, {2,3} -> cB
    if (tid < 8) {
        int a = tid >> 1, hh = tid & 1;
        int chunk = hh ? cB : cA;
        if (chunk >= 0) {
            float v0 = sm.wv[a*4 + 2*hh];   int i0 = sm.wi[a*4 + 2*hh];
            float v1 = sm.wv[a*4 + 2*hh+1]; int i1 = sm.wi[a*4 + 2*hh+1];
            if (v1 > v0 || (v1 == v0 && i1 < i0)) { v0 = v1; i0 = i1; }
            sm.chv[a][chunk] = v0; sm.chi[a][chunk] = i0;
        }
    }
    __syncthreads();
}

// Per-atom best over the block's chunk range -> exchange slot [b][h][atom].
// RELAXED AGENT ATOMIC stores (coherence-point, no fence needed) + vmcnt drain
// so the store is globally visible before this wave reaches the barrier.
__device__ __forceinline__ void best_write(KSmem& sm, int a0, int b, int h, int tid,
                                           float* __restrict__ abv, int* __restrict__ abi) {
    const int lane = tid & 63, w = tid >> 6;  // wave w -> atom w
    int cstart = h ? 16 : 0, nch = h ? 17 : 16;
    float bv = -INFINITY; int bi = 0x7fffffff;
    if (lane < nch) { bv = sm.chv[w][cstart + lane]; bi = sm.chi[w][cstart + lane]; }
    wave_amax(bv, bi);
    if (lane == 0) {
        int s = b*2*A + h*A + a0*4 + w;
        __hip_atomic_store(&abv[s], bv, __ATOMIC_RELAXED, __HIP_MEMORY_SCOPE_AGENT);
        __hip_atomic_store(&abi[s], bi, __ATOMIC_RELAXED, __HIP_MEMORY_SCOPE_AGENT);
    }
    asm volatile("s_waitcnt vmcnt(0)" ::: "memory");  // ack at coherence point
}

// Batch-wide argmax over 2*A exchange entries (2 halves per atom).
// RELAXED AGENT ATOMIC loads (bypass stale L1/L2 -> always-current values).
__device__ __forceinline__ void pick(KSmem& sm, int b, int tid,
                                     const float* __restrict__ avc, const int* __restrict__ aic) {
    const int lane = tid & 63, w = tid >> 6;
    int s0 = b*2*A + tid;
    float v0 = __hip_atomic_load(&avc[s0],     __ATOMIC_RELAXED, __HIP_MEMORY_SCOPE_AGENT);
    int   i0 = __hip_atomic_load(&aic[s0],     __ATOMIC_RELAXED, __HIP_MEMORY_SCOPE_AGENT);
    float v1 = __hip_atomic_load(&avc[s0 + A], __ATOMIC_RELAXED, __HIP_MEMORY_SCOPE_AGENT);
    int   i1 = __hip_atomic_load(&aic[s0 + A], __ATOMIC_RELAXED, __HIP_MEMORY_SCOPE_AGENT);
    if (v1 > v0 || (v1 == v0 && i1 < i0)) { v0 = v1; i0 = i1; }
    wave_amax(v0, i0);
    if (lane == 0) { sm.wv[w] = v0; sm.wi[w] = i0; }
    __syncthreads();
    if (tid == 0) {
        float bv = sm.wv[0]; int bi = sm.wi[0];
        for (int j = 1; j < 4; j++)
            if (sm.wv[j] > bv || (sm.wv[j] == bv && sm.wi[j] < bi)) { bv = sm.wv[j]; bi = sm.wi[j]; }
        sm.fv = bv; sm.fi = bi;
    }
    __syncthreads();
}

__global__ void __launch_bounds__(256, 2)
k_coop(const float* __restrict__ x, const float* __restrict__ d, float* __restrict__ out,
       float* __restrict__ dn,
       float* __restrict__ abv0, int* __restrict__ abi0,
       float* __restrict__ abv1, int* __restrict__ abi1, unsigned* __restrict__ bar) {
    extern __shared__ char raw[];
    KSmem& sm = *(KSmem*)raw;
    const int bid = blockIdx.x, tid = threadIdx.x;
    const int b = bid >> 7, r = bid & 127;
    const int h = r >> 6, a0 = r & 63;       // half, atom-group (4 atoms)
    const int lane = tid & 63, w = tid >> 6;
    const int baseF = h * HBASE;
    const int cstart = h ? 16 : 0, cend = h ? 33 : 16;
    unsigned* cb = bar + b*BARSTRIDE;

    // ---- init: x -> LDS rp window (padded domain), zero tail ----
    {
        const float4* x4 = (const float4*)(x + (size_t)b*T);
        float4* rp4w = (float4*)sm.rp;
        int b4 = baseF >> 2;
        for (int i = tid; i < RPN/4; i += 256) {
            int g4 = b4 + i;
            float4 v = {0.f,0.f,0.f,0.f};
            if (i < RPSTORE/4 && g4 >= PAD/4 && g4 < (PAD+T)/4) v = x4[g4 - PAD/4];
            rp4w[i] = v;
        }
    }
    // ---- normalize own 4 atoms into LDS + global dn (redundant identical writes;
    //      published by the one full-fence barrier below) ----
    #pragma unroll
    for (int s = 0; s < 4; s++) {
        int atom = a0*4 + s;
        float v = d[atom*K + tid];
        float sq = v*v;
        #pragma unroll
        for (int off = 32; off; off >>= 1) sq += __shfl_down(sq, off);
        if (lane == 0) sm.wv[w] = sq;
        __syncthreads();
        float norm = sqrtf(sm.wv[0] + sm.wv[1] + sm.wv[2] + sm.wv[3]) + 1e-12f;
        float nv = v / norm;
        ((float*)&sm.dn4[s][0])[tid] = nv;
        dn[atom*K + tid] = nv;
        __syncthreads();
    }
    // ---- initial conv over own half (8 or 9 chunk-pair passes) ----
    {
        int npass = h ? 9 : 8;
        for (int p = 0; p < npass; p++) {
            int ca = cstart + 2*p;
            int cb2 = (ca + 1 < cend) ? ca + 1 : -1;
            chunks_update(sm, baseF, ca, cb2, a0*4, tid);
        }
    }
    best_write(sm, a0, b, h, tid, abv0, abi0);
    unsigned gen = 1; gbar_full(cb, gen*BPB2, tid);   // the ONLY full-fence barrier

    const float* avc = abv0; const int* aic = abi0;
    float* avn = abv1; int* ain = abi1;
    for (int it = 0; it < ITERS-1; it++) {
        pick(sm, b, tid, avc, aic);
        float val = sm.fv; int idx = sm.fi;
        int atom = idx / TOUT, pos = idx - atom*TOUT;
        float ds = dn[atom*K + tid];            // plain load, L1-hot (dn immutable)
        int li = pos + tid - baseF;             // local residual update (if in range)
        if (li >= 0 && li < RPSTORE) sm.rp[li] -= val * ds;
        __syncthreads();
        int lo = pos - (K-1); if (lo < 0) lo = 0;
        int g0 = lo >> 9, g1 = g0 + 1;          // the 2 affected global chunks
        bool in0 = (g0 >= cstart && g0 < cend);
        bool in1 = (g1 >= cstart && g1 < cend);
        int ca = in0 ? g0 : (in1 ? g1 : -1);
        int cb2 = (in0 && in1) ? g1 : -1;
        if (ca >= 0) chunks_update(sm, baseF, ca, cb2, a0*4, tid);
        best_write(sm, a0, b, h, tid, avn, ain);  // chv always current -> always refresh
        { const float* t1 = avc; avc = avn; avn = (float*)t1; }
        { const int*   t2 = aic; aic = ain; ain = (int*)t2; }
        gen++; gbar_nf(cb, gen*BPB2, tid);        // fence-free
    }
    // ---- final pick + update + out (one writer block per (batch, half)) ----
    if (a0 == 0) {
        pick(sm, b, tid, avc, aic);
        float val = sm.fv; int idx = sm.fi;
        int atom = idx / TOUT, pos = idx - atom*TOUT;
        float ds = dn[atom*K + tid];
        int li = pos + tid - baseF;
        if (li >= 0 && li < RPSTORE) sm.rp[li] -= val * ds;
        __syncthreads();
        // out[b][o] = x[b][o] - rp[o+PAD]; h=0 covers o in [0,8064), h=1 [8064,16384)
        int o_lo4 = h ? (HBASE - PAD)/4 : 0;
        int o_hi4 = h ? T/4 : (HBASE - PAD)/4;
        const float4* xb4 = (const float4*)(x + (size_t)b*T);
        float4* o4 = (float4*)(out + (size_t)b*T);
        for (int i4 = o_lo4 + tid; i4 < o_hi4; i4 += 256) {
            float4 xv = xb4[i4];
            float4 rv = *(const float4*)&sm.rp[i4*4 + PAD - baseF];
            float4 ov; ov.x = xv.x - rv.x; ov.y = xv.y - rv.y;
            ov.z = xv.z - rv.z; ov.w = xv.w - rv.w;
            o4[i4] = ov;
        }
    }
}

// ===================== fallback path (R6, race-free, unchanged) =====================
struct Smem {
    float rp[TILE + K + 16];
    float dnA[K];
    float dnB[K];
    float dnsel[K];
    float wv[16]; int wi[16];
    float fv; int fi;
};

__device__ __forceinline__ void dev_norm(int a0, int tid, const float* __restrict__ d,
                                         float* __restrict__ dn, Smem& sm) {
    int lane = tid & 63, w = tid >> 6;
    #pragma unroll
    for (int s = 0; s < 2; s++) {
        int atom = a0*2 + s;
        float v = d[atom*K + tid];
        float sq = v*v;
        #pragma unroll
        for (int off = 32; off; off >>= 1) sq += __shfl_down(sq, off);
        if (lane == 0) sm.wv[w] = sq;
        __syncthreads();
        float norm = sqrtf(sm.wv[0] + sm.wv[1] + sm.wv[2] + sm.wv[3]) + 1e-12f;
        dn[atom*K + tid] = v / norm;
        __syncthreads();
    }
}

__device__ __forceinline__ void dev_init(int a0, int b, int tid, const float* __restrict__ x,
                                         float* __restrict__ rp, float* __restrict__ recon) {
    int i = a0*256 + tid;
    if (i < TP) {
        float v = (i >= PAD && i < PAD + T) ? x[b*T + (i - PAD)] : 0.f;
        rp[(size_t)b*TP + i] = v;
        recon[(size_t)b*TP + i] = 0.f;
    }
}

__device__ void dev_conv(int a0, int b, int tid, const float* __restrict__ rp,
                         const float* __restrict__ dn,
                         float* __restrict__ segval, int* __restrict__ segidx,
                         float* __restrict__ abv, int* __restrict__ abi, Smem& sm) {
    const int aA = a0*2, aB = a0*2 + 1;
    const int lane = tid & 63, w = tid >> 6;
    sm.dnA[tid] = dn[aA*K + tid];
    sm.dnB[tid] = dn[aB*K + tid];
    const float4* rp4 = (const float4*)(rp + (size_t)b*TP);

    for (int tile = 0; tile < NTILE; tile++) {
        int t0 = tile * TILE;
        __syncthreads();
        float4* s4 = (float4*)sm.rp;
        for (int i = tid; i < 580; i += 256) {
            int g = t0/4 + i;
            float4 v = {0.f,0.f,0.f,0.f};
            if (g*4 < TP) v = rp4[g];
            s4[i] = v;
        }
        __syncthreads();
        const float4* srp4 = (const float4*)sm.rp;
        const float4* dA4  = (const float4*)sm.dnA;
        const float4* dB4  = (const float4*)sm.dnB;
        float accA0[4] = {0,0,0,0}, accA1[4] = {0,0,0,0};
        float accB0[4] = {0,0,0,0}, accB1[4] = {0,0,0,0};
        float4 p = srp4[tid];
        float4 q = srp4[tid + 256];
        #pragma unroll 4
        for (int kq = 0; kq < 64; kq++) {
            float4 dA = dA4[kq];
            float4 dB = dB4[kq];
            float4 pn = srp4[tid + kq + 1];
            float4 qn = srp4[tid + 256 + kq + 1];
            TAP(accA0[0], p.x,p.y,p.z,p.w, dA); TAP(accA0[1], p.y,p.z,p.w,pn.x, dA);
            TAP(accA0[2], p.z,p.w,pn.x,pn.y, dA); TAP(accA0[3], p.w,pn.x,pn.y,pn.z, dA);
            TAP(accB0[0], p.x,p.y,p.z,p.w, dB); TAP(accB0[1], p.y,p.z,p.w,pn.x, dB);
            TAP(accB0[2], p.z,p.w,pn.x,pn.y, dB); TAP(accB0[3], p.w,pn.x,pn.y,pn.z, dB);
            TAP(accA1[0], q.x,q.y,q.z,q.w, dA); TAP(accA1[1], q.y,q.z,q.w,qn.x, dA);
            TAP(accA1[2], q.z,q.w,qn.x,qn.y, dA); TAP(accA1[3], q.w,qn.x,qn.y,qn.z, dA);
            TAP(accB1[0], q.x,q.y,q.z,q.w, dB); TAP(accB1[1], q.y,q.z,q.w,qn.x, dB);
            TAP(accB1[2], q.z,q.w,qn.x,qn.y, dB); TAP(accB1[3], q.w,qn.x,qn.y,qn.z, dB);
            p = pn; q = qn;
        }
        int lt = tid * 4;
        float bvA0 = -INFINITY, bvA1 = -INFINITY, bvB0 = -INFINITY, bvB1 = -INFINITY;
        int biA0 = 0x7fffffff, biA1 = 0x7fffffff, biB0 = 0x7fffffff, biB1 = 0x7fffffff;
        #pragma unroll
        for (int j = 0; j < 4; j++) {
            int t = t0 + lt + j;
            if (t < TOUT) {
                if (accA0[j] > bvA0) { bvA0 = accA0[j]; biA0 = aA*TOUT + t; }
                if (accB0[j] > bvB0) { bvB0 = accB0[j]; biB0 = aB*TOUT + t; }
            }
            int t1 = t0 + 1024 + lt + j;
            if (t1 < TOUT) {
                if (accA1[j] > bvA1) { bvA1 = accA1[j]; biA1 = aA*TOUT + t1; }
                if (accB1[j] > bvB1) { bvB1 = accB1[j]; biB1 = aB*TOUT + t1; }
            }
        }
        wave_amax(bvA0, biA0); wave_amax(bvA1, biA1);
        wave_amax(bvB0, biB0); wave_amax(bvB1, biB1);
        if (lane == 0) {
            sm.wv[w]    = bvA0; sm.wi[w]    = biA0;
            sm.wv[4+w]  = bvA1; sm.wi[4+w]  = biA1;
            sm.wv[8+w]  = bvB0; sm.wi[8+w]  = biB0;
            sm.wv[12+w] = bvB1; sm.wi[12+w] = biB1;
        }
        __syncthreads();
        if (tid < 4) {
            float v0 = sm.wv[2*tid];   int i0 = sm.wi[2*tid];
            float v1 = sm.wv[2*tid+1]; int i1 = sm.wi[2*tid+1];
            if (v1 > v0 || (v1 == v0 && i1 < i0)) { v0 = v1; i0 = i1; }
            int chunk = tile*4 + tid;
            if (chunk < NCHUNK) {
                segval[((size_t)b*A + aA)*NCP + chunk] = v0;
                segidx[((size_t)b*A + aA)*NCP + chunk] = i0;
            }
        } else if (tid >= 64 && tid < 68) {
            int c = tid - 64;
            float v0 = sm.wv[8+2*c];   int i0 = sm.wi[8+2*c];
            float v1 = sm.wv[8+2*c+1]; int i1 = sm.wi[8+2*c+1];
            if (v1 > v0 || (v1 == v0 && i1 < i0)) { v0 = v1; i0 = i1; }
            int chunk = tile*4 + c;
            if (chunk < NCHUNK) {
                segval[((size_t)b*A + aB)*NCP + chunk] = v0;
                segidx[((size_t)b*A + aB)*NCP + chunk] = i0;
            }
        }
    }
    __syncthreads();
    if (w < 2) {
        int atom = (w == 0) ? aA : aB;
        float bv = -INFINITY; int bi = 0x7fffffff;
        if (lane < NCHUNK) {
            bv = segval[((size_t)b*A + atom)*NCP + lane];
            bi = segidx[((size_t)b*A + atom)*NCP + lane];
        }
        wave_amax(bv, bi);
        if (lane == 0) { abv[b*A + atom] = bv; abi[b*A + atom] = bi; }
    }
}

__device__ void dev_iter(int a0, int b, int tid, int last,
                         const float* __restrict__ avc, const int* __restrict__ aic,
                         float* __restrict__ avn, int* __restrict__ ain,
                         const float* __restrict__ rin, float* __restrict__ rout,
                         float* __restrict__ recon, const float* __restrict__ dn,
                         float* __restrict__ segval, int* __restrict__ segidx, Smem& sm) {
    const int aA = a0*2, aB = a0*2 + 1;
    const int lane = tid & 63, w = tid >> 6;

    float bv0 = avc[b*A + tid]; int bi0 = aic[b*A + tid];
    const float4* rin4 = (const float4*)(rin + (size_t)b*TP);
    const int icopy = a0*256 + tid;
    const bool docopy = (!last) && (icopy < TP/4);
    float4 vcopy = {0.f,0.f,0.f,0.f};
    if (docopy) vcopy = rin4[icopy];
    sm.dnA[tid] = dn[aA*K + tid];
    sm.dnB[tid] = dn[aB*K + tid];

    {
        float bv = bv0; int bi = bi0;
        wave_amax(bv, bi);
        if (lane == 0) { sm.wv[w] = bv; sm.wi[w] = bi; }
        __syncthreads();
        if (tid == 0) {
            bv = sm.wv[0]; bi = sm.wi[0];
            for (int j = 1; j < 4; j++)
                if (sm.wv[j] > bv || (sm.wv[j] == bv && sm.wi[j] < bi)) { bv = sm.wv[j]; bi = sm.wi[j]; }
            sm.fv = bv; sm.fi = bi;
        }
        __syncthreads();
    }
    float val = sm.fv; int idx = sm.fi;
    int atom = idx / TOUT, pos = idx - atom*TOUT;
    sm.dnsel[tid] = dn[atom*K + tid];

    int lo = pos - (K-1); if (lo < 0) lo = 0;
    int c_lo = lo >> 9;
    int tbase = c_lo * CHUNK;

    if (!last) {
        float4* s4 = (float4*)sm.rp;
        for (int i = tid; i < 324; i += 256) {
            int g = tbase/4 + i;
            float4 v = {0.f,0.f,0.f,0.f};
            if (g*4 < TP) v = rin4[g];
            s4[i] = v;
        }
    }
    __syncthreads();
    if (docopy) {
        float4* rout4 = (float4*)(rout + (size_t)b*TP);
        float4 v = vcopy;
        int o = icopy*4 - pos;
        if (o > -4 && o < K) {
            if (o+0 >= 0 && o+0 < K) v.x -= val * sm.dnsel[o+0];
            if (o+1 >= 0 && o+1 < K) v.y -= val * sm.dnsel[o+1];
            if (o+2 >= 0 && o+2 < K) v.z -= val * sm.dnsel[o+2];
            if (o+3 >= 0 && o+3 < K) v.w -= val * sm.dnsel[o+3];
        }
        rout4[icopy] = v;
    }
    if (a0 == 0) {
        recon[(size_t)b*TP + pos + tid] += val * sm.dnsel[tid];
    }
    if (last) return;

    sm.rp[pos + tid - tbase] -= val * sm.dnsel[tid];
    __syncthreads();

    const float4* srp4 = (const float4*)sm.rp;
    const float4* dA4  = (const float4*)sm.dnA;
    const float4* dB4  = (const float4*)sm.dnB;
    float cA[4] = {0,0,0,0}, cB[4] = {0,0,0,0};
    float4 p = srp4[tid];
    #pragma unroll 4
    for (int kq = 0; kq < 64; kq++) {
        float4 dA = dA4[kq];
        float4 dB = dB4[kq];
        float4 pn = srp4[tid + kq + 1];
        TAP(cA[0], p.x,p.y,p.z,p.w, dA); TAP(cA[1], p.y,p.z,p.w,pn.x, dA);
        TAP(cA[2], p.z,p.w,pn.x,pn.y, dA); TAP(cA[3], p.w,pn.x,pn.y,pn.z, dA);
        TAP(cB[0], p.x,p.y,p.z,p.w, dB); TAP(cB[1], p.y,p.z,p.w,pn.x, dB);
        TAP(cB[2], p.z,p.w,pn.x,pn.y, dB); TAP(cB[3], p.w,pn.x,pn.y,pn.z, dB);
        p = pn;
    }
    int lt = tid * 4;
    float bvA = -INFINITY, bvB = -INFINITY;
    int biA = 0x7fffffff, biB = 0x7fffffff;
    #pragma unroll
    for (int j = 0; j < 4; j++) {
        int t = tbase + lt + j;
        if (t < TOUT) {
            if (cA[j] > bvA) { bvA = cA[j]; biA = aA*TOUT + t; }
            if (cB[j] > bvB) { bvB = cB[j]; biB = aB*TOUT + t; }
        }
    }
    wave_amax(bvA, biA); wave_amax(bvB, biB);
    if (lane == 0) { sm.wv[w] = bvA; sm.wi[w] = biA; sm.wv[8+w] = bvB; sm.wi[8+w] = biB; }
    __syncthreads();
    if (tid < 2) {
        float v0 = sm.wv[2*tid];   int i0 = sm.wi[2*tid];
        float v1 = sm.wv[2*tid+1]; int i1 = sm.wi[2*tid+1];
        if (v1 > v0 || (v1 == v0 && i1 < i0)) { v0 = v1; i0 = i1; }
        int chunk = c_lo + tid;
        if (chunk < NCHUNK) {
            segval[((size_t)b*A + aA)*NCP + chunk] = v0;
            segidx[((size_t)b*A + aA)*NCP + chunk] = i0;
        }
    } else if (tid >= 64 && tid < 66) {
        int c = tid - 64;
        float v0 = sm.wv[8+2*c];   int i0 = sm.wi[8+2*c];
        float v1 = sm.wv[8+2*c+1]; int i1 = sm.wi[8+2*c+1];
        if (v1 > v0 || (v1 == v0 && i1 < i0)) { v0 = v1; i0 = i1; }
        int chunk = c_lo + c;
        if (chunk < NCHUNK) {
            segval[((size_t)b*A + aB)*NCP + chunk] = v0;
            segidx[((size_t)b*A + aB)*NCP + chunk] = i0;
        }
    }
    __syncthreads();
    if (w < 2) {
        int at = (w == 0) ? aA : aB;
        float bv = -INFINITY; int bi = 0x7fffffff;
        if (lane < NCHUNK) {
            bv = segval[((size_t)b*A + at)*NCP + lane];
            bi = segidx[((size_t)b*A + at)*NCP + lane];
        }
        wave_amax(bv, bi);
        if (lane == 0) { avn[b*A + at] = bv; ain[b*A + at] = bi; }
    }
}

__global__ void __launch_bounds__(256) k_f_norm_init(const float* x, const float* d,
                                                     float* dn, float* rp0, float* recon) {
    __shared__ Smem sm;
    dev_norm(blockIdx.x & 127, threadIdx.x, d, dn, sm);
    dev_init(blockIdx.x & 127, blockIdx.x >> 7, threadIdx.x, x, rp0, recon);
}
__global__ void __launch_bounds__(256, 2) k_f_conv(const float* rp, const float* dn,
                                                   float* segval, int* segidx,
                                                   float* abv, int* abi) {
    __shared__ Smem sm;
    dev_conv(blockIdx.x & 127, blockIdx.x >> 7, threadIdx.x, rp, dn, segval, segidx, abv, abi, sm);
}
__global__ void __launch_bounds__(256, 2) k_f_iter(int last,
                                                   const float* avc, const int* aic,
                                                   float* avn, int* ain,
                                                   const float* rin, float* rout,
                                                   float* recon, const float* dn,
                                                   float* segval, int* segidx) {
    __shared__ Smem sm;
    dev_iter(blockIdx.x & 127, blockIdx.x >> 7, threadIdx.x, last,
             avc, aic, avn, ain, rin, rout, recon, dn, segval, segidx, sm);
}
__global__ void k_f_out(const float* recon, float* out) {
    int i = blockIdx.x * blockDim.x + threadIdx.x;
    if (i >= B*T) return;
    int b = i / T, t = i - b*T;
    out[i] = recon[(size_t)b*TP + PAD + t];
}

extern "C" void kernel_launch(void* const* d_in, const int* in_sizes, int n_in,
                              void* d_out, int out_size, void* d_ws, size_t ws_size,
                              hipStream_t stream) {
    const float* x = (const float*)d_in[0];
    const float* d = (const float*)d_in[1];
    float* out = (float*)d_out;

    float* ws     = (float*)d_ws;
    float* dn     = ws;                                   // A*K
    float* rp0    = dn  + (size_t)A*K;                    // B*TP (fallback)
    float* rp1    = rp0 + (size_t)B*TP;                   // B*TP (fallback)
    float* recon  = rp1 + (size_t)B*TP;                   // B*TP (fallback)
    float* segval = recon + (size_t)B*TP;                 // B*A*NCP (fallback)
    int*   segidx = (int*)(segval + (size_t)B*A*NCP);     // B*A*NCP (fallback)
    float* abv0   = (float*)(segidx + (size_t)B*A*NCP);   // B*2*A
    float* abv1   = abv0 + (size_t)B*2*A;                 // B*2*A
    int*   abi0   = (int*)(abv1 + (size_t)B*2*A);         // B*2*A
    int*   abi1   = abi0 + (size_t)B*2*A;                 // B*2*A
    unsigned* bar = (unsigned*)(abi1 + (size_t)B*2*A);    // per-batch counters

    // Coop-path feasibility: 512 co-resident blocks at DLDS dynamic LDS
    // (2 blocks/CU). Host queries only.
    (void)hipFuncSetAttribute((const void*)k_coop,
                              hipFuncAttributeMaxDynamicSharedMemorySize, DLDS);
    int nb = 0, ncu = 0;
    hipError_t e1 = hipOccupancyMaxActiveBlocksPerMultiprocessor(&nb, (const void*)k_coop,
                                                                 256, DLDS);
    hipError_t e2 = hipDeviceGetAttribute(&ncu, hipDeviceAttributeMultiprocessorCount, 0);
    bool coop = (e1 == hipSuccess && e2 == hipSuccess && nb > 0 && ncu > 0 &&
                 (long)nb * ncu >= NBLK);
    if (coop) {
        (void)hipMemsetAsync(bar, 0, B*BARSTRIDE*sizeof(unsigned), stream);
        hipLaunchKernelGGL(k_coop, dim3(NBLK), dim3(256), DLDS, stream,
                           x, d, out, dn, abv0, abi0, abv1, abi1, bar);
        return;
    }
    // fallback: separate launches, double-buffered (race-free)
    k_f_norm_init<<<NBLK, 256, 0, stream>>>(x, d, dn, rp0, recon);
    k_f_conv<<<NBLK, 256, 0, stream>>>(rp0, dn, segval, segidx, abv0, abi0);
    float* rbuf[2] = {rp0, rp1};
    float* av[2]   = {abv0, abv1};
    int*   ai[2]   = {abi0, abi1};
    for (int it = 0; it < ITERS; it++) {
        k_f_iter<<<NBLK, 256, 0, stream>>>(it == ITERS-1 ? 1 : 0,
                                           av[it & 1], ai[it & 1],
                                           av[(it + 1) & 1], ai[(it + 1) & 1],
                                           rbuf[it & 1], rbuf[(it + 1) & 1],
                                           recon, dn, segval, segidx);
    }
    k_f_out<<<(B*T + 255)/256, 256, 0, stream>>>(recon, out);
}

// Round 10
// 522.122 us; speedup vs baseline: 1.3577x; 1.0360x over previous
//
#include <hip/hip_runtime.h>
#include <math.h>

#define B    4
#define T    16384
#define A    256
#define K    256
#define PAD  128
#define TP   (T + 2*PAD)      // 16640
#define TOUT (TP - K + 1)     // 16385
#define ITERS 16
#define CHUNK 512
#define NCHUNK 33
#define NCP  36               // (fallback) padded per-atom chunk stride
#define TILE 2048
#define NTILE 9
#define NBLK 512              // grid (both paths)
#define BPB2 128              // blocks per batch (coop path)
#define HBASE 8192            // half split point (outputs & rp base)
#define RPSTORE 8448          // stored rp floats per block (8192 + 256 overlap)
#define RPN 8704              // LDS rp floats incl. zero pad for masked over-reads
#define NGRP 8                // arrival sub-counters per batch (16 arrivals each)
#define SUBSTRIDE 32          // uints between sub-counters (128 B line each)
#define BARSTRIDE (NGRP*SUBSTRIDE)  // uints between per-batch barrier regions
#define DLDS 40960            // dynamic LDS request -> 2 blocks/CU (80KB/CU)

#define TAP(acc, s0,s1,s2,s3, dq) { acc = fmaf(s0,(dq).x,acc); acc = fmaf(s1,(dq).y,acc); \
                                    acc = fmaf(s2,(dq).z,acc); acc = fmaf(s3,(dq).w,acc); }

__device__ __forceinline__ void wave_amax(float& bv, int& bi) {
    #pragma unroll
    for (int off = 32; off; off >>= 1) {
        float ov = __shfl_down(bv, off);
        int   oi = __shfl_down(bi, off);
        if (ov > bv || (ov == bv && oi < bi)) { bv = ov; bi = oi; }
    }
}

// ===================== LDS-resident HALVES path (fence-free + split barrier) =====================
// R9 proved fences cost ~170us (709->541). Remaining per-iter cost (~29us vs
// ~10us countable) is pinned on the SINGLE-LINE barrier: 128 relaxed arrival
// RMWs serialize at the coherence point (~58ns each, R2->R3 measurement) and
// 128 pollers' atomic loads queue on the same line ahead of arrivals.
// R10: (1) 8-way split arrival counters (16 RMWs/line, parallel drain),
// lanes 0-7 poll 8 separate lines, s_sleep(4) backoff; (2) block-local
// pre-reduced exchange: 1 entry per block (128/batch), pick loads 1 pair.
struct KSmem {
    float  rp[RPN];           // 34816 B ([8448..8704) zero pad, never written)
    float4 dn4[4][64];        // own 4 atoms' taps, 4096 B
    float  chv[4][34];        // per-atom chunk maxima (global chunk ids)
    int    chi[4][34];
    float  wv[16]; int wi[16];
    float  fv; int fi;
};

// Split-counter per-batch barrier. Arrival: one RMW into sub-counter (r>>4)
// -- 16 serialized RMWs per line, 8 lines in parallel (~1us vs ~7.4us).
// Detection: wave 0 lanes 0..7 poll one line each, __all combine, s_sleep(4)
// backoff (~107ns) to keep poll loads from saturating the lines.
// fence=true only for the ONE publication barrier (dn plain stores).
__device__ __forceinline__ void gbar_sub(unsigned* sub, int r, unsigned gen16, int tid,
                                         bool release_arrival, bool acquire_exit) {
    __syncthreads();
    if (tid == 0)
        __hip_atomic_fetch_add(&sub[(r >> 4)*SUBSTRIDE], 1u,
                               release_arrival ? __ATOMIC_RELEASE : __ATOMIC_RELAXED,
                               __HIP_MEMORY_SCOPE_AGENT);
    if (tid < 64) {
        for (;;) {
            unsigned ok = 1;
            if (tid < NGRP)
                ok = (__hip_atomic_load(&sub[tid*SUBSTRIDE], __ATOMIC_RELAXED,
                                        __HIP_MEMORY_SCOPE_AGENT) >= gen16);
            if (__all((int)ok)) break;
            __builtin_amdgcn_s_sleep(4);
        }
    }
    __syncthreads();
    if (acquire_exit) __builtin_amdgcn_fence(__ATOMIC_ACQUIRE, "agent");
}

// Compute conv outputs for up to two 512-chunks (cA -> threads 0..127,
// cB -> threads 128..255; -1 = inactive) for the block's 4 atoms, from LDS rp.
// REPLACES chv/chi entries for the valid chunks. Chunk ids are GLOBAL (0..32).
__device__ void chunks_update(KSmem& sm, int baseF, int cA, int cB, int aBase, int tid) {
    const int lane = tid & 63, w = tid >> 6;
    const int grp = tid >> 7;
    const int cg = grp ? cB : cA;
    const int lt = cg*512 + (tid & 127)*4;    // global output t (j=0); cg>=0 only
    float c0[4] = {0,0,0,0}, c1[4] = {0,0,0,0}, c2[4] = {0,0,0,0}, c3[4] = {0,0,0,0};
    if (cg >= 0) {
        const float4* srp4 = (const float4*)sm.rp;
        int ol4 = (lt - baseF) >> 2;
        float4 p = srp4[ol4];
        #pragma unroll 4
        for (int kq = 0; kq < 64; kq++) {
            float4 d0 = sm.dn4[0][kq];
            float4 d1 = sm.dn4[1][kq];
            float4 d2 = sm.dn4[2][kq];
            float4 d3 = sm.dn4[3][kq];
            float4 pn = srp4[ol4 + kq + 1];
            TAP(c0[0], p.x,p.y,p.z,p.w, d0); TAP(c0[1], p.y,p.z,p.w,pn.x, d0);
            TAP(c0[2], p.z,p.w,pn.x,pn.y, d0); TAP(c0[3], p.w,pn.x,pn.y,pn.z, d0);
            TAP(c1[0], p.x,p.y,p.z,p.w, d1); TAP(c1[1], p.y,p.z,p.w,pn.x, d1);
            TAP(c1[2], p.z,p.w,pn.x,pn.y, d1); TAP(c1[3], p.w,pn.x,pn.y,pn.z, d1);
            TAP(c2[0], p.x,p.y,p.z,p.w, d2); TAP(c2[1], p.y,p.z,p.w,pn.x, d2);
            TAP(c2[2], p.z,p.w,pn.x,pn.y, d2); TAP(c2[3], p.w,pn.x,pn.y,pn.z, d2);
            TAP(c3[0], p.x,p.y,p.z,p.w, d3); TAP(c3[1], p.y,p.z,p.w,pn.x, d3);
            TAP(c3[2], p.z,p.w,pn.x,pn.y, d3); TAP(c3[3], p.w,pn.x,pn.y,pn.z, d3);
            p = pn;
        }
    }
    float bv0 = -INFINITY, bv1 = -INFINITY, bv2 = -INFINITY, bv3 = -INFINITY;
    int bi0 = 0x7fffffff, bi1 = 0x7fffffff, bi2 = 0x7fffffff, bi3 = 0x7fffffff;
    if (cg >= 0) {
        #pragma unroll
        for (int j = 0; j < 4; j++) {
            int t = lt + j;
            if (t < TOUT) {
                if (c0[j] > bv0) { bv0 = c0[j]; bi0 = (aBase+0)*TOUT + t; }
                if (c1[j] > bv1) { bv1 = c1[j]; bi1 = (aBase+1)*TOUT + t; }
                if (c2[j] > bv2) { bv2 = c2[j]; bi2 = (aBase+2)*TOUT + t; }
                if (c3[j] > bv3) { bv3 = c3[j]; bi3 = (aBase+3)*TOUT + t; }
            }
        }
    }
    wave_amax(bv0, bi0); wave_amax(bv1, bi1); wave_amax(bv2, bi2); wave_amax(bv3, bi3);
    if (lane == 0) {
        sm.wv[0*4+w] = bv0; sm.wi[0*4+w] = bi0;
        sm.wv[1*4+w] = bv1; sm.wi[1*4+w] = bi1;
        sm.wv[2*4+w] = bv2; sm.wi[2*4+w] = bi2;
        sm.wv[3*4+w] = bv3; sm.wi[3*4+w] = bi3;
    }
    __syncthreads();
    // combine wave pairs: waves {0,1} -> cA, {2,3} -> cB
    if (tid < 8) {
        int a = tid >> 1, hh = tid & 1;
        int chunk = hh ? cB : cA;
        if (chunk >= 0) {
            float v0 = sm.wv[a*4 + 2*hh];   int i0 = sm.wi[a*4 + 2*hh];
            float v1 = sm.wv[a*4 + 2*hh+1]; int i1 = sm.wi[a*4 + 2*hh+1];
            if (v1 > v0 || (v1 == v0 && i1 < i0)) { v0 = v1; i0 = i1; }
            sm.chv[a][chunk] = v0; sm.chi[a][chunk] = i0;
        }
    }
    __syncthreads();
}

// Block-local best over 4 atoms x own chunk range -> ONE exchange slot.
// Hierarchical (max val, min idx) composition preserves global tie-breaking.
// Relaxed agent atomic stores + vmcnt drain (ack at coherence point) so the
// stores are globally visible before this wave's barrier arrival RMW.
__device__ __forceinline__ void best_write1(KSmem& sm, int slot, int h, int tid,
                                            float* __restrict__ abv, int* __restrict__ abi) {
    const int lane = tid & 63, w = tid >> 6;  // wave w -> atom w
    int cstart = h ? 16 : 0, nch = h ? 17 : 16;
    float bv = -INFINITY; int bi = 0x7fffffff;
    if (lane < nch) { bv = sm.chv[w][cstart + lane]; bi = sm.chi[w][cstart + lane]; }
    wave_amax(bv, bi);
    if (lane == 0) { sm.wv[8+w] = bv; sm.wi[8+w] = bi; }
    __syncthreads();
    if (tid == 0) {
        float v = sm.wv[8]; int i = sm.wi[8];
        #pragma unroll
        for (int j = 1; j < 4; j++)
            if (sm.wv[8+j] > v || (sm.wv[8+j] == v && sm.wi[8+j] < i)) { v = sm.wv[8+j]; i = sm.wi[8+j]; }
        __hip_atomic_store(&abv[slot], v, __ATOMIC_RELAXED, __HIP_MEMORY_SCOPE_AGENT);
        __hip_atomic_store(&abi[slot], i, __ATOMIC_RELAXED, __HIP_MEMORY_SCOPE_AGENT);
    }
    asm volatile("s_waitcnt vmcnt(0)" ::: "memory");  // ack at coherence point
}

// Batch-wide argmax over BPB2=128 pre-reduced entries (1 load pair, tid<128).
__device__ __forceinline__ void pick1(KSmem& sm, int b, int tid,
                                      const float* __restrict__ avc, const int* __restrict__ aic) {
    const int lane = tid & 63, w = tid >> 6;
    float v = -INFINITY; int i = 0x7fffffff;
    if (tid < BPB2) {
        int s = b*BPB2 + tid;
        v = __hip_atomic_load(&avc[s], __ATOMIC_RELAXED, __HIP_MEMORY_SCOPE_AGENT);
        i = __hip_atomic_load(&aic[s], __ATOMIC_RELAXED, __HIP_MEMORY_SCOPE_AGENT);
    }
    if (w < 2) {
        wave_amax(v, i);
        if (lane == 0) { sm.wv[w] = v; sm.wi[w] = i; }
    }
    __syncthreads();
    if (tid == 0) {
        float bv = sm.wv[0]; int bi = sm.wi[0];
        if (sm.wv[1] > bv || (sm.wv[1] == bv && sm.wi[1] < bi)) { bv = sm.wv[1]; bi = sm.wi[1]; }
        sm.fv = bv; sm.fi = bi;
    }
    __syncthreads();
}

__global__ void __launch_bounds__(256, 2)
k_coop(const float* __restrict__ x, const float* __restrict__ d, float* __restrict__ out,
       float* __restrict__ dn,
       float* __restrict__ abv0, int* __restrict__ abi0,
       float* __restrict__ abv1, int* __restrict__ abi1, unsigned* __restrict__ bar) {
    extern __shared__ char raw[];
    KSmem& sm = *(KSmem*)raw;
    const int bid = blockIdx.x, tid = threadIdx.x;
    const int b = bid >> 7, r = bid & 127;
    const int h = r >> 6, a0 = r & 63;       // half, atom-group (4 atoms)
    const int lane = tid & 63, w = tid >> 6;
    const int baseF = h * HBASE;
    const int cstart = h ? 16 : 0, cend = h ? 33 : 16;
    const int slot = b*BPB2 + r;             // 1 exchange slot per block
    unsigned* sub = bar + b*BARSTRIDE;

    // ---- init: x -> LDS rp window (padded domain), zero tail ----
    {
        const float4* x4 = (const float4*)(x + (size_t)b*T);
        float4* rp4w = (float4*)sm.rp;
        int b4 = baseF >> 2;
        for (int i = tid; i < RPN/4; i += 256) {
            int g4 = b4 + i;
            float4 v = {0.f,0.f,0.f,0.f};
            if (i < RPSTORE/4 && g4 >= PAD/4 && g4 < (PAD+T)/4) v = x4[g4 - PAD/4];
            rp4w[i] = v;
        }
    }
    // ---- normalize own 4 atoms into LDS + global dn (redundant identical writes;
    //      published by the one full-fence barrier below) ----
    #pragma unroll
    for (int s = 0; s < 4; s++) {
        int atom = a0*4 + s;
        float v = d[atom*K + tid];
        float sq = v*v;
        #pragma unroll
        for (int off = 32; off; off >>= 1) sq += __shfl_down(sq, off);
        if (lane == 0) sm.wv[w] = sq;
        __syncthreads();
        float norm = sqrtf(sm.wv[0] + sm.wv[1] + sm.wv[2] + sm.wv[3]) + 1e-12f;
        float nv = v / norm;
        ((float*)&sm.dn4[s][0])[tid] = nv;
        dn[atom*K + tid] = nv;
        __syncthreads();
    }
    // ---- initial conv over own half (8 or 9 chunk-pair passes) ----
    {
        int npass = h ? 9 : 8;
        for (int p = 0; p < npass; p++) {
            int ca = cstart + 2*p;
            int cb2 = (ca + 1 < cend) ? ca + 1 : -1;
            chunks_update(sm, baseF, ca, cb2, a0*4, tid);
        }
    }
    best_write1(sm, slot, h, tid, abv0, abi0);
    unsigned gen = 1;
    gbar_sub(sub, r, gen*16u, tid, true, true);   // the ONLY full-fence barrier

    const float* avc = abv0; const int* aic = abi0;
    float* avn = abv1; int* ain = abi1;
    for (int it = 0; it < ITERS-1; it++) {
        pick1(sm, b, tid, avc, aic);
        float val = sm.fv; int idx = sm.fi;
        int atom = idx / TOUT, pos = idx - atom*TOUT;
        float ds = dn[atom*K + tid];            // plain load, L1-hot (dn immutable)
        int li = pos + tid - baseF;             // local residual update (if in range)
        if (li >= 0 && li < RPSTORE) sm.rp[li] -= val * ds;
        __syncthreads();
        int lo = pos - (K-1); if (lo < 0) lo = 0;
        int g0 = lo >> 9, g1 = g0 + 1;          // the 2 affected global chunks
        bool in0 = (g0 >= cstart && g0 < cend);
        bool in1 = (g1 >= cstart && g1 < cend);
        int ca = in0 ? g0 : (in1 ? g1 : -1);
        int cb2 = (in0 && in1) ? g1 : -1;
        if (ca >= 0) chunks_update(sm, baseF, ca, cb2, a0*4, tid);
        best_write1(sm, slot, h, tid, avn, ain);  // always refresh (chv current)
        { const float* t1 = avc; avc = avn; avn = (float*)t1; }
        { const int*   t2 = aic; aic = ain; ain = (int*)t2; }
        gen++;
        gbar_sub(sub, r, gen*16u, tid, false, false);  // fence-free
    }
    // ---- final pick + update + out (one writer block per (batch, half)) ----
    if (a0 == 0) {
        pick1(sm, b, tid, avc, aic);
        float val = sm.fv; int idx = sm.fi;
        int atom = idx / TOUT, pos = idx - atom*TOUT;
        float ds = dn[atom*K + tid];
        int li = pos + tid - baseF;
        if (li >= 0 && li < RPSTORE) sm.rp[li] -= val * ds;
        __syncthreads();
        // out[b][o] = x[b][o] - rp[o+PAD]; h=0 covers o in [0,8064), h=1 [8064,16384)
        int o_lo4 = h ? (HBASE - PAD)/4 : 0;
        int o_hi4 = h ? T/4 : (HBASE - PAD)/4;
        const float4* xb4 = (const float4*)(x + (size_t)b*T);
        float4* o4 = (float4*)(out + (size_t)b*T);
        for (int i4 = o_lo4 + tid; i4 < o_hi4; i4 += 256) {
            float4 xv = xb4[i4];
            float4 rv = *(const float4*)&sm.rp[i4*4 + PAD - baseF];
            float4 ov; ov.x = xv.x - rv.x; ov.y = xv.y - rv.y;
            ov.z = xv.z - rv.z; ov.w = xv.w - rv.w;
            o4[i4] = ov;
        }
    }
}

// ===================== fallback path (R6, race-free, unchanged) =====================
struct Smem {
    float rp[TILE + K + 16];
    float dnA[K];
    float dnB[K];
    float dnsel[K];
    float wv[16]; int wi[16];
    float fv; int fi;
};

__device__ __forceinline__ void dev_norm(int a0, int tid, const float* __restrict__ d,
                                         float* __restrict__ dn, Smem& sm) {
    int lane = tid & 63, w = tid >> 6;
    #pragma unroll
    for (int s = 0; s < 2; s++) {
        int atom = a0*2 + s;
        float v = d[atom*K + tid];
        float sq = v*v;
        #pragma unroll
        for (int off = 32; off; off >>= 1) sq += __shfl_down(sq, off);
        if (lane == 0) sm.wv[w] = sq;
        __syncthreads();
        float norm = sqrtf(sm.wv[0] + sm.wv[1] + sm.wv[2] + sm.wv[3]) + 1e-12f;
        dn[atom*K + tid] = v / norm;
        __syncthreads();
    }
}

__device__ __forceinline__ void dev_init(int a0, int b, int tid, const float* __restrict__ x,
                                         float* __restrict__ rp, float* __restrict__ recon) {
    int i = a0*256 + tid;
    if (i < TP) {
        float v = (i >= PAD && i < PAD + T) ? x[b*T + (i - PAD)] : 0.f;
        rp[(size_t)b*TP + i] = v;
        recon[(size_t)b*TP + i] = 0.f;
    }
}

__device__ void dev_conv(int a0, int b, int tid, const float* __restrict__ rp,
                         const float* __restrict__ dn,
                         float* __restrict__ segval, int* __restrict__ segidx,
                         float* __restrict__ abv, int* __restrict__ abi, Smem& sm) {
    const int aA = a0*2, aB = a0*2 + 1;
    const int lane = tid & 63, w = tid >> 6;
    sm.dnA[tid] = dn[aA*K + tid];
    sm.dnB[tid] = dn[aB*K + tid];
    const float4* rp4 = (const float4*)(rp + (size_t)b*TP);

    for (int tile = 0; tile < NTILE; tile++) {
        int t0 = tile * TILE;
        __syncthreads();
        float4* s4 = (float4*)sm.rp;
        for (int i = tid; i < 580; i += 256) {
            int g = t0/4 + i;
            float4 v = {0.f,0.f,0.f,0.f};
            if (g*4 < TP) v = rp4[g];
            s4[i] = v;
        }
        __syncthreads();
        const float4* srp4 = (const float4*)sm.rp;
        const float4* dA4  = (const float4*)sm.dnA;
        const float4* dB4  = (const float4*)sm.dnB;
        float accA0[4] = {0,0,0,0}, accA1[4] = {0,0,0,0};
        float accB0[4] = {0,0,0,0}, accB1[4] = {0,0,0,0};
        float4 p = srp4[tid];
        float4 q = srp4[tid + 256];
        #pragma unroll 4
        for (int kq = 0; kq < 64; kq++) {
            float4 dA = dA4[kq];
            float4 dB = dB4[kq];
            float4 pn = srp4[tid + kq + 1];
            float4 qn = srp4[tid + 256 + kq + 1];
            TAP(accA0[0], p.x,p.y,p.z,p.w, dA); TAP(accA0[1], p.y,p.z,p.w,pn.x, dA);
            TAP(accA0[2], p.z,p.w,pn.x,pn.y, dA); TAP(accA0[3], p.w,pn.x,pn.y,pn.z, dA);
            TAP(accB0[0], p.x,p.y,p.z,p.w, dB); TAP(accB0[1], p.y,p.z,p.w,pn.x, dB);
            TAP(accB0[2], p.z,p.w,pn.x,pn.y, dB); TAP(accB0[3], p.w,pn.x,pn.y,pn.z, dB);
            TAP(accA1[0], q.x,q.y,q.z,q.w, dA); TAP(accA1[1], q.y,q.z,q.w,qn.x, dA);
            TAP(accA1[2], q.z,q.w,qn.x,qn.y, dA); TAP(accA1[3], q.w,qn.x,qn.y,qn.z, dA);
            TAP(accB1[0], q.x,q.y,q.z,q.w, dB); TAP(accB1[1], q.y,q.z,q.w,qn.x, dB);
            TAP(accB1[2], q.z,q.w,qn.x,qn.y, dB); TAP(accB1[3], q.w,qn.x,qn.y,qn.z, dB);
            p = pn; q = qn;
        }
        int lt = tid * 4;
        float bvA0 = -INFINITY, bvA1 = -INFINITY, bvB0 = -INFINITY, bvB1 = -INFINITY;
        int biA0 = 0x7fffffff, biA1 = 0x7fffffff, biB0 = 0x7fffffff, biB1 = 0x7fffffff;
        #pragma unroll
        for (int j = 0; j < 4; j++) {
            int t = t0 + lt + j;
            if (t < TOUT) {
                if (accA0[j] > bvA0) { bvA0 = accA0[j]; biA0 = aA*TOUT + t; }
                if (accB0[j] > bvB0) { bvB0 = accB0[j]; biB0 = aB*TOUT + t; }
            }
            int t1 = t0 + 1024 + lt + j;
            if (t1 < TOUT) {
                if (accA1[j] > bvA1) { bvA1 = accA1[j]; biA1 = aA*TOUT + t1; }
                if (accB1[j] > bvB1) { bvB1 = accB1[j]; biB1 = aB*TOUT + t1; }
            }
        }
        wave_amax(bvA0, biA0); wave_amax(bvA1, biA1);
        wave_amax(bvB0, biB0); wave_amax(bvB1, biB1);
        if (lane == 0) {
            sm.wv[w]    = bvA0; sm.wi[w]    = biA0;
            sm.wv[4+w]  = bvA1; sm.wi[4+w]  = biA1;
            sm.wv[8+w]  = bvB0; sm.wi[8+w]  = biB0;
            sm.wv[12+w] = bvB1; sm.wi[12+w] = biB1;
        }
        __syncthreads();
        if (tid < 4) {
            float v0 = sm.wv[2*tid];   int i0 = sm.wi[2*tid];
            float v1 = sm.wv[2*tid+1]; int i1 = sm.wi[2*tid+1];
            if (v1 > v0 || (v1 == v0 && i1 < i0)) { v0 = v1; i0 = i1; }
            int chunk = tile*4 + tid;
            if (chunk < NCHUNK) {
                segval[((size_t)b*A + aA)*NCP + chunk] = v0;
                segidx[((size_t)b*A + aA)*NCP + chunk] = i0;
            }
        } else if (tid >= 64 && tid < 68) {
            int c = tid - 64;
            float v0 = sm.wv[8+2*c];   int i0 = sm.wi[8+2*c];
            float v1 = sm.wv[8+2*c+1]; int i1 = sm.wi[8+2*c+1];
            if (v1 > v0 || (v1 == v0 && i1 < i0)) { v0 = v1; i0 = i1; }
            int chunk = tile*4 + c;
            if (chunk < NCHUNK) {
                segval[((size_t)b*A + aB)*NCP + chunk] = v0;
                segidx[((size_t)b*A + aB)*NCP + chunk] = i0;
            }
        }
    }
    __syncthreads();
    if (w < 2) {
        int atom = (w == 0) ? aA : aB;
        float bv = -INFINITY; int bi = 0x7fffffff;
        if (lane < NCHUNK) {
            bv = segval[((size_t)b*A + atom)*NCP + lane];
            bi = segidx[((size_t)b*A + atom)*NCP + lane];
        }
        wave_amax(bv, bi);
        if (lane == 0) { abv[b*A + atom] = bv; abi[b*A + atom] = bi; }
    }
}

__device__ void dev_iter(int a0, int b, int tid, int last,
                         const float* __restrict__ avc, const int* __restrict__ aic,
                         float* __restrict__ avn, int* __restrict__ ain,
                         const float* __restrict__ rin, float* __restrict__ rout,
                         float* __restrict__ recon, const float* __restrict__ dn,
                         float* __restrict__ segval, int* __restrict__ segidx, Smem& sm) {
    const int aA = a0*2, aB = a0*2 + 1;
    const int lane = tid & 63, w = tid >> 6;

    float bv0 = avc[b*A + tid]; int bi0 = aic[b*A + tid];
    const float4* rin4 = (const float4*)(rin + (size_t)b*TP);
    const int icopy = a0*256 + tid;
    const bool docopy = (!last) && (icopy < TP/4);
    float4 vcopy = {0.f,0.f,0.f,0.f};
    if (docopy) vcopy = rin4[icopy];
    sm.dnA[tid] = dn[aA*K + tid];
    sm.dnB[tid] = dn[aB*K + tid];

    {
        float bv = bv0; int bi = bi0;
        wave_amax(bv, bi);
        if (lane == 0) { sm.wv[w] = bv; sm.wi[w] = bi; }
        __syncthreads();
        if (tid == 0) {
            bv = sm.wv[0]; bi = sm.wi[0];
            for (int j = 1; j < 4; j++)
                if (sm.wv[j] > bv || (sm.wv[j] == bv && sm.wi[j] < bi)) { bv = sm.wv[j]; bi = sm.wi[j]; }
            sm.fv = bv; sm.fi = bi;
        }
        __syncthreads();
    }
    float val = sm.fv; int idx = sm.fi;
    int atom = idx / TOUT, pos = idx - atom*TOUT;
    sm.dnsel[tid] = dn[atom*K + tid];

    int lo = pos - (K-1); if (lo < 0) lo = 0;
    int c_lo = lo >> 9;
    int tbase = c_lo * CHUNK;

    if (!last) {
        float4* s4 = (float4*)sm.rp;
        for (int i = tid; i < 324; i += 256) {
            int g = tbase/4 + i;
            float4 v = {0.f,0.f,0.f,0.f};
            if (g*4 < TP) v = rin4[g];
            s4[i] = v;
        }
    }
    __syncthreads();
    if (docopy) {
        float4* rout4 = (float4*)(rout + (size_t)b*TP);
        float4 v = vcopy;
        int o = icopy*4 - pos;
        if (o > -4 && o < K) {
            if (o+0 >= 0 && o+0 < K) v.x -= val * sm.dnsel[o+0];
            if (o+1 >= 0 && o+1 < K) v.y -= val * sm.dnsel[o+1];
            if (o+2 >= 0 && o+2 < K) v.z -= val * sm.dnsel[o+2];
            if (o+3 >= 0 && o+3 < K) v.w -= val * sm.dnsel[o+3];
        }
        rout4[icopy] = v;
    }
    if (a0 == 0) {
        recon[(size_t)b*TP + pos + tid] += val * sm.dnsel[tid];
    }
    if (last) return;

    sm.rp[pos + tid - tbase] -= val * sm.dnsel[tid];
    __syncthreads();

    const float4* srp4 = (const float4*)sm.rp;
    const float4* dA4  = (const float4*)sm.dnA;
    const float4* dB4  = (const float4*)sm.dnB;
    float cA[4] = {0,0,0,0}, cB[4] = {0,0,0,0};
    float4 p = srp4[tid];
    #pragma unroll 4
    for (int kq = 0; kq < 64; kq++) {
        float4 dA = dA4[kq];
        float4 dB = dB4[kq];
        float4 pn = srp4[tid + kq + 1];
        TAP(cA[0], p.x,p.y,p.z,p.w, dA); TAP(cA[1], p.y,p.z,p.w,pn.x, dA);
        TAP(cA[2], p.z,p.w,pn.x,pn.y, dA); TAP(cA[3], p.w,pn.x,pn.y,pn.z, dA);
        TAP(cB[0], p.x,p.y,p.z,p.w, dB); TAP(cB[1], p.y,p.z,p.w,pn.x, dB);
        TAP(cB[2], p.z,p.w,pn.x,pn.y, dB); TAP(cB[3], p.w,pn.x,pn.y,pn.z, dB);
        p = pn;
    }
    int lt = tid * 4;
    float bvA = -INFINITY, bvB = -INFINITY;
    int biA = 0x7fffffff, biB = 0x7fffffff;
    #pragma unroll
    for (int j = 0; j < 4; j++) {
        int t = tbase + lt + j;
        if (t < TOUT) {
            if (cA[j] > bvA) { bvA = cA[j]; biA = aA*TOUT + t; }
            if (cB[j] > bvB) { bvB = cB[j]; biB = aB*TOUT + t; }
        }
    }
    wave_amax(bvA, biA); wave_amax(bvB, biB);
    if (lane == 0) { sm.wv[w] = bvA; sm.wi[w] = biA; sm.wv[8+w] = bvB; sm.wi[8+w] = biB; }
    __syncthreads();
    if (tid < 2) {
        float v0 = sm.wv[2*tid];   int i0 = sm.wi[2*tid];
        float v1 = sm.wv[2*tid+1]; int i1 = sm.wi[2*tid+1];
        if (v1 > v0 || (v1 == v0 && i1 < i0)) { v0 = v1; i0 = i1; }
        int chunk = c_lo + tid;
        if (chunk < NCHUNK) {
            segval[((size_t)b*A + aA)*NCP + chunk] = v0;
            segidx[((size_t)b*A + aA)*NCP + chunk] = i0;
        }
    } else if (tid >= 64 && tid < 66) {
        int c = tid - 64;
        float v0 = sm.wv[8+2*c];   int i0 = sm.wi[8+2*c];
        float v1 = sm.wv[8+2*c+1]; int i1 = sm.wi[8+2*c+1];
        if (v1 > v0 || (v1 == v0 && i1 < i0)) { v0 = v1; i0 = i1; }
        int chunk = c_lo + c;
        if (chunk < NCHUNK) {
            segval[((size_t)b*A + aB)*NCP + chunk] = v0;
            segidx[((size_t)b*A + aB)*NCP + chunk] = i0;
        }
    }
    __syncthreads();
    if (w < 2) {
        int at = (w == 0) ? aA : aB;
        float bv = -INFINITY; int bi = 0x7fffffff;
        if (lane < NCHUNK) {
            bv = segval[((size_t)b*A + at)*NCP + lane];
            bi = segidx[((size_t)b*A + at)*NCP + lane];
        }
        wave_amax(bv, bi);
        if (lane == 0) { avn[b*A + at] = bv; ain[b*A + at] = bi; }
    }
}

__global__ void __launch_bounds__(256) k_f_norm_init(const float* x, const float* d,
                                                     float* dn, float* rp0, float* recon) {
    __shared__ Smem sm;
    dev_norm(blockIdx.x & 127, threadIdx.x, d, dn, sm);
    dev_init(blockIdx.x & 127, blockIdx.x >> 7, threadIdx.x, x, rp0, recon);
}
__global__ void __launch_bounds__(256, 2) k_f_conv(const float* rp, const float* dn,
                                                   float* segval, int* segidx,
                                                   float* abv, int* abi) {
    __shared__ Smem sm;
    dev_conv(blockIdx.x & 127, blockIdx.x >> 7, threadIdx.x, rp, dn, segval, segidx, abv, abi, sm);
}
__global__ void __launch_bounds__(256, 2) k_f_iter(int last,
                                                   const float* avc, const int* aic,
                                                   float* avn, int* ain,
                                                   const float* rin, float* rout,
                                                   float* recon, const float* dn,
                                                   float* segval, int* segidx) {
    __shared__ Smem sm;
    dev_iter(blockIdx.x & 127, blockIdx.x >> 7, threadIdx.x, last,
             avc, aic, avn, ain, rin, rout, recon, dn, segval, segidx, sm);
}
__global__ void k_f_out(const float* recon, float* out) {
    int i = blockIdx.x * blockDim.x + threadIdx.x;
    if (i >= B*T) return;
    int b = i / T, t = i - b*T;
    out[i] = recon[(size_t)b*TP + PAD + t];
}

extern "C" void kernel_launch(void* const* d_in, const int* in_sizes, int n_in,
                              void* d_out, int out_size, void* d_ws, size_t ws_size,
                              hipStream_t stream) {
    const float* x = (const float*)d_in[0];
    const float* d = (const float*)d_in[1];
    float* out = (float*)d_out;

    float* ws     = (float*)d_ws;
    float* dn     = ws;                                   // A*K
    float* rp0    = dn  + (size_t)A*K;                    // B*TP (fallback)
    float* rp1    = rp0 + (size_t)B*TP;                   // B*TP (fallback)
    float* recon  = rp1 + (size_t)B*TP;                   // B*TP (fallback)
    float* segval = recon + (size_t)B*TP;                 // B*A*NCP (fallback)
    int*   segidx = (int*)(segval + (size_t)B*A*NCP);     // B*A*NCP (fallback)
    float* abv0   = (float*)(segidx + (size_t)B*A*NCP);   // max(B*A fallback, B*BPB2 coop)
    float* abv1   = abv0 + (size_t)B*2*A;                 // same size
    int*   abi0   = (int*)(abv1 + (size_t)B*2*A);
    int*   abi1   = abi0 + (size_t)B*2*A;
    unsigned* bar = (unsigned*)(abi1 + (size_t)B*2*A);    // B x NGRP split counters

    // Coop-path feasibility: 512 co-resident blocks at DLDS dynamic LDS
    // (2 blocks/CU). Host queries only.
    (void)hipFuncSetAttribute((const void*)k_coop,
                              hipFuncAttributeMaxDynamicSharedMemorySize, DLDS);
    int nb = 0, ncu = 0;
    hipError_t e1 = hipOccupancyMaxActiveBlocksPerMultiprocessor(&nb, (const void*)k_coop,
                                                                 256, DLDS);
    hipError_t e2 = hipDeviceGetAttribute(&ncu, hipDeviceAttributeMultiprocessorCount, 0);
    bool coop = (e1 == hipSuccess && e2 == hipSuccess && nb > 0 && ncu > 0 &&
                 (long)nb * ncu >= NBLK);
    if (coop) {
        (void)hipMemsetAsync(bar, 0, B*BARSTRIDE*sizeof(unsigned), stream);
        hipLaunchKernelGGL(k_coop, dim3(NBLK), dim3(256), DLDS, stream,
                           x, d, out, dn, abv0, abi0, abv1, abi1, bar);
        return;
    }
    // fallback: separate launches, double-buffered (race-free)
    k_f_norm_init<<<NBLK, 256, 0, stream>>>(x, d, dn, rp0, recon);
    k_f_conv<<<NBLK, 256, 0, stream>>>(rp0, dn, segval, segidx, abv0, abi0);
    float* rbuf[2] = {rp0, rp1};
    float* av[2]   = {abv0, abv1};
    int*   ai[2]   = {abi0, abi1};
    for (int it = 0; it < ITERS; it++) {
        k_f_iter<<<NBLK, 256, 0, stream>>>(it == ITERS-1 ? 1 : 0,
                                           av[it & 1], ai[it & 1],
                                           av[(it + 1) & 1], ai[(it + 1) & 1],
                                           rbuf[it & 1], rbuf[(it + 1) & 1],
                                           recon, dn, segval, segidx);
    }
    k_f_out<<<(B*T + 255)/256, 256, 0, stream>>>(recon, out);
}

// Round 11
// 517.032 us; speedup vs baseline: 1.3710x; 1.0098x over previous
//
#include <hip/hip_runtime.h>
#include <math.h>

#define B    4
#define T    16384
#define A    256
#define K    256
#define PAD  128
#define TP   (T + 2*PAD)      // 16640
#define TOUT (TP - K + 1)     // 16385
#define ITERS 16
#define CHUNK 512
#define NCHUNK 33
#define NCP  36               // (fallback) padded per-atom chunk stride
#define TILE 2048
#define NTILE 9
#define NBLK 512              // grid (both paths)
#define BPB2 128              // blocks per batch (coop path)
#define HBASE 8192            // half split point (outputs & rp base)
#define RPSTORE 8448          // stored rp floats per block (8192 + 256 overlap)
#define RPN 8704              // LDS rp floats incl. zero pad for masked over-reads
#define NGRP 8                // arrival sub-counters per batch (fence barrier only)
#define SUBSTRIDE 32          // uints between sub-counters (128 B line each)
#define BARSTRIDE (NGRP*SUBSTRIDE)  // uints between per-batch barrier regions
#define DLDS 40960            // dynamic LDS request -> 2 blocks/CU (80KB/CU)

#define TAP(acc, s0,s1,s2,s3, dq) { acc = fmaf(s0,(dq).x,acc); acc = fmaf(s1,(dq).y,acc); \
                                    acc = fmaf(s2,(dq).z,acc); acc = fmaf(s3,(dq).w,acc); }

typedef unsigned long long u64;

__device__ __forceinline__ void wave_amax(float& bv, int& bi) {
    #pragma unroll
    for (int off = 32; off; off >>= 1) {
        float ov = __shfl_down(bv, off);
        int   oi = __shfl_down(bi, off);
        if (ov > bv || (ov == bv && oi < bi)) { bv = ov; bi = oi; }
    }
}

// ===================== LDS-resident HALVES path, gen-tagged slot exchange =====================
// R9: removing per-iter fences saved 170us. R10: splitting arrival RMWs saved
// only 19us -> the cost is the MULTI-PHASE per-iter coherence chain (write ->
// ack -> arrive -> detect -> read). R11 fuses barrier+exchange: each block
// publishes ONE packed u64 [gen+1:8 | val:32 | idx:23]; readers poll their
// slot's GEN TAG -- detection IS the data read. Two parity arrays alternate;
// the dependency chain (write gen g+2 requires consuming winner g+1 requires
// all blocks consumed gen g) makes overwrite-before-read impossible. Slots are
// CONTIGUOUS (1KB/batch/parity) so a wave's 64 polls coalesce to 4 lines.
struct KSmem {
    float  rp[RPN];           // 34816 B ([8448..8704) zero pad, never written)
    float4 dn4[4][64];        // own 4 atoms' taps, 4096 B
    float  chv[4][34];        // per-atom chunk maxima (global chunk ids)
    int    chi[4][34];
    float  wv[16]; int wi[16];
    float  fv; int fi;
};

// Split-counter per-batch barrier -- used ONCE (dn publication fence).
__device__ __forceinline__ void gbar_sub(unsigned* sub, int r, unsigned gen16, int tid) {
    __syncthreads();
    if (tid == 0)
        __hip_atomic_fetch_add(&sub[(r >> 4)*SUBSTRIDE], 1u,
                               __ATOMIC_RELEASE, __HIP_MEMORY_SCOPE_AGENT);
    if (tid < 64) {
        for (;;) {
            unsigned ok = 1;
            if (tid < NGRP)
                ok = (__hip_atomic_load(&sub[tid*SUBSTRIDE], __ATOMIC_RELAXED,
                                        __HIP_MEMORY_SCOPE_AGENT) >= gen16);
            if (__all((int)ok)) break;
            __builtin_amdgcn_s_sleep(4);
        }
    }
    __syncthreads();
    __builtin_amdgcn_fence(__ATOMIC_ACQUIRE, "agent");
}

// Compute conv outputs for up to two 512-chunks (cA -> threads 0..127,
// cB -> threads 128..255; -1 = inactive) for the block's 4 atoms, from LDS rp.
// REPLACES chv/chi entries for the valid chunks. Chunk ids are GLOBAL (0..32).
__device__ void chunks_update(KSmem& sm, int baseF, int cA, int cB, int aBase, int tid) {
    const int lane = tid & 63, w = tid >> 6;
    const int grp = tid >> 7;
    const int cg = grp ? cB : cA;
    const int lt = cg*512 + (tid & 127)*4;    // global output t (j=0); cg>=0 only
    float c0[4] = {0,0,0,0}, c1[4] = {0,0,0,0}, c2[4] = {0,0,0,0}, c3[4] = {0,0,0,0};
    if (cg >= 0) {
        const float4* srp4 = (const float4*)sm.rp;
        int ol4 = (lt - baseF) >> 2;
        float4 p = srp4[ol4];
        #pragma unroll 4
        for (int kq = 0; kq < 64; kq++) {
            float4 d0 = sm.dn4[0][kq];
            float4 d1 = sm.dn4[1][kq];
            float4 d2 = sm.dn4[2][kq];
            float4 d3 = sm.dn4[3][kq];
            float4 pn = srp4[ol4 + kq + 1];
            TAP(c0[0], p.x,p.y,p.z,p.w, d0); TAP(c0[1], p.y,p.z,p.w,pn.x, d0);
            TAP(c0[2], p.z,p.w,pn.x,pn.y, d0); TAP(c0[3], p.w,pn.x,pn.y,pn.z, d0);
            TAP(c1[0], p.x,p.y,p.z,p.w, d1); TAP(c1[1], p.y,p.z,p.w,pn.x, d1);
            TAP(c1[2], p.z,p.w,pn.x,pn.y, d1); TAP(c1[3], p.w,pn.x,pn.y,pn.z, d1);
            TAP(c2[0], p.x,p.y,p.z,p.w, d2); TAP(c2[1], p.y,p.z,p.w,pn.x, d2);
            TAP(c2[2], p.z,p.w,pn.x,pn.y, d2); TAP(c2[3], p.w,pn.x,pn.y,pn.z, d2);
            TAP(c3[0], p.x,p.y,p.z,p.w, d3); TAP(c3[1], p.y,p.z,p.w,pn.x, d3);
            TAP(c3[2], p.z,p.w,pn.x,pn.y, d3); TAP(c3[3], p.w,pn.x,pn.y,pn.z, d3);
            p = pn;
        }
    }
    float bv0 = -INFINITY, bv1 = -INFINITY, bv2 = -INFINITY, bv3 = -INFINITY;
    int bi0 = 0x7fffffff, bi1 = 0x7fffffff, bi2 = 0x7fffffff, bi3 = 0x7fffffff;
    if (cg >= 0) {
        #pragma unroll
        for (int j = 0; j < 4; j++) {
            int t = lt + j;
            if (t < TOUT) {
                if (c0[j] > bv0) { bv0 = c0[j]; bi0 = (aBase+0)*TOUT + t; }
                if (c1[j] > bv1) { bv1 = c1[j]; bi1 = (aBase+1)*TOUT + t; }
                if (c2[j] > bv2) { bv2 = c2[j]; bi2 = (aBase+2)*TOUT + t; }
                if (c3[j] > bv3) { bv3 = c3[j]; bi3 = (aBase+3)*TOUT + t; }
            }
        }
    }
    wave_amax(bv0, bi0); wave_amax(bv1, bi1); wave_amax(bv2, bi2); wave_amax(bv3, bi3);
    if (lane == 0) {
        sm.wv[0*4+w] = bv0; sm.wi[0*4+w] = bi0;
        sm.wv[1*4+w] = bv1; sm.wi[1*4+w] = bi1;
        sm.wv[2*4+w] = bv2; sm.wi[2*4+w] = bi2;
        sm.wv[3*4+w] = bv3; sm.wi[3*4+w] = bi3;
    }
    __syncthreads();
    // combine wave pairs: waves {0,1} -> cA, {2,3} -> cB
    if (tid < 8) {
        int a = tid >> 1, hh = tid & 1;
        int chunk = hh ? cB : cA;
        if (chunk >= 0) {
            float v0 = sm.wv[a*4 + 2*hh];   int i0 = sm.wi[a*4 + 2*hh];
            float v1 = sm.wv[a*4 + 2*hh+1]; int i1 = sm.wi[a*4 + 2*hh+1];
            if (v1 > v0 || (v1 == v0 && i1 < i0)) { v0 = v1; i0 = i1; }
            sm.chv[a][chunk] = v0; sm.chi[a][chunk] = i0;
        }
    }
    __syncthreads();
}

// Block-local best over 4 atoms x own chunk range -> ONE packed u64 slot.
// [gen+1 : 8][val bits : 32][idx : 23]  (idx < 256*16385 = 4194560 < 2^23)
__device__ __forceinline__ void slot_write(KSmem& sm, u64* wp, int gen, int h, int tid) {
    const int lane = tid & 63, w = tid >> 6;  // wave w -> atom w
    int cstart = h ? 16 : 0, nch = h ? 17 : 16;
    float bv = -INFINITY; int bi = 0x7fffffff;
    if (lane < nch) { bv = sm.chv[w][cstart + lane]; bi = sm.chi[w][cstart + lane]; }
    wave_amax(bv, bi);
    if (lane == 0) { sm.wv[8+w] = bv; sm.wi[8+w] = bi; }
    __syncthreads();
    if (tid == 0) {
        float v = sm.wv[8]; int i = sm.wi[8];
        #pragma unroll
        for (int j = 1; j < 4; j++)
            if (sm.wv[8+j] > v || (sm.wv[8+j] == v && sm.wi[8+j] < i)) { v = sm.wv[8+j]; i = sm.wi[8+j]; }
        u64 e = ((u64)(unsigned)(gen + 1) << 56)
              | ((u64)__float_as_uint(v) << 24)
              | (u64)(unsigned)i;
        __hip_atomic_store(wp, e, __ATOMIC_RELAXED, __HIP_MEMORY_SCOPE_AGENT);
    }
}

// Fused detect+read+argmax: lanes tid<128 poll their own slot until the gen
// tag matches (independent per-lane spins, no block barrier per round), then
// 2-wave argmax reduce. Winner -> sm.fv/fi. Deterministic across blocks.
__device__ __forceinline__ void pick_poll(KSmem& sm, const u64* sl, int gen, int tid) {
    const int lane = tid & 63, w = tid >> 6;
    float v = -INFINITY; int i = 0x7fffffff;
    if (tid < BPB2) {
        const u64* p = sl + tid;
        u64 e;
        for (;;) {
            e = __hip_atomic_load(p, __ATOMIC_RELAXED, __HIP_MEMORY_SCOPE_AGENT);
            if ((unsigned)(e >> 56) == (unsigned)(gen + 1)) break;
            __builtin_amdgcn_s_sleep(1);
        }
        v = __uint_as_float((unsigned)((e >> 24) & 0xFFFFFFFFull));
        i = (int)(e & 0x7FFFFF);
    }
    if (w < 2) {
        wave_amax(v, i);
        if (lane == 0) { sm.wv[w] = v; sm.wi[w] = i; }
    }
    __syncthreads();
    if (tid == 0) {
        float bv = sm.wv[0]; int bi = sm.wi[0];
        if (sm.wv[1] > bv || (sm.wv[1] == bv && sm.wi[1] < bi)) { bv = sm.wv[1]; bi = sm.wi[1]; }
        sm.fv = bv; sm.fi = bi;
    }
    __syncthreads();
}

__global__ void __launch_bounds__(256, 2)
k_coop(const float* __restrict__ x, const float* __restrict__ d, float* __restrict__ out,
       float* __restrict__ dn, u64* __restrict__ slots, unsigned* __restrict__ bar) {
    extern __shared__ char raw[];
    KSmem& sm = *(KSmem*)raw;
    const int bid = blockIdx.x, tid = threadIdx.x;
    const int b = bid >> 7, r = bid & 127;
    const int h = r >> 6, a0 = r & 63;       // half, atom-group (4 atoms)
    const int lane = tid & 63, w = tid >> 6;
    const int baseF = h * HBASE;
    const int cstart = h ? 16 : 0, cend = h ? 33 : 16;
    u64* slotsb = slots + (size_t)b*2*BPB2;  // [parity][BPB2] contiguous
    unsigned* sub = bar + b*BARSTRIDE;

    // ---- init: x -> LDS rp window (padded domain), zero tail ----
    {
        const float4* x4 = (const float4*)(x + (size_t)b*T);
        float4* rp4w = (float4*)sm.rp;
        int b4 = baseF >> 2;
        for (int i = tid; i < RPN/4; i += 256) {
            int g4 = b4 + i;
            float4 v = {0.f,0.f,0.f,0.f};
            if (i < RPSTORE/4 && g4 >= PAD/4 && g4 < (PAD+T)/4) v = x4[g4 - PAD/4];
            rp4w[i] = v;
        }
    }
    // ---- normalize own 4 atoms into LDS + global dn (redundant identical writes;
    //      published by the one full-fence barrier below) ----
    #pragma unroll
    for (int s = 0; s < 4; s++) {
        int atom = a0*4 + s;
        float v = d[atom*K + tid];
        float sq = v*v;
        #pragma unroll
        for (int off = 32; off; off >>= 1) sq += __shfl_down(sq, off);
        if (lane == 0) sm.wv[w] = sq;
        __syncthreads();
        float norm = sqrtf(sm.wv[0] + sm.wv[1] + sm.wv[2] + sm.wv[3]) + 1e-12f;
        float nv = v / norm;
        ((float*)&sm.dn4[s][0])[tid] = nv;
        dn[atom*K + tid] = nv;
        __syncthreads();
    }
    // ---- initial conv over own half (8 or 9 chunk-pair passes) ----
    {
        int npass = h ? 9 : 8;
        for (int p = 0; p < npass; p++) {
            int ca = cstart + 2*p;
            int cb2 = (ca + 1 < cend) ? ca + 1 : -1;
            chunks_update(sm, baseF, ca, cb2, a0*4, tid);
        }
    }
    slot_write(sm, slotsb + 0*BPB2 + r, 0, h, tid);   // gen 0, parity 0
    gbar_sub(sub, r, 16u, tid);                        // the ONLY full barrier (dn fence)

    for (int it = 0; it < ITERS-1; it++) {
        pick_poll(sm, slotsb + (it & 1)*BPB2, it, tid);
        float val = sm.fv; int idx = sm.fi;
        int atom = idx / TOUT, pos = idx - atom*TOUT;
        float ds = dn[atom*K + tid];            // plain load, L1-hot (dn immutable)
        int li = pos + tid - baseF;             // local residual update (if in range)
        if (li >= 0 && li < RPSTORE) sm.rp[li] -= val * ds;
        __syncthreads();
        int lo = pos - (K-1); if (lo < 0) lo = 0;
        int g0 = lo >> 9, g1 = g0 + 1;          // the 2 affected global chunks
        bool in0 = (g0 >= cstart && g0 < cend);
        bool in1 = (g1 >= cstart && g1 < cend);
        int ca = in0 ? g0 : (in1 ? g1 : -1);
        int cb2 = (in0 && in1) ? g1 : -1;
        if (ca >= 0) chunks_update(sm, baseF, ca, cb2, a0*4, tid);
        slot_write(sm, slotsb + ((it+1) & 1)*BPB2 + r, it+1, h, tid);
        // no barrier: next pick_poll's gen tags ARE the synchronization
    }
    // ---- final pick + update + out (one writer block per (batch, half)) ----
    if (a0 == 0) {
        pick_poll(sm, slotsb + ((ITERS-1) & 1)*BPB2, ITERS-1, tid);
        float val = sm.fv; int idx = sm.fi;
        int atom = idx / TOUT, pos = idx - atom*TOUT;
        float ds = dn[atom*K + tid];
        int li = pos + tid - baseF;
        if (li >= 0 && li < RPSTORE) sm.rp[li] -= val * ds;
        __syncthreads();
        // out[b][o] = x[b][o] - rp[o+PAD]; h=0 covers o in [0,8064), h=1 [8064,16384)
        int o_lo4 = h ? (HBASE - PAD)/4 : 0;
        int o_hi4 = h ? T/4 : (HBASE - PAD)/4;
        const float4* xb4 = (const float4*)(x + (size_t)b*T);
        float4* o4 = (float4*)(out + (size_t)b*T);
        for (int i4 = o_lo4 + tid; i4 < o_hi4; i4 += 256) {
            float4 xv = xb4[i4];
            float4 rv = *(const float4*)&sm.rp[i4*4 + PAD - baseF];
            float4 ov; ov.x = xv.x - rv.x; ov.y = xv.y - rv.y;
            ov.z = xv.z - rv.z; ov.w = xv.w - rv.w;
            o4[i4] = ov;
        }
    }
}

// ===================== fallback path (R6, race-free, unchanged) =====================
struct Smem {
    float rp[TILE + K + 16];
    float dnA[K];
    float dnB[K];
    float dnsel[K];
    float wv[16]; int wi[16];
    float fv; int fi;
};

__device__ __forceinline__ void dev_norm(int a0, int tid, const float* __restrict__ d,
                                         float* __restrict__ dn, Smem& sm) {
    int lane = tid & 63, w = tid >> 6;
    #pragma unroll
    for (int s = 0; s < 2; s++) {
        int atom = a0*2 + s;
        float v = d[atom*K + tid];
        float sq = v*v;
        #pragma unroll
        for (int off = 32; off; off >>= 1) sq += __shfl_down(sq, off);
        if (lane == 0) sm.wv[w] = sq;
        __syncthreads();
        float norm = sqrtf(sm.wv[0] + sm.wv[1] + sm.wv[2] + sm.wv[3]) + 1e-12f;
        dn[atom*K + tid] = v / norm;
        __syncthreads();
    }
}

__device__ __forceinline__ void dev_init(int a0, int b, int tid, const float* __restrict__ x,
                                         float* __restrict__ rp, float* __restrict__ recon) {
    int i = a0*256 + tid;
    if (i < TP) {
        float v = (i >= PAD && i < PAD + T) ? x[b*T + (i - PAD)] : 0.f;
        rp[(size_t)b*TP + i] = v;
        recon[(size_t)b*TP + i] = 0.f;
    }
}

__device__ void dev_conv(int a0, int b, int tid, const float* __restrict__ rp,
                         const float* __restrict__ dn,
                         float* __restrict__ segval, int* __restrict__ segidx,
                         float* __restrict__ abv, int* __restrict__ abi, Smem& sm) {
    const int aA = a0*2, aB = a0*2 + 1;
    const int lane = tid & 63, w = tid >> 6;
    sm.dnA[tid] = dn[aA*K + tid];
    sm.dnB[tid] = dn[aB*K + tid];
    const float4* rp4 = (const float4*)(rp + (size_t)b*TP);

    for (int tile = 0; tile < NTILE; tile++) {
        int t0 = tile * TILE;
        __syncthreads();
        float4* s4 = (float4*)sm.rp;
        for (int i = tid; i < 580; i += 256) {
            int g = t0/4 + i;
            float4 v = {0.f,0.f,0.f,0.f};
            if (g*4 < TP) v = rp4[g];
            s4[i] = v;
        }
        __syncthreads();
        const float4* srp4 = (const float4*)sm.rp;
        const float4* dA4  = (const float4*)sm.dnA;
        const float4* dB4  = (const float4*)sm.dnB;
        float accA0[4] = {0,0,0,0}, accA1[4] = {0,0,0,0};
        float accB0[4] = {0,0,0,0}, accB1[4] = {0,0,0,0};
        float4 p = srp4[tid];
        float4 q = srp4[tid + 256];
        #pragma unroll 4
        for (int kq = 0; kq < 64; kq++) {
            float4 dA = dA4[kq];
            float4 dB = dB4[kq];
            float4 pn = srp4[tid + kq + 1];
            float4 qn = srp4[tid + 256 + kq + 1];
            TAP(accA0[0], p.x,p.y,p.z,p.w, dA); TAP(accA0[1], p.y,p.z,p.w,pn.x, dA);
            TAP(accA0[2], p.z,p.w,pn.x,pn.y, dA); TAP(accA0[3], p.w,pn.x,pn.y,pn.z, dA);
            TAP(accB0[0], p.x,p.y,p.z,p.w, dB); TAP(accB0[1], p.y,p.z,p.w,pn.x, dB);
            TAP(accB0[2], p.z,p.w,pn.x,pn.y, dB); TAP(accB0[3], p.w,pn.x,pn.y,pn.z, dB);
            TAP(accA1[0], q.x,q.y,q.z,q.w, dA); TAP(accA1[1], q.y,q.z,q.w,qn.x, dA);
            TAP(accA1[2], q.z,q.w,qn.x,qn.y, dA); TAP(accA1[3], q.w,qn.x,qn.y,qn.z, dA);
            TAP(accB1[0], q.x,q.y,q.z,q.w, dB); TAP(accB1[1], q.y,q.z,q.w,qn.x, dB);
            TAP(accB1[2], q.z,q.w,qn.x,qn.y, dB); TAP(accB1[3], q.w,qn.x,qn.y,qn.z, dB);
            p = pn; q = qn;
        }
        int lt = tid * 4;
        float bvA0 = -INFINITY, bvA1 = -INFINITY, bvB0 = -INFINITY, bvB1 = -INFINITY;
        int biA0 = 0x7fffffff, biA1 = 0x7fffffff, biB0 = 0x7fffffff, biB1 = 0x7fffffff;
        #pragma unroll
        for (int j = 0; j < 4; j++) {
            int t = t0 + lt + j;
            if (t < TOUT) {
                if (accA0[j] > bvA0) { bvA0 = accA0[j]; biA0 = aA*TOUT + t; }
                if (accB0[j] > bvB0) { bvB0 = accB0[j]; biB0 = aB*TOUT + t; }
            }
            int t1 = t0 + 1024 + lt + j;
            if (t1 < TOUT) {
                if (accA1[j] > bvA1) { bvA1 = accA1[j]; biA1 = aA*TOUT + t1; }
                if (accB1[j] > bvB1) { bvB1 = accB1[j]; biB1 = aB*TOUT + t1; }
            }
        }
        wave_amax(bvA0, biA0); wave_amax(bvA1, biA1);
        wave_amax(bvB0, biB0); wave_amax(bvB1, biB1);
        if (lane == 0) {
            sm.wv[w]    = bvA0; sm.wi[w]    = biA0;
            sm.wv[4+w]  = bvA1; sm.wi[4+w]  = biA1;
            sm.wv[8+w]  = bvB0; sm.wi[8+w]  = biB0;
            sm.wv[12+w] = bvB1; sm.wi[12+w] = biB1;
        }
        __syncthreads();
        if (tid < 4) {
            float v0 = sm.wv[2*tid];   int i0 = sm.wi[2*tid];
            float v1 = sm.wv[2*tid+1]; int i1 = sm.wi[2*tid+1];
            if (v1 > v0 || (v1 == v0 && i1 < i0)) { v0 = v1; i0 = i1; }
            int chunk = tile*4 + tid;
            if (chunk < NCHUNK) {
                segval[((size_t)b*A + aA)*NCP + chunk] = v0;
                segidx[((size_t)b*A + aA)*NCP + chunk] = i0;
            }
        } else if (tid >= 64 && tid < 68) {
            int c = tid - 64;
            float v0 = sm.wv[8+2*c];   int i0 = sm.wi[8+2*c];
            float v1 = sm.wv[8+2*c+1]; int i1 = sm.wi[8+2*c+1];
            if (v1 > v0 || (v1 == v0 && i1 < i0)) { v0 = v1; i0 = i1; }
            int chunk = tile*4 + c;
            if (chunk < NCHUNK) {
                segval[((size_t)b*A + aB)*NCP + chunk] = v0;
                segidx[((size_t)b*A + aB)*NCP + chunk] = i0;
            }
        }
    }
    __syncthreads();
    if (w < 2) {
        int atom = (w == 0) ? aA : aB;
        float bv = -INFINITY; int bi = 0x7fffffff;
        if (lane < NCHUNK) {
            bv = segval[((size_t)b*A + atom)*NCP + lane];
            bi = segidx[((size_t)b*A + atom)*NCP + lane];
        }
        wave_amax(bv, bi);
        if (lane == 0) { abv[b*A + atom] = bv; abi[b*A + atom] = bi; }
    }
}

__device__ void dev_iter(int a0, int b, int tid, int last,
                         const float* __restrict__ avc, const int* __restrict__ aic,
                         float* __restrict__ avn, int* __restrict__ ain,
                         const float* __restrict__ rin, float* __restrict__ rout,
                         float* __restrict__ recon, const float* __restrict__ dn,
                         float* __restrict__ segval, int* __restrict__ segidx, Smem& sm) {
    const int aA = a0*2, aB = a0*2 + 1;
    const int lane = tid & 63, w = tid >> 6;

    float bv0 = avc[b*A + tid]; int bi0 = aic[b*A + tid];
    const float4* rin4 = (const float4*)(rin + (size_t)b*TP);
    const int icopy = a0*256 + tid;
    const bool docopy = (!last) && (icopy < TP/4);
    float4 vcopy = {0.f,0.f,0.f,0.f};
    if (docopy) vcopy = rin4[icopy];
    sm.dnA[tid] = dn[aA*K + tid];
    sm.dnB[tid] = dn[aB*K + tid];

    {
        float bv = bv0; int bi = bi0;
        wave_amax(bv, bi);
        if (lane == 0) { sm.wv[w] = bv; sm.wi[w] = bi; }
        __syncthreads();
        if (tid == 0) {
            bv = sm.wv[0]; bi = sm.wi[0];
            for (int j = 1; j < 4; j++)
                if (sm.wv[j] > bv || (sm.wv[j] == bv && sm.wi[j] < bi)) { bv = sm.wv[j]; bi = sm.wi[j]; }
            sm.fv = bv; sm.fi = bi;
        }
        __syncthreads();
    }
    float val = sm.fv; int idx = sm.fi;
    int atom = idx / TOUT, pos = idx - atom*TOUT;
    sm.dnsel[tid] = dn[atom*K + tid];

    int lo = pos - (K-1); if (lo < 0) lo = 0;
    int c_lo = lo >> 9;
    int tbase = c_lo * CHUNK;

    if (!last) {
        float4* s4 = (float4*)sm.rp;
        for (int i = tid; i < 324; i += 256) {
            int g = tbase/4 + i;
            float4 v = {0.f,0.f,0.f,0.f};
            if (g*4 < TP) v = rin4[g];
            s4[i] = v;
        }
    }
    __syncthreads();
    if (docopy) {
        float4* rout4 = (float4*)(rout + (size_t)b*TP);
        float4 v = vcopy;
        int o = icopy*4 - pos;
        if (o > -4 && o < K) {
            if (o+0 >= 0 && o+0 < K) v.x -= val * sm.dnsel[o+0];
            if (o+1 >= 0 && o+1 < K) v.y -= val * sm.dnsel[o+1];
            if (o+2 >= 0 && o+2 < K) v.z -= val * sm.dnsel[o+2];
            if (o+3 >= 0 && o+3 < K) v.w -= val * sm.dnsel[o+3];
        }
        rout4[icopy] = v;
    }
    if (a0 == 0) {
        recon[(size_t)b*TP + pos + tid] += val * sm.dnsel[tid];
    }
    if (last) return;

    sm.rp[pos + tid - tbase] -= val * sm.dnsel[tid];
    __syncthreads();

    const float4* srp4 = (const float4*)sm.rp;
    const float4* dA4  = (const float4*)sm.dnA;
    const float4* dB4  = (const float4*)sm.dnB;
    float cA[4] = {0,0,0,0}, cB[4] = {0,0,0,0};
    float4 p = srp4[tid];
    #pragma unroll 4
    for (int kq = 0; kq < 64; kq++) {
        float4 dA = dA4[kq];
        float4 dB = dB4[kq];
        float4 pn = srp4[tid + kq + 1];
        TAP(cA[0], p.x,p.y,p.z,p.w, dA); TAP(cA[1], p.y,p.z,p.w,pn.x, dA);
        TAP(cA[2], p.z,p.w,pn.x,pn.y, dA); TAP(cA[3], p.w,pn.x,pn.y,pn.z, dA);
        TAP(cB[0], p.x,p.y,p.z,p.w, dB); TAP(cB[1], p.y,p.z,p.w,pn.x, dB);
        TAP(cB[2], p.z,p.w,pn.x,pn.y, dB); TAP(cB[3], p.w,pn.x,pn.y,pn.z, dB);
        p = pn;
    }
    int lt = tid * 4;
    float bvA = -INFINITY, bvB = -INFINITY;
    int biA = 0x7fffffff, biB = 0x7fffffff;
    #pragma unroll
    for (int j = 0; j < 4; j++) {
        int t = tbase + lt + j;
        if (t < TOUT) {
            if (cA[j] > bvA) { bvA = cA[j]; biA = aA*TOUT + t; }
            if (cB[j] > bvB) { bvB = cB[j]; biB = aB*TOUT + t; }
        }
    }
    wave_amax(bvA, biA); wave_amax(bvB, biB);
    if (lane == 0) { sm.wv[w] = bvA; sm.wi[w] = biA; sm.wv[8+w] = bvB; sm.wi[8+w] = biB; }
    __syncthreads();
    if (tid < 2) {
        float v0 = sm.wv[2*tid];   int i0 = sm.wi[2*tid];
        float v1 = sm.wv[2*tid+1]; int i1 = sm.wi[2*tid+1];
        if (v1 > v0 || (v1 == v0 && i1 < i0)) { v0 = v1; i0 = i1; }
        int chunk = c_lo + tid;
        if (chunk < NCHUNK) {
            segval[((size_t)b*A + aA)*NCP + chunk] = v0;
            segidx[((size_t)b*A + aA)*NCP + chunk] = i0;
        }
    } else if (tid >= 64 && tid < 66) {
        int c = tid - 64;
        float v0 = sm.wv[8+2*c];   int i0 = sm.wi[8+2*c];
        float v1 = sm.wv[8+2*c+1]; int i1 = sm.wi[8+2*c+1];
        if (v1 > v0 || (v1 == v0 && i1 < i0)) { v0 = v1; i0 = i1; }
        int chunk = c_lo + c;
        if (chunk < NCHUNK) {
            segval[((size_t)b*A + aB)*NCP + chunk] = v0;
            segidx[((size_t)b*A + aB)*NCP + chunk] = i0;
        }
    }
    __syncthreads();
    if (w < 2) {
        int at = (w == 0) ? aA : aB;
        float bv = -INFINITY; int bi = 0x7fffffff;
        if (lane < NCHUNK) {
            bv = segval[((size_t)b*A + at)*NCP + lane];
            bi = segidx[((size_t)b*A + at)*NCP + lane];
        }
        wave_amax(bv, bi);
        if (lane == 0) { avn[b*A + at] = bv; ain[b*A + at] = bi; }
    }
}

__global__ void __launch_bounds__(256) k_f_norm_init(const float* x, const float* d,
                                                     float* dn, float* rp0, float* recon) {
    __shared__ Smem sm;
    dev_norm(blockIdx.x & 127, threadIdx.x, d, dn, sm);
    dev_init(blockIdx.x & 127, blockIdx.x >> 7, threadIdx.x, x, rp0, recon);
}
__global__ void __launch_bounds__(256, 2) k_f_conv(const float* rp, const float* dn,
                                                   float* segval, int* segidx,
                                                   float* abv, int* abi) {
    __shared__ Smem sm;
    dev_conv(blockIdx.x & 127, blockIdx.x >> 7, threadIdx.x, rp, dn, segval, segidx, abv, abi, sm);
}
__global__ void __launch_bounds__(256, 2) k_f_iter(int last,
                                                   const float* avc, const int* aic,
                                                   float* avn, int* ain,
                                                   const float* rin, float* rout,
                                                   float* recon, const float* dn,
                                                   float* segval, int* segidx) {
    __shared__ Smem sm;
    dev_iter(blockIdx.x & 127, blockIdx.x >> 7, threadIdx.x, last,
             avc, aic, avn, ain, rin, rout, recon, dn, segval, segidx, sm);
}
__global__ void k_f_out(const float* recon, float* out) {
    int i = blockIdx.x * blockDim.x + threadIdx.x;
    if (i >= B*T) return;
    int b = i / T, t = i - b*T;
    out[i] = recon[(size_t)b*TP + PAD + t];
}

extern "C" void kernel_launch(void* const* d_in, const int* in_sizes, int n_in,
                              void* d_out, int out_size, void* d_ws, size_t ws_size,
                              hipStream_t stream) {
    const float* x = (const float*)d_in[0];
    const float* d = (const float*)d_in[1];
    float* out = (float*)d_out;

    float* ws     = (float*)d_ws;
    float* dn     = ws;                                   // A*K
    float* rp0    = dn  + (size_t)A*K;                    // B*TP (fallback)
    float* rp1    = rp0 + (size_t)B*TP;                   // B*TP (fallback)
    float* recon  = rp1 + (size_t)B*TP;                   // B*TP (fallback)
    float* segval = recon + (size_t)B*TP;                 // B*A*NCP (fallback)
    int*   segidx = (int*)(segval + (size_t)B*A*NCP);     // B*A*NCP (fallback)
    float* abv0   = (float*)(segidx + (size_t)B*A*NCP);   // B*2*A (fallback exchange)
    float* abv1   = abv0 + (size_t)B*2*A;
    int*   abi0   = (int*)(abv1 + (size_t)B*2*A);
    int*   abi1   = abi0 + (size_t)B*2*A;
    unsigned* bar = (unsigned*)(abi1 + (size_t)B*2*A);    // B x NGRP split counters
    u64*  slots   = (u64*)(bar + (size_t)B*BARSTRIDE);    // B x 2 x BPB2 packed slots

    // Coop-path feasibility: 512 co-resident blocks at DLDS dynamic LDS
    // (2 blocks/CU). Host queries only.
    (void)hipFuncSetAttribute((const void*)k_coop,
                              hipFuncAttributeMaxDynamicSharedMemorySize, DLDS);
    int nb = 0, ncu = 0;
    hipError_t e1 = hipOccupancyMaxActiveBlocksPerMultiprocessor(&nb, (const void*)k_coop,
                                                                 256, DLDS);
    hipError_t e2 = hipDeviceGetAttribute(&ncu, hipDeviceAttributeMultiprocessorCount, 0);
    bool coop = (e1 == hipSuccess && e2 == hipSuccess && nb > 0 && ncu > 0 &&
                 (long)nb * ncu >= NBLK);
    if (coop) {
        (void)hipMemsetAsync(bar, 0, B*BARSTRIDE*sizeof(unsigned), stream);
        (void)hipMemsetAsync(slots, 0xFF, (size_t)B*2*BPB2*sizeof(u64), stream);  // gen=255 sentinel
        hipLaunchKernelGGL(k_coop, dim3(NBLK), dim3(256), DLDS, stream,
                           x, d, out, dn, slots, bar);
        return;
    }
    // fallback: separate launches, double-buffered (race-free)
    k_f_norm_init<<<NBLK, 256, 0, stream>>>(x, d, dn, rp0, recon);
    k_f_conv<<<NBLK, 256, 0, stream>>>(rp0, dn, segval, segidx, abv0, abi0);
    float* rbuf[2] = {rp0, rp1};
    float* av[2]   = {abv0, abv1};
    int*   ai[2]   = {abi0, abi1};
    for (int it = 0; it < ITERS; it++) {
        k_f_iter<<<NBLK, 256, 0, stream>>>(it == ITERS-1 ? 1 : 0,
                                           av[it & 1], ai[it & 1],
                                           av[(it + 1) & 1], ai[(it + 1) & 1],
                                           rbuf[it & 1], rbuf[(it + 1) & 1],
                                           recon, dn, segval, segidx);
    }
    k_f_out<<<(B*T + 255)/256, 256, 0, stream>>>(recon, out);
}

// Round 12
// 516.951 us; speedup vs baseline: 1.3713x; 1.0002x over previous
//
#include <hip/hip_runtime.h>
#include <math.h>

#define B    4
#define T    16384
#define A    256
#define K    256
#define PAD  128
#define TP   (T + 2*PAD)      // 16640
#define TOUT (TP - K + 1)     // 16385
#define ITERS 16
#define CHUNK 512
#define NCHUNK 33
#define NCP  36               // (fallback) padded per-atom chunk stride
#define TILE 2048
#define NTILE 9
#define NBLK 512              // grid (both paths)
#define BPB2 128              // blocks per batch (coop path)
#define HBASE 8192            // half split point (outputs & rp base)
#define RPSTORE 8448          // stored rp floats per block (8192 + 256 overlap)
#define RPN 8704              // LDS rp floats incl. zero pad for masked over-reads
#define NGRP 8                // groups of 16 blocks (umax slot + counter each)
#define SUBSTRIDE 32          // uints between counters (128 B line each)
#define BARSTRIDE (NGRP*SUBSTRIDE)  // uints per batch counter region
#define GSTRIDE 16            // u64s between group umax slots (128 B line each)
#define GPAR (NGRP*GSTRIDE)   // u64s per parity region (per batch)
#define DLDS 40960            // dynamic LDS request -> 2 blocks/CU (80KB/CU)

#define TAP(acc, s0,s1,s2,s3, dq) { acc = fmaf(s0,(dq).x,acc); acc = fmaf(s1,(dq).y,acc); \
                                    acc = fmaf(s2,(dq).z,acc); acc = fmaf(s3,(dq).w,acc); }

typedef unsigned long long u64;

__device__ __forceinline__ void wave_amax(float& bv, int& bi) {
    #pragma unroll
    for (int off = 32; off; off >>= 1) {
        float ov = __shfl_down(bv, off);
        int   oi = __shfl_down(bi, off);
        if (ov > bv || (ov == bv && oi < bi)) { bv = ov; bi = oi; }
    }
}

// ===================== LDS-resident HALVES path, atomic-max exchange =====================
// R9-R11 lesson: sync FLAVOR is irrelevant (517-541 across 3 designs); the
// hidden per-iter cost is the pick's 128 PER-LANE ATOMIC LOADS per block
// (65K uncoalesced coherence-point transactions per iteration ~= 15-25us of
// per-line queueing). R12: merge block bests via packed-u64 atomic_umax into
// 8 per-batch group slots; pick = poll 8 counters + read 8 slots. Atomic ops
// per block-iter: ~130 -> ~18.
// Packing: [gen:9][sortable-val:32][0x7FFFFF-idx:23]; gen in the top bits
// makes stale-gen entries lose automatically (no resets); parity-doubled
// slots prevent overwrite-before-read (writing gen+2 into a parity requires
// every block consumed gen -- same proof as R11).
struct KSmem {
    float  rp[RPN];           // 34816 B ([8448..8704) zero pad, never written)
    float4 dn4[4][64];        // own 4 atoms' taps, 4096 B
    float  chv[4][34];        // per-atom chunk maxima (global chunk ids)
    int    chi[4][34];
    float  wv[16]; int wi[16];
    float  fv; int fi;
};

// Split-counter per-batch barrier -- used ONCE (dn publication fence), own
// counter region (separate from the pick counters).
__device__ __forceinline__ void gbar_sub(unsigned* sub, int r, unsigned gen16, int tid) {
    __syncthreads();
    if (tid == 0)
        __hip_atomic_fetch_add(&sub[(r >> 4)*SUBSTRIDE], 1u,
                               __ATOMIC_RELEASE, __HIP_MEMORY_SCOPE_AGENT);
    if (tid < 64) {
        for (;;) {
            unsigned ok = 1;
            if (tid < NGRP)
                ok = (__hip_atomic_load(&sub[tid*SUBSTRIDE], __ATOMIC_RELAXED,
                                        __HIP_MEMORY_SCOPE_AGENT) >= gen16);
            if (__all((int)ok)) break;
            __builtin_amdgcn_s_sleep(4);
        }
    }
    __syncthreads();
    __builtin_amdgcn_fence(__ATOMIC_ACQUIRE, "agent");
}

// Compute conv outputs for up to two 512-chunks (cA -> threads 0..127,
// cB -> threads 128..255; -1 = inactive) for the block's 4 atoms, from LDS rp.
// REPLACES chv/chi entries for the valid chunks. Chunk ids are GLOBAL (0..32).
__device__ void chunks_update(KSmem& sm, int baseF, int cA, int cB, int aBase, int tid) {
    const int lane = tid & 63, w = tid >> 6;
    const int grp = tid >> 7;
    const int cg = grp ? cB : cA;
    const int lt = cg*512 + (tid & 127)*4;    // global output t (j=0); cg>=0 only
    float c0[4] = {0,0,0,0}, c1[4] = {0,0,0,0}, c2[4] = {0,0,0,0}, c3[4] = {0,0,0,0};
    if (cg >= 0) {
        const float4* srp4 = (const float4*)sm.rp;
        int ol4 = (lt - baseF) >> 2;
        float4 p = srp4[ol4];
        #pragma unroll 4
        for (int kq = 0; kq < 64; kq++) {
            float4 d0 = sm.dn4[0][kq];
            float4 d1 = sm.dn4[1][kq];
            float4 d2 = sm.dn4[2][kq];
            float4 d3 = sm.dn4[3][kq];
            float4 pn = srp4[ol4 + kq + 1];
            TAP(c0[0], p.x,p.y,p.z,p.w, d0); TAP(c0[1], p.y,p.z,p.w,pn.x, d0);
            TAP(c0[2], p.z,p.w,pn.x,pn.y, d0); TAP(c0[3], p.w,pn.x,pn.y,pn.z, d0);
            TAP(c1[0], p.x,p.y,p.z,p.w, d1); TAP(c1[1], p.y,p.z,p.w,pn.x, d1);
            TAP(c1[2], p.z,p.w,pn.x,pn.y, d1); TAP(c1[3], p.w,pn.x,pn.y,pn.z, d1);
            TAP(c2[0], p.x,p.y,p.z,p.w, d2); TAP(c2[1], p.y,p.z,p.w,pn.x, d2);
            TAP(c2[2], p.z,p.w,pn.x,pn.y, d2); TAP(c2[3], p.w,pn.x,pn.y,pn.z, d2);
            TAP(c3[0], p.x,p.y,p.z,p.w, d3); TAP(c3[1], p.y,p.z,p.w,pn.x, d3);
            TAP(c3[2], p.z,p.w,pn.x,pn.y, d3); TAP(c3[3], p.w,pn.x,pn.y,pn.z, d3);
            p = pn;
        }
    }
    float bv0 = -INFINITY, bv1 = -INFINITY, bv2 = -INFINITY, bv3 = -INFINITY;
    int bi0 = 0x7fffffff, bi1 = 0x7fffffff, bi2 = 0x7fffffff, bi3 = 0x7fffffff;
    if (cg >= 0) {
        #pragma unroll
        for (int j = 0; j < 4; j++) {
            int t = lt + j;
            if (t < TOUT) {
                if (c0[j] > bv0) { bv0 = c0[j]; bi0 = (aBase+0)*TOUT + t; }
                if (c1[j] > bv1) { bv1 = c1[j]; bi1 = (aBase+1)*TOUT + t; }
                if (c2[j] > bv2) { bv2 = c2[j]; bi2 = (aBase+2)*TOUT + t; }
                if (c3[j] > bv3) { bv3 = c3[j]; bi3 = (aBase+3)*TOUT + t; }
            }
        }
    }
    wave_amax(bv0, bi0); wave_amax(bv1, bi1); wave_amax(bv2, bi2); wave_amax(bv3, bi3);
    if (lane == 0) {
        sm.wv[0*4+w] = bv0; sm.wi[0*4+w] = bi0;
        sm.wv[1*4+w] = bv1; sm.wi[1*4+w] = bi1;
        sm.wv[2*4+w] = bv2; sm.wi[2*4+w] = bi2;
        sm.wv[3*4+w] = bv3; sm.wi[3*4+w] = bi3;
    }
    __syncthreads();
    // combine wave pairs: waves {0,1} -> cA, {2,3} -> cB
    if (tid < 8) {
        int a = tid >> 1, hh = tid & 1;
        int chunk = hh ? cB : cA;
        if (chunk >= 0) {
            float v0 = sm.wv[a*4 + 2*hh];   int i0 = sm.wi[a*4 + 2*hh];
            float v1 = sm.wv[a*4 + 2*hh+1]; int i1 = sm.wi[a*4 + 2*hh+1];
            if (v1 > v0 || (v1 == v0 && i1 < i0)) { v0 = v1; i0 = i1; }
            sm.chv[a][chunk] = v0; sm.chi[a][chunk] = i0;
        }
    }
    __syncthreads();
}

// Block best over 4 atoms x own chunk range -> ONE atomic_umax merge + one
// arrival add (vmcnt-ordered so the umax is globally performed before the
// counter increment is observable).
__device__ __forceinline__ void publish(KSmem& sm, u64* gslot, unsigned* gcnt,
                                        int gen, int h, int tid) {
    const int lane = tid & 63, w = tid >> 6;  // wave w -> atom w
    int cstart = h ? 16 : 0, nch = h ? 17 : 16;
    float bv = -INFINITY; int bi = 0x7fffffff;
    if (lane < nch) { bv = sm.chv[w][cstart + lane]; bi = sm.chi[w][cstart + lane]; }
    wave_amax(bv, bi);
    if (lane == 0) { sm.wv[8+w] = bv; sm.wi[8+w] = bi; }
    __syncthreads();
    if (tid == 0) {
        float v = sm.wv[8]; int i = sm.wi[8];
        #pragma unroll
        for (int j = 1; j < 4; j++)
            if (sm.wv[8+j] > v || (sm.wv[8+j] == v && sm.wi[8+j] < i)) { v = sm.wv[8+j]; i = sm.wi[8+j]; }
        unsigned s = __float_as_uint(v);
        unsigned key = (s & 0x80000000u) ? ~s : (s | 0x80000000u);   // sortable float
        u64 e = ((u64)(unsigned)gen << 55) | ((u64)key << 23)
              | (u64)(unsigned)(0x7FFFFF - i);                        // tie -> min idx
        __hip_atomic_fetch_max(gslot, e, __ATOMIC_RELAXED, __HIP_MEMORY_SCOPE_AGENT);
        asm volatile("s_waitcnt vmcnt(0)" ::: "memory");              // umax performed
        __hip_atomic_fetch_add(gcnt, 1u, __ATOMIC_RELAXED, __HIP_MEMORY_SCOPE_AGENT);
    }
}

// Pick: lanes 0-7 poll the 8 group counters (>= gen*16), then read the 8
// parity slots (tag == gen guaranteed stable until this block proceeds),
// 8-lane u64 max reduce, unpack, broadcast. ~18 atomic ops per block total.
__device__ __forceinline__ void pick(KSmem& sm, const u64* gparity,
                                     const unsigned* cntb, int gen, int tid) {
    const int lane = tid & 63;
    if (tid < 64) {
        for (;;) {
            unsigned ok = 1;
            if (lane < NGRP)
                ok = (__hip_atomic_load(&cntb[lane*SUBSTRIDE], __ATOMIC_RELAXED,
                                        __HIP_MEMORY_SCOPE_AGENT) >= (unsigned)gen*16u);
            if (__all((int)ok)) break;
            __builtin_amdgcn_s_sleep(2);
        }
        u64 e = 0;
        if (lane < NGRP) {
            const u64* p = gparity + lane*GSTRIDE;
            for (;;) {
                e = __hip_atomic_load(p, __ATOMIC_RELAXED, __HIP_MEMORY_SCOPE_AGENT);
                if ((unsigned)(e >> 55) == (unsigned)gen) break;
                __builtin_amdgcn_s_sleep(1);
            }
        }
        #pragma unroll
        for (int off = 4; off; off >>= 1) {
            u64 o = __shfl_down(e, off);
            if (lane < NGRP && o > e) e = o;   // tags equal -> plain u64 order works
        }
        if (lane == 0) {
            unsigned key = (unsigned)((e >> 23) & 0xFFFFFFFFull);
            unsigned s = (key & 0x80000000u) ? (key ^ 0x80000000u) : ~key;
            sm.fv = __uint_as_float(s);
            sm.fi = 0x7FFFFF - (int)(e & 0x7FFFFF);
        }
    }
    __syncthreads();
}

__global__ void __launch_bounds__(256, 2)
k_coop(const float* __restrict__ x, const float* __restrict__ d, float* __restrict__ out,
       float* __restrict__ dn, u64* __restrict__ gmax,
       unsigned* __restrict__ cnt, unsigned* __restrict__ fbar) {
    extern __shared__ char raw[];
    KSmem& sm = *(KSmem*)raw;
    const int bid = blockIdx.x, tid = threadIdx.x;
    const int b = bid >> 7, r = bid & 127;
    const int h = r >> 6, a0 = r & 63;       // half, atom-group (4 atoms)
    const int lane = tid & 63, w = tid >> 6;
    const int baseF = h * HBASE;
    const int cstart = h ? 16 : 0, cend = h ? 33 : 16;
    const int grp = r >> 4;                  // 8 groups of 16 blocks
    u64* gmaxb = gmax + (size_t)b*2*GPAR;    // [parity][NGRP*GSTRIDE]
    unsigned* cntb = cnt + b*BARSTRIDE;
    unsigned* fbarb = fbar + b*BARSTRIDE;

    // ---- init: x -> LDS rp window (padded domain), zero tail ----
    {
        const float4* x4 = (const float4*)(x + (size_t)b*T);
        float4* rp4w = (float4*)sm.rp;
        int b4 = baseF >> 2;
        for (int i = tid; i < RPN/4; i += 256) {
            int g4 = b4 + i;
            float4 v = {0.f,0.f,0.f,0.f};
            if (i < RPSTORE/4 && g4 >= PAD/4 && g4 < (PAD+T)/4) v = x4[g4 - PAD/4];
            rp4w[i] = v;
        }
    }
    // ---- normalize own 4 atoms into LDS + global dn (redundant identical writes;
    //      published by the one full-fence barrier below) ----
    #pragma unroll
    for (int s = 0; s < 4; s++) {
        int atom = a0*4 + s;
        float v = d[atom*K + tid];
        float sq = v*v;
        #pragma unroll
        for (int off = 32; off; off >>= 1) sq += __shfl_down(sq, off);
        if (lane == 0) sm.wv[w] = sq;
        __syncthreads();
        float norm = sqrtf(sm.wv[0] + sm.wv[1] + sm.wv[2] + sm.wv[3]) + 1e-12f;
        float nv = v / norm;
        ((float*)&sm.dn4[s][0])[tid] = nv;
        dn[atom*K + tid] = nv;
        __syncthreads();
    }
    // ---- initial conv over own half (8 or 9 chunk-pair passes) ----
    {
        int npass = h ? 9 : 8;
        for (int p = 0; p < npass; p++) {
            int ca = cstart + 2*p;
            int cb2 = (ca + 1 < cend) ? ca + 1 : -1;
            chunks_update(sm, baseF, ca, cb2, a0*4, tid);
        }
    }
    int gen = 1;
    publish(sm, gmaxb + (gen&1)*GPAR + grp*GSTRIDE, cntb + grp*SUBSTRIDE, gen, h, tid);
    gbar_sub(fbarb, r, 16u, tid);            // the ONLY full-fence barrier (dn)

    for (int it = 0; it < ITERS-1; it++) {
        pick(sm, gmaxb + (gen&1)*GPAR, cntb, gen, tid);
        float val = sm.fv; int idx = sm.fi;
        int atom = idx / TOUT, pos = idx - atom*TOUT;
        float ds = dn[atom*K + tid];            // plain load, L2-hot (dn immutable)
        int li = pos + tid - baseF;             // local residual update (if in range)
        if (li >= 0 && li < RPSTORE) sm.rp[li] -= val * ds;
        __syncthreads();
        int lo = pos - (K-1); if (lo < 0) lo = 0;
        int g0 = lo >> 9, g1 = g0 + 1;          // the 2 affected global chunks
        bool in0 = (g0 >= cstart && g0 < cend);
        bool in1 = (g1 >= cstart && g1 < cend);
        int ca = in0 ? g0 : (in1 ? g1 : -1);
        int cb2 = (in0 && in1) ? g1 : -1;
        if (ca >= 0) chunks_update(sm, baseF, ca, cb2, a0*4, tid);
        publish(sm, gmaxb + ((gen+1)&1)*GPAR + grp*GSTRIDE, cntb + grp*SUBSTRIDE,
                gen+1, h, tid);
        gen++;
        // no separate barrier: next pick's counter/tag checks ARE the sync
    }
    // ---- final pick + update + out (one writer block per (batch, half)) ----
    if (a0 == 0) {
        pick(sm, gmaxb + (gen&1)*GPAR, cntb, gen, tid);
        float val = sm.fv; int idx = sm.fi;
        int atom = idx / TOUT, pos = idx - atom*TOUT;
        float ds = dn[atom*K + tid];
        int li = pos + tid - baseF;
        if (li >= 0 && li < RPSTORE) sm.rp[li] -= val * ds;
        __syncthreads();
        // out[b][o] = x[b][o] - rp[o+PAD]; h=0 covers o in [0,8064), h=1 [8064,16384)
        int o_lo4 = h ? (HBASE - PAD)/4 : 0;
        int o_hi4 = h ? T/4 : (HBASE - PAD)/4;
        const float4* xb4 = (const float4*)(x + (size_t)b*T);
        float4* o4 = (float4*)(out + (size_t)b*T);
        for (int i4 = o_lo4 + tid; i4 < o_hi4; i4 += 256) {
            float4 xv = xb4[i4];
            float4 rv = *(const float4*)&sm.rp[i4*4 + PAD - baseF];
            float4 ov; ov.x = xv.x - rv.x; ov.y = xv.y - rv.y;
            ov.z = xv.z - rv.z; ov.w = xv.w - rv.w;
            o4[i4] = ov;
        }
    }
}

// ===================== fallback path (R6, race-free, unchanged) =====================
struct Smem {
    float rp[TILE + K + 16];
    float dnA[K];
    float dnB[K];
    float dnsel[K];
    float wv[16]; int wi[16];
    float fv; int fi;
};

__device__ __forceinline__ void dev_norm(int a0, int tid, const float* __restrict__ d,
                                         float* __restrict__ dn, Smem& sm) {
    int lane = tid & 63, w = tid >> 6;
    #pragma unroll
    for (int s = 0; s < 2; s++) {
        int atom = a0*2 + s;
        float v = d[atom*K + tid];
        float sq = v*v;
        #pragma unroll
        for (int off = 32; off; off >>= 1) sq += __shfl_down(sq, off);
        if (lane == 0) sm.wv[w] = sq;
        __syncthreads();
        float norm = sqrtf(sm.wv[0] + sm.wv[1] + sm.wv[2] + sm.wv[3]) + 1e-12f;
        dn[atom*K + tid] = v / norm;
        __syncthreads();
    }
}

__device__ __forceinline__ void dev_init(int a0, int b, int tid, const float* __restrict__ x,
                                         float* __restrict__ rp, float* __restrict__ recon) {
    int i = a0*256 + tid;
    if (i < TP) {
        float v = (i >= PAD && i < PAD + T) ? x[b*T + (i - PAD)] : 0.f;
        rp[(size_t)b*TP + i] = v;
        recon[(size_t)b*TP + i] = 0.f;
    }
}

__device__ void dev_conv(int a0, int b, int tid, const float* __restrict__ rp,
                         const float* __restrict__ dn,
                         float* __restrict__ segval, int* __restrict__ segidx,
                         float* __restrict__ abv, int* __restrict__ abi, Smem& sm) {
    const int aA = a0*2, aB = a0*2 + 1;
    const int lane = tid & 63, w = tid >> 6;
    sm.dnA[tid] = dn[aA*K + tid];
    sm.dnB[tid] = dn[aB*K + tid];
    const float4* rp4 = (const float4*)(rp + (size_t)b*TP);

    for (int tile = 0; tile < NTILE; tile++) {
        int t0 = tile * TILE;
        __syncthreads();
        float4* s4 = (float4*)sm.rp;
        for (int i = tid; i < 580; i += 256) {
            int g = t0/4 + i;
            float4 v = {0.f,0.f,0.f,0.f};
            if (g*4 < TP) v = rp4[g];
            s4[i] = v;
        }
        __syncthreads();
        const float4* srp4 = (const float4*)sm.rp;
        const float4* dA4  = (const float4*)sm.dnA;
        const float4* dB4  = (const float4*)sm.dnB;
        float accA0[4] = {0,0,0,0}, accA1[4] = {0,0,0,0};
        float accB0[4] = {0,0,0,0}, accB1[4] = {0,0,0,0};
        float4 p = srp4[tid];
        float4 q = srp4[tid + 256];
        #pragma unroll 4
        for (int kq = 0; kq < 64; kq++) {
            float4 dA = dA4[kq];
            float4 dB = dB4[kq];
            float4 pn = srp4[tid + kq + 1];
            float4 qn = srp4[tid + 256 + kq + 1];
            TAP(accA0[0], p.x,p.y,p.z,p.w, dA); TAP(accA0[1], p.y,p.z,p.w,pn.x, dA);
            TAP(accA0[2], p.z,p.w,pn.x,pn.y, dA); TAP(accA0[3], p.w,pn.x,pn.y,pn.z, dA);
            TAP(accB0[0], p.x,p.y,p.z,p.w, dB); TAP(accB0[1], p.y,p.z,p.w,pn.x, dB);
            TAP(accB0[2], p.z,p.w,pn.x,pn.y, dB); TAP(accB0[3], p.w,pn.x,pn.y,pn.z, dB);
            TAP(accA1[0], q.x,q.y,q.z,q.w, dA); TAP(accA1[1], q.y,q.z,q.w,qn.x, dA);
            TAP(accA1[2], q.z,q.w,qn.x,qn.y, dA); TAP(accA1[3], q.w,qn.x,qn.y,qn.z, dA);
            TAP(accB1[0], q.x,q.y,q.z,q.w, dB); TAP(accB1[1], q.y,q.z,q.w,qn.x, dB);
            TAP(accB1[2], q.z,q.w,qn.x,qn.y, dB); TAP(accB1[3], q.w,qn.x,qn.y,qn.z, dB);
            p = pn; q = qn;
        }
        int lt = tid * 4;
        float bvA0 = -INFINITY, bvA1 = -INFINITY, bvB0 = -INFINITY, bvB1 = -INFINITY;
        int biA0 = 0x7fffffff, biA1 = 0x7fffffff, biB0 = 0x7fffffff, biB1 = 0x7fffffff;
        #pragma unroll
        for (int j = 0; j < 4; j++) {
            int t = t0 + lt + j;
            if (t < TOUT) {
                if (accA0[j] > bvA0) { bvA0 = accA0[j]; biA0 = aA*TOUT + t; }
                if (accB0[j] > bvB0) { bvB0 = accB0[j]; biB0 = aB*TOUT + t; }
            }
            int t1 = t0 + 1024 + lt + j;
            if (t1 < TOUT) {
                if (accA1[j] > bvA1) { bvA1 = accA1[j]; biA1 = aA*TOUT + t1; }
                if (accB1[j] > bvB1) { bvB1 = accB1[j]; biB1 = aB*TOUT + t1; }
            }
        }
        wave_amax(bvA0, biA0); wave_amax(bvA1, biA1);
        wave_amax(bvB0, biB0); wave_amax(bvB1, biB1);
        if (lane == 0) {
            sm.wv[w]    = bvA0; sm.wi[w]    = biA0;
            sm.wv[4+w]  = bvA1; sm.wi[4+w]  = biA1;
            sm.wv[8+w]  = bvB0; sm.wi[8+w]  = biB0;
            sm.wv[12+w] = bvB1; sm.wi[12+w] = biB1;
        }
        __syncthreads();
        if (tid < 4) {
            float v0 = sm.wv[2*tid];   int i0 = sm.wi[2*tid];
            float v1 = sm.wv[2*tid+1]; int i1 = sm.wi[2*tid+1];
            if (v1 > v0 || (v1 == v0 && i1 < i0)) { v0 = v1; i0 = i1; }
            int chunk = tile*4 + tid;
            if (chunk < NCHUNK) {
                segval[((size_t)b*A + aA)*NCP + chunk] = v0;
                segidx[((size_t)b*A + aA)*NCP + chunk] = i0;
            }
        } else if (tid >= 64 && tid < 68) {
            int c = tid - 64;
            float v0 = sm.wv[8+2*c];   int i0 = sm.wi[8+2*c];
            float v1 = sm.wv[8+2*c+1]; int i1 = sm.wi[8+2*c+1];
            if (v1 > v0 || (v1 == v0 && i1 < i0)) { v0 = v1; i0 = i1; }
            int chunk = tile*4 + c;
            if (chunk < NCHUNK) {
                segval[((size_t)b*A + aB)*NCP + chunk] = v0;
                segidx[((size_t)b*A + aB)*NCP + chunk] = i0;
            }
        }
    }
    __syncthreads();
    if (w < 2) {
        int atom = (w == 0) ? aA : aB;
        float bv = -INFINITY; int bi = 0x7fffffff;
        if (lane < NCHUNK) {
            bv = segval[((size_t)b*A + atom)*NCP + lane];
            bi = segidx[((size_t)b*A + atom)*NCP + lane];
        }
        wave_amax(bv, bi);
        if (lane == 0) { abv[b*A + atom] = bv; abi[b*A + atom] = bi; }
    }
}

__device__ void dev_iter(int a0, int b, int tid, int last,
                         const float* __restrict__ avc, const int* __restrict__ aic,
                         float* __restrict__ avn, int* __restrict__ ain,
                         const float* __restrict__ rin, float* __restrict__ rout,
                         float* __restrict__ recon, const float* __restrict__ dn,
                         float* __restrict__ segval, int* __restrict__ segidx, Smem& sm) {
    const int aA = a0*2, aB = a0*2 + 1;
    const int lane = tid & 63, w = tid >> 6;

    float bv0 = avc[b*A + tid]; int bi0 = aic[b*A + tid];
    const float4* rin4 = (const float4*)(rin + (size_t)b*TP);
    const int icopy = a0*256 + tid;
    const bool docopy = (!last) && (icopy < TP/4);
    float4 vcopy = {0.f,0.f,0.f,0.f};
    if (docopy) vcopy = rin4[icopy];
    sm.dnA[tid] = dn[aA*K + tid];
    sm.dnB[tid] = dn[aB*K + tid];

    {
        float bv = bv0; int bi = bi0;
        wave_amax(bv, bi);
        if (lane == 0) { sm.wv[w] = bv; sm.wi[w] = bi; }
        __syncthreads();
        if (tid == 0) {
            bv = sm.wv[0]; bi = sm.wi[0];
            for (int j = 1; j < 4; j++)
                if (sm.wv[j] > bv || (sm.wv[j] == bv && sm.wi[j] < bi)) { bv = sm.wv[j]; bi = sm.wi[j]; }
            sm.fv = bv; sm.fi = bi;
        }
        __syncthreads();
    }
    float val = sm.fv; int idx = sm.fi;
    int atom = idx / TOUT, pos = idx - atom*TOUT;
    sm.dnsel[tid] = dn[atom*K + tid];

    int lo = pos - (K-1); if (lo < 0) lo = 0;
    int c_lo = lo >> 9;
    int tbase = c_lo * CHUNK;

    if (!last) {
        float4* s4 = (float4*)sm.rp;
        for (int i = tid; i < 324; i += 256) {
            int g = tbase/4 + i;
            float4 v = {0.f,0.f,0.f,0.f};
            if (g*4 < TP) v = rin4[g];
            s4[i] = v;
        }
    }
    __syncthreads();
    if (docopy) {
        float4* rout4 = (float4*)(rout + (size_t)b*TP);
        float4 v = vcopy;
        int o = icopy*4 - pos;
        if (o > -4 && o < K) {
            if (o+0 >= 0 && o+0 < K) v.x -= val * sm.dnsel[o+0];
            if (o+1 >= 0 && o+1 < K) v.y -= val * sm.dnsel[o+1];
            if (o+2 >= 0 && o+2 < K) v.z -= val * sm.dnsel[o+2];
            if (o+3 >= 0 && o+3 < K) v.w -= val * sm.dnsel[o+3];
        }
        rout4[icopy] = v;
    }
    if (a0 == 0) {
        recon[(size_t)b*TP + pos + tid] += val * sm.dnsel[tid];
    }
    if (last) return;

    sm.rp[pos + tid - tbase] -= val * sm.dnsel[tid];
    __syncthreads();

    const float4* srp4 = (const float4*)sm.rp;
    const float4* dA4  = (const float4*)sm.dnA;
    const float4* dB4  = (const float4*)sm.dnB;
    float cA[4] = {0,0,0,0}, cB[4] = {0,0,0,0};
    float4 p = srp4[tid];
    #pragma unroll 4
    for (int kq = 0; kq < 64; kq++) {
        float4 dA = dA4[kq];
        float4 dB = dB4[kq];
        float4 pn = srp4[tid + kq + 1];
        TAP(cA[0], p.x,p.y,p.z,p.w, dA); TAP(cA[1], p.y,p.z,p.w,pn.x, dA);
        TAP(cA[2], p.z,p.w,pn.x,pn.y, dA); TAP(cA[3], p.w,pn.x,pn.y,pn.z, dA);
        TAP(cB[0], p.x,p.y,p.z,p.w, dB); TAP(cB[1], p.y,p.z,p.w,pn.x, dB);
        TAP(cB[2], p.z,p.w,pn.x,pn.y, dB); TAP(cB[3], p.w,pn.x,pn.y,pn.z, dB);
        p = pn;
    }
    int lt = tid * 4;
    float bvA = -INFINITY, bvB = -INFINITY;
    int biA = 0x7fffffff, biB = 0x7fffffff;
    #pragma unroll
    for (int j = 0; j < 4; j++) {
        int t = tbase + lt + j;
        if (t < TOUT) {
            if (cA[j] > bvA) { bvA = cA[j]; biA = aA*TOUT + t; }
            if (cB[j] > bvB) { bvB = cB[j]; biB = aB*TOUT + t; }
        }
    }
    wave_amax(bvA, biA); wave_amax(bvB, biB);
    if (lane == 0) { sm.wv[w] = bvA; sm.wi[w] = biA; sm.wv[8+w] = bvB; sm.wi[8+w] = biB; }
    __syncthreads();
    if (tid < 2) {
        float v0 = sm.wv[2*tid];   int i0 = sm.wi[2*tid];
        float v1 = sm.wv[2*tid+1]; int i1 = sm.wi[2*tid+1];
        if (v1 > v0 || (v1 == v0 && i1 < i0)) { v0 = v1; i0 = i1; }
        int chunk = c_lo + tid;
        if (chunk < NCHUNK) {
            segval[((size_t)b*A + aA)*NCP + chunk] = v0;
            segidx[((size_t)b*A + aA)*NCP + chunk] = i0;
        }
    } else if (tid >= 64 && tid < 66) {
        int c = tid - 64;
        float v0 = sm.wv[8+2*c];   int i0 = sm.wi[8+2*c];
        float v1 = sm.wv[8+2*c+1]; int i1 = sm.wi[8+2*c+1];
        if (v1 > v0 || (v1 == v0 && i1 < i0)) { v0 = v1; i0 = i1; }
        int chunk = c_lo + c;
        if (chunk < NCHUNK) {
            segval[((size_t)b*A + aB)*NCP + chunk] = v0;
            segidx[((size_t)b*A + aB)*NCP + chunk] = i0;
        }
    }
    __syncthreads();
    if (w < 2) {
        int at = (w == 0) ? aA : aB;
        float bv = -INFINITY; int bi = 0x7fffffff;
        if (lane < NCHUNK) {
            bv = segval[((size_t)b*A + at)*NCP + lane];
            bi = segidx[((size_t)b*A + at)*NCP + lane];
        }
        wave_amax(bv, bi);
        if (lane == 0) { avn[b*A + at] = bv; ain[b*A + at] = bi; }
    }
}

__global__ void __launch_bounds__(256) k_f_norm_init(const float* x, const float* d,
                                                     float* dn, float* rp0, float* recon) {
    __shared__ Smem sm;
    dev_norm(blockIdx.x & 127, threadIdx.x, d, dn, sm);
    dev_init(blockIdx.x & 127, blockIdx.x >> 7, threadIdx.x, x, rp0, recon);
}
__global__ void __launch_bounds__(256, 2) k_f_conv(const float* rp, const float* dn,
                                                   float* segval, int* segidx,
                                                   float* abv, int* abi) {
    __shared__ Smem sm;
    dev_conv(blockIdx.x & 127, blockIdx.x >> 7, threadIdx.x, rp, dn, segval, segidx, abv, abi, sm);
}
__global__ void __launch_bounds__(256, 2) k_f_iter(int last,
                                                   const float* avc, const int* aic,
                                                   float* avn, int* ain,
                                                   const float* rin, float* rout,
                                                   float* recon, const float* dn,
                                                   float* segval, int* segidx) {
    __shared__ Smem sm;
    dev_iter(blockIdx.x & 127, blockIdx.x >> 7, threadIdx.x, last,
             avc, aic, avn, ain, rin, rout, recon, dn, segval, segidx, sm);
}
__global__ void k_f_out(const float* recon, float* out) {
    int i = blockIdx.x * blockDim.x + threadIdx.x;
    if (i >= B*T) return;
    int b = i / T, t = i - b*T;
    out[i] = recon[(size_t)b*TP + PAD + t];
}

extern "C" void kernel_launch(void* const* d_in, const int* in_sizes, int n_in,
                              void* d_out, int out_size, void* d_ws, size_t ws_size,
                              hipStream_t stream) {
    const float* x = (const float*)d_in[0];
    const float* d = (const float*)d_in[1];
    float* out = (float*)d_out;

    float* ws     = (float*)d_ws;
    float* dn     = ws;                                   // A*K
    float* rp0    = dn  + (size_t)A*K;                    // B*TP (fallback)
    float* rp1    = rp0 + (size_t)B*TP;                   // B*TP (fallback)
    float* recon  = rp1 + (size_t)B*TP;                   // B*TP (fallback)
    float* segval = recon + (size_t)B*TP;                 // B*A*NCP (fallback)
    int*   segidx = (int*)(segval + (size_t)B*A*NCP);     // B*A*NCP (fallback)
    float* abv0   = (float*)(segidx + (size_t)B*A*NCP);   // B*2*A (fallback exchange)
    float* abv1   = abv0 + (size_t)B*2*A;
    int*   abi0   = (int*)(abv1 + (size_t)B*2*A);
    int*   abi1   = abi0 + (size_t)B*2*A;
    unsigned* cnt = (unsigned*)(abi1 + (size_t)B*2*A);    // B x NGRP pick counters
    unsigned* fbar= cnt + (size_t)B*BARSTRIDE;            // B x NGRP fence counters
    u64*  gmax    = (u64*)(fbar + (size_t)B*BARSTRIDE);   // B x 2 x NGRP umax slots

    // Coop-path feasibility: 512 co-resident blocks at DLDS dynamic LDS
    // (2 blocks/CU). Host queries only.
    (void)hipFuncSetAttribute((const void*)k_coop,
                              hipFuncAttributeMaxDynamicSharedMemorySize, DLDS);
    int nb = 0, ncu = 0;
    hipError_t e1 = hipOccupancyMaxActiveBlocksPerMultiprocessor(&nb, (const void*)k_coop,
                                                                 256, DLDS);
    hipError_t e2 = hipDeviceGetAttribute(&ncu, hipDeviceAttributeMultiprocessorCount, 0);
    bool coop = (e1 == hipSuccess && e2 == hipSuccess && nb > 0 && ncu > 0 &&
                 (long)nb * ncu >= NBLK);
    if (coop) {
        // cnt + fbar + gmax are contiguous: one memset (counters 0, tags 0)
        size_t zbytes = (size_t)B*BARSTRIDE*4*2 + (size_t)B*2*GPAR*8;
        (void)hipMemsetAsync(cnt, 0, zbytes, stream);
        hipLaunchKernelGGL(k_coop, dim3(NBLK), dim3(256), DLDS, stream,
                           x, d, out, dn, gmax, cnt, fbar);
        return;
    }
    // fallback: separate launches, double-buffered (race-free)
    k_f_norm_init<<<NBLK, 256, 0, stream>>>(x, d, dn, rp0, recon);
    k_f_conv<<<NBLK, 256, 0, stream>>>(rp0, dn, segval, segidx, abv0, abi0);
    float* rbuf[2] = {rp0, rp1};
    float* av[2]   = {abv0, abv1};
    int*   ai[2]   = {abi0, abi1};
    for (int it = 0; it < ITERS; it++) {
        k_f_iter<<<NBLK, 256, 0, stream>>>(it == ITERS-1 ? 1 : 0,
                                           av[it & 1], ai[it & 1],
                                           av[(it + 1) & 1], ai[(it + 1) & 1],
                                           rbuf[it & 1], rbuf[(it + 1) & 1],
                                           recon, dn, segval, segidx);
    }
    k_f_out<<<(B*T + 255)/256, 256, 0, stream>>>(recon, out);
}

// Round 13
// 498.767 us; speedup vs baseline: 1.4212x; 1.0365x over previous
//
#include <hip/hip_runtime.h>
#include <math.h>

#define B    4
#define T    16384
#define A    256
#define K    256
#define PAD  128
#define TP   (T + 2*PAD)      // 16640
#define TOUT (TP - K + 1)     // 16385
#define ITERS 16
#define CHUNK 512
#define NCHUNK 33
#define NCP  36               // (fallback) padded per-atom chunk stride
#define TILE 2048
#define NTILE 9
#define NBLK 512              // grid (both paths)
#define BPB2 128              // blocks per batch (coop path)
#define HBASE 8192            // half split point (outputs & rp base)
#define RPSTORE 8448          // stored rp floats per block (8192 + 256 overlap)
#define RPN 8704              // LDS rp floats incl. zero pad for masked over-reads
#define NGRP 8                // fence-barrier split counters / relay replicas
#define SUBSTRIDE 32          // uints between fence counters (128 B line each)
#define BARSTRIDE (NGRP*SUBSTRIDE)  // uints per batch fence region
#define RSTRIDE 16            // u64s between relay replicas (128 B line each)
#define DLDS 40960            // dynamic LDS request -> 2 blocks/CU (80KB/CU)

#define TAP(acc, s0,s1,s2,s3, dq) { acc = fmaf(s0,(dq).x,acc); acc = fmaf(s1,(dq).y,acc); \
                                    acc = fmaf(s2,(dq).z,acc); acc = fmaf(s3,(dq).w,acc); }

typedef unsigned long long u64;

__device__ __forceinline__ void wave_amax(float& bv, int& bi) {
    #pragma unroll
    for (int off = 32; off; off >>= 1) {
        float ov = __shfl_down(bv, off);
        int   oi = __shfl_down(bi, off);
        if (ov > bv || (ov == bv && oi < bi)) { bv = ov; bi = oi; }
    }
}

// ===================== LDS-resident HALVES path, leader-relay exchange =====================
// R9-R12: per-iter sync cost (~25us) was invariant to fences, arrival RMWs,
// and atomic-op COUNT. The shared flaw: ~1000 concurrent pollers on 8-16
// coherence-point lines (10x oversubscribed -> deep queues; publisher stores
// land BEHIND the poll queue). R13 collapses poll concurrency:
//   1. 128 blocks STORE gen-tagged bests to own slots (no polls on slot lines
//      except the leader's).
//   2. ONE leader block per batch polls the 128 slots (its 128 lanes are the
//      only pollers there), u64-max reduces, writes winner to 8 relay lines.
//   3. Every block polls its relay replica with ONE lane -> 16 pollers/line.
// Slot overwrite g->g+1 is race-free: relay g is written only after the
// leader observed ALL slots at g; a block writes g+1 only after consuming
// relay g. Packing: [gen:9][sortable-val:32][0x7FFFFF-idx:23] (R12-verified).
struct KSmem {
    float  rp[RPN];           // 34816 B ([8448..8704) zero pad, never written)
    float4 dn4[4][64];        // own 4 atoms' taps, 4096 B
    float  chv[4][34];        // per-atom chunk maxima (global chunk ids)
    int    chi[4][34];
    float  wv[16]; int wi[16];
    float  fv; int fi;
    u64    red[2];            // leader 2-wave reduce scratch
};

// Split-counter per-batch barrier -- used ONCE (dn publication fence).
__device__ __forceinline__ void gbar_sub(unsigned* sub, int r, unsigned gen16, int tid) {
    __syncthreads();
    if (tid == 0)
        __hip_atomic_fetch_add(&sub[(r >> 4)*SUBSTRIDE], 1u,
                               __ATOMIC_RELEASE, __HIP_MEMORY_SCOPE_AGENT);
    if (tid < 64) {
        for (;;) {
            unsigned ok = 1;
            if (tid < NGRP)
                ok = (__hip_atomic_load(&sub[tid*SUBSTRIDE], __ATOMIC_RELAXED,
                                        __HIP_MEMORY_SCOPE_AGENT) >= gen16);
            if (__all((int)ok)) break;
            __builtin_amdgcn_s_sleep(4);
        }
    }
    __syncthreads();
    __builtin_amdgcn_fence(__ATOMIC_ACQUIRE, "agent");
}

// Compute conv outputs for up to two 512-chunks (cA -> threads 0..127,
// cB -> threads 128..255; -1 = inactive) for the block's 4 atoms, from LDS rp.
// REPLACES chv/chi entries for the valid chunks. Chunk ids are GLOBAL (0..32).
__device__ void chunks_update(KSmem& sm, int baseF, int cA, int cB, int aBase, int tid) {
    const int lane = tid & 63, w = tid >> 6;
    const int grp = tid >> 7;
    const int cg = grp ? cB : cA;
    const int lt = cg*512 + (tid & 127)*4;    // global output t (j=0); cg>=0 only
    float c0[4] = {0,0,0,0}, c1[4] = {0,0,0,0}, c2[4] = {0,0,0,0}, c3[4] = {0,0,0,0};
    if (cg >= 0) {
        const float4* srp4 = (const float4*)sm.rp;
        int ol4 = (lt - baseF) >> 2;
        float4 p = srp4[ol4];
        #pragma unroll 4
        for (int kq = 0; kq < 64; kq++) {
            float4 d0 = sm.dn4[0][kq];
            float4 d1 = sm.dn4[1][kq];
            float4 d2 = sm.dn4[2][kq];
            float4 d3 = sm.dn4[3][kq];
            float4 pn = srp4[ol4 + kq + 1];
            TAP(c0[0], p.x,p.y,p.z,p.w, d0); TAP(c0[1], p.y,p.z,p.w,pn.x, d0);
            TAP(c0[2], p.z,p.w,pn.x,pn.y, d0); TAP(c0[3], p.w,pn.x,pn.y,pn.z, d0);
            TAP(c1[0], p.x,p.y,p.z,p.w, d1); TAP(c1[1], p.y,p.z,p.w,pn.x, d1);
            TAP(c1[2], p.z,p.w,pn.x,pn.y, d1); TAP(c1[3], p.w,pn.x,pn.y,pn.z, d1);
            TAP(c2[0], p.x,p.y,p.z,p.w, d2); TAP(c2[1], p.y,p.z,p.w,pn.x, d2);
            TAP(c2[2], p.z,p.w,pn.x,pn.y, d2); TAP(c2[3], p.w,pn.x,pn.y,pn.z, d2);
            TAP(c3[0], p.x,p.y,p.z,p.w, d3); TAP(c3[1], p.y,p.z,p.w,pn.x, d3);
            TAP(c3[2], p.z,p.w,pn.x,pn.y, d3); TAP(c3[3], p.w,pn.x,pn.y,pn.z, d3);
            p = pn;
        }
    }
    float bv0 = -INFINITY, bv1 = -INFINITY, bv2 = -INFINITY, bv3 = -INFINITY;
    int bi0 = 0x7fffffff, bi1 = 0x7fffffff, bi2 = 0x7fffffff, bi3 = 0x7fffffff;
    if (cg >= 0) {
        #pragma unroll
        for (int j = 0; j < 4; j++) {
            int t = lt + j;
            if (t < TOUT) {
                if (c0[j] > bv0) { bv0 = c0[j]; bi0 = (aBase+0)*TOUT + t; }
                if (c1[j] > bv1) { bv1 = c1[j]; bi1 = (aBase+1)*TOUT + t; }
                if (c2[j] > bv2) { bv2 = c2[j]; bi2 = (aBase+2)*TOUT + t; }
                if (c3[j] > bv3) { bv3 = c3[j]; bi3 = (aBase+3)*TOUT + t; }
            }
        }
    }
    wave_amax(bv0, bi0); wave_amax(bv1, bi1); wave_amax(bv2, bi2); wave_amax(bv3, bi3);
    if (lane == 0) {
        sm.wv[0*4+w] = bv0; sm.wi[0*4+w] = bi0;
        sm.wv[1*4+w] = bv1; sm.wi[1*4+w] = bi1;
        sm.wv[2*4+w] = bv2; sm.wi[2*4+w] = bi2;
        sm.wv[3*4+w] = bv3; sm.wi[3*4+w] = bi3;
    }
    __syncthreads();
    // combine wave pairs: waves {0,1} -> cA, {2,3} -> cB
    if (tid < 8) {
        int a = tid >> 1, hh = tid & 1;
        int chunk = hh ? cB : cA;
        if (chunk >= 0) {
            float v0 = sm.wv[a*4 + 2*hh];   int i0 = sm.wi[a*4 + 2*hh];
            float v1 = sm.wv[a*4 + 2*hh+1]; int i1 = sm.wi[a*4 + 2*hh+1];
            if (v1 > v0 || (v1 == v0 && i1 < i0)) { v0 = v1; i0 = i1; }
            sm.chv[a][chunk] = v0; sm.chi[a][chunk] = i0;
        }
    }
    __syncthreads();
}

// Block best over 4 atoms x own chunk range -> ONE gen-tagged u64 store.
__device__ __forceinline__ void publish(KSmem& sm, u64* slot, int gen, int h, int tid) {
    const int lane = tid & 63, w = tid >> 6;  // wave w -> atom w
    int cstart = h ? 16 : 0, nch = h ? 17 : 16;
    float bv = -INFINITY; int bi = 0x7fffffff;
    if (lane < nch) { bv = sm.chv[w][cstart + lane]; bi = sm.chi[w][cstart + lane]; }
    wave_amax(bv, bi);
    if (lane == 0) { sm.wv[8+w] = bv; sm.wi[8+w] = bi; }
    __syncthreads();
    if (tid == 0) {
        float v = sm.wv[8]; int i = sm.wi[8];
        #pragma unroll
        for (int j = 1; j < 4; j++)
            if (sm.wv[8+j] > v || (sm.wv[8+j] == v && sm.wi[8+j] < i)) { v = sm.wv[8+j]; i = sm.wi[8+j]; }
        unsigned s = __float_as_uint(v);
        unsigned key = (s & 0x80000000u) ? ~s : (s | 0x80000000u);   // sortable float
        u64 e = ((u64)(unsigned)gen << 55) | ((u64)key << 23)
              | (u64)(unsigned)(0x7FFFFF - i);                        // tie -> min idx
        __hip_atomic_store(slot, e, __ATOMIC_RELAXED, __HIP_MEMORY_SCOPE_AGENT);
    }
}

// Leader: lanes 0..127 poll the 128 slots (sole pollers on those lines),
// u64-max reduce (tags equal -> plain order), write winner to 8 relay lines,
// unpack winner locally.
__device__ __forceinline__ void lead_reduce(KSmem& sm, u64* slotsb, u64* relayb,
                                            int gen, int tid) {
    const int lane = tid & 63, w = tid >> 6;
    if (tid < BPB2) {
        const u64* p = slotsb + tid;
        u64 e;
        for (;;) {
            e = __hip_atomic_load(p, __ATOMIC_RELAXED, __HIP_MEMORY_SCOPE_AGENT);
            if ((unsigned)(e >> 55) == (unsigned)gen) break;
            __builtin_amdgcn_s_sleep(1);
        }
        #pragma unroll
        for (int off = 32; off; off >>= 1) {
            u64 o = __shfl_down(e, off);
            if (o > e) e = o;
        }
        if (lane == 0) sm.red[w] = e;
    }
    __syncthreads();
    if (tid == 0) {
        u64 m = (sm.red[0] > sm.red[1]) ? sm.red[0] : sm.red[1];
        #pragma unroll
        for (int j = 0; j < NGRP; j++)
            __hip_atomic_store(&relayb[j*RSTRIDE], m, __ATOMIC_RELAXED,
                               __HIP_MEMORY_SCOPE_AGENT);
        unsigned key = (unsigned)((m >> 23) & 0xFFFFFFFFull);
        unsigned s = (key & 0x80000000u) ? (key ^ 0x80000000u) : ~key;
        sm.fv = __uint_as_float(s);
        sm.fi = 0x7FFFFF - (int)(m & 0x7FFFFF);
    }
    __syncthreads();
}

// Non-leader: ONE lane polls this block's relay replica (16 pollers/line).
__device__ __forceinline__ void pick_relay(KSmem& sm, const u64* rl, int gen, int tid) {
    if (tid == 0) {
        u64 e;
        for (;;) {
            e = __hip_atomic_load(rl, __ATOMIC_RELAXED, __HIP_MEMORY_SCOPE_AGENT);
            if ((unsigned)(e >> 55) == (unsigned)gen) break;
            __builtin_amdgcn_s_sleep(2);
        }
        unsigned key = (unsigned)((e >> 23) & 0xFFFFFFFFull);
        unsigned s = (key & 0x80000000u) ? (key ^ 0x80000000u) : ~key;
        sm.fv = __uint_as_float(s);
        sm.fi = 0x7FFFFF - (int)(e & 0x7FFFFF);
    }
    __syncthreads();
}

__global__ void __launch_bounds__(256, 2)
k_coop(const float* __restrict__ x, const float* __restrict__ d, float* __restrict__ out,
       float* __restrict__ dn, u64* __restrict__ slots, u64* __restrict__ relay,
       unsigned* __restrict__ fbar) {
    extern __shared__ char raw[];
    KSmem& sm = *(KSmem*)raw;
    const int bid = blockIdx.x, tid = threadIdx.x;
    const int b = bid >> 7, r = bid & 127;
    const int h = r >> 6, a0 = r & 63;       // half, atom-group (4 atoms)
    const int lane = tid & 63, w = tid >> 6;
    const int baseF = h * HBASE;
    const int cstart = h ? 16 : 0, cend = h ? 33 : 16;
    const bool islead = (r == 0);
    u64* slotsb = slots + (size_t)b*BPB2;    // 128 contiguous slots (8 lines)
    u64* relayb = relay + (size_t)b*NGRP*RSTRIDE;
    unsigned* fbarb = fbar + b*BARSTRIDE;

    // ---- init: x -> LDS rp window (padded domain), zero tail ----
    {
        const float4* x4 = (const float4*)(x + (size_t)b*T);
        float4* rp4w = (float4*)sm.rp;
        int b4 = baseF >> 2;
        for (int i = tid; i < RPN/4; i += 256) {
            int g4 = b4 + i;
            float4 v = {0.f,0.f,0.f,0.f};
            if (i < RPSTORE/4 && g4 >= PAD/4 && g4 < (PAD+T)/4) v = x4[g4 - PAD/4];
            rp4w[i] = v;
        }
    }
    // ---- normalize own 4 atoms into LDS + global dn (redundant identical writes;
    //      published by the one full-fence barrier below) ----
    #pragma unroll
    for (int s = 0; s < 4; s++) {
        int atom = a0*4 + s;
        float v = d[atom*K + tid];
        float sq = v*v;
        #pragma unroll
        for (int off = 32; off; off >>= 1) sq += __shfl_down(sq, off);
        if (lane == 0) sm.wv[w] = sq;
        __syncthreads();
        float norm = sqrtf(sm.wv[0] + sm.wv[1] + sm.wv[2] + sm.wv[3]) + 1e-12f;
        float nv = v / norm;
        ((float*)&sm.dn4[s][0])[tid] = nv;
        dn[atom*K + tid] = nv;
        __syncthreads();
    }
    // ---- initial conv over own half (8 or 9 chunk-pair passes) ----
    {
        int npass = h ? 9 : 8;
        for (int p = 0; p < npass; p++) {
            int ca = cstart + 2*p;
            int cb2 = (ca + 1 < cend) ? ca + 1 : -1;
            chunks_update(sm, baseF, ca, cb2, a0*4, tid);
        }
    }
    int gen = 1;
    publish(sm, slotsb + r, gen, h, tid);
    gbar_sub(fbarb, r, 16u, tid);            // the ONLY full-fence barrier (dn)

    for (int it = 0; it < ITERS-1; it++) {
        if (islead) lead_reduce(sm, slotsb, relayb, gen, tid);
        else        pick_relay(sm, relayb + (r >> 4)*RSTRIDE, gen, tid);
        float val = sm.fv; int idx = sm.fi;
        int atom = idx / TOUT, pos = idx - atom*TOUT;
        float ds = dn[atom*K + tid];            // plain load, L2-hot (dn immutable)
        int li = pos + tid - baseF;             // local residual update (if in range)
        if (li >= 0 && li < RPSTORE) sm.rp[li] -= val * ds;
        __syncthreads();
        int lo = pos - (K-1); if (lo < 0) lo = 0;
        int g0 = lo >> 9, g1 = g0 + 1;          // the 2 affected global chunks
        bool in0 = (g0 >= cstart && g0 < cend);
        bool in1 = (g1 >= cstart && g1 < cend);
        int ca = in0 ? g0 : (in1 ? g1 : -1);
        int cb2 = (in0 && in1) ? g1 : -1;
        if (ca >= 0) chunks_update(sm, baseF, ca, cb2, a0*4, tid);
        publish(sm, slotsb + r, gen+1, h, tid);
        gen++;
        // no separate barrier: slot/relay gen tags ARE the synchronization
    }
    // ---- final pick + update + out (one writer block per (batch, half)) ----
    if (a0 == 0) {
        if (islead) lead_reduce(sm, slotsb, relayb, gen, tid);
        else        pick_relay(sm, relayb + (r >> 4)*RSTRIDE, gen, tid);
        float val = sm.fv; int idx = sm.fi;
        int atom = idx / TOUT, pos = idx - atom*TOUT;
        float ds = dn[atom*K + tid];
        int li = pos + tid - baseF;
        if (li >= 0 && li < RPSTORE) sm.rp[li] -= val * ds;
        __syncthreads();
        // out[b][o] = x[b][o] - rp[o+PAD]; h=0 covers o in [0,8064), h=1 [8064,16384)
        int o_lo4 = h ? (HBASE - PAD)/4 : 0;
        int o_hi4 = h ? T/4 : (HBASE - PAD)/4;
        const float4* xb4 = (const float4*)(x + (size_t)b*T);
        float4* o4 = (float4*)(out + (size_t)b*T);
        for (int i4 = o_lo4 + tid; i4 < o_hi4; i4 += 256) {
            float4 xv = xb4[i4];
            float4 rv = *(const float4*)&sm.rp[i4*4 + PAD - baseF];
            float4 ov; ov.x = xv.x - rv.x; ov.y = xv.y - rv.y;
            ov.z = xv.z - rv.z; ov.w = xv.w - rv.w;
            o4[i4] = ov;
        }
    }
}

// ===================== fallback path (R6, race-free, unchanged) =====================
struct Smem {
    float rp[TILE + K + 16];
    float dnA[K];
    float dnB[K];
    float dnsel[K];
    float wv[16]; int wi[16];
    float fv; int fi;
};

__device__ __forceinline__ void dev_norm(int a0, int tid, const float* __restrict__ d,
                                         float* __restrict__ dn, Smem& sm) {
    int lane = tid & 63, w = tid >> 6;
    #pragma unroll
    for (int s = 0; s < 2; s++) {
        int atom = a0*2 + s;
        float v = d[atom*K + tid];
        float sq = v*v;
        #pragma unroll
        for (int off = 32; off; off >>= 1) sq += __shfl_down(sq, off);
        if (lane == 0) sm.wv[w] = sq;
        __syncthreads();
        float norm = sqrtf(sm.wv[0] + sm.wv[1] + sm.wv[2] + sm.wv[3]) + 1e-12f;
        dn[atom*K + tid] = v / norm;
        __syncthreads();
    }
}

__device__ __forceinline__ void dev_init(int a0, int b, int tid, const float* __restrict__ x,
                                         float* __restrict__ rp, float* __restrict__ recon) {
    int i = a0*256 + tid;
    if (i < TP) {
        float v = (i >= PAD && i < PAD + T) ? x[b*T + (i - PAD)] : 0.f;
        rp[(size_t)b*TP + i] = v;
        recon[(size_t)b*TP + i] = 0.f;
    }
}

__device__ void dev_conv(int a0, int b, int tid, const float* __restrict__ rp,
                         const float* __restrict__ dn,
                         float* __restrict__ segval, int* __restrict__ segidx,
                         float* __restrict__ abv, int* __restrict__ abi, Smem& sm) {
    const int aA = a0*2, aB = a0*2 + 1;
    const int lane = tid & 63, w = tid >> 6;
    sm.dnA[tid] = dn[aA*K + tid];
    sm.dnB[tid] = dn[aB*K + tid];
    const float4* rp4 = (const float4*)(rp + (size_t)b*TP);

    for (int tile = 0; tile < NTILE; tile++) {
        int t0 = tile * TILE;
        __syncthreads();
        float4* s4 = (float4*)sm.rp;
        for (int i = tid; i < 580; i += 256) {
            int g = t0/4 + i;
            float4 v = {0.f,0.f,0.f,0.f};
            if (g*4 < TP) v = rp4[g];
            s4[i] = v;
        }
        __syncthreads();
        const float4* srp4 = (const float4*)sm.rp;
        const float4* dA4  = (const float4*)sm.dnA;
        const float4* dB4  = (const float4*)sm.dnB;
        float accA0[4] = {0,0,0,0}, accA1[4] = {0,0,0,0};
        float accB0[4] = {0,0,0,0}, accB1[4] = {0,0,0,0};
        float4 p = srp4[tid];
        float4 q = srp4[tid + 256];
        #pragma unroll 4
        for (int kq = 0; kq < 64; kq++) {
            float4 dA = dA4[kq];
            float4 dB = dB4[kq];
            float4 pn = srp4[tid + kq + 1];
            float4 qn = srp4[tid + 256 + kq + 1];
            TAP(accA0[0], p.x,p.y,p.z,p.w, dA); TAP(accA0[1], p.y,p.z,p.w,pn.x, dA);
            TAP(accA0[2], p.z,p.w,pn.x,pn.y, dA); TAP(accA0[3], p.w,pn.x,pn.y,pn.z, dA);
            TAP(accB0[0], p.x,p.y,p.z,p.w, dB); TAP(accB0[1], p.y,p.z,p.w,pn.x, dB);
            TAP(accB0[2], p.z,p.w,pn.x,pn.y, dB); TAP(accB0[3], p.w,pn.x,pn.y,pn.z, dB);
            TAP(accA1[0], q.x,q.y,q.z,q.w, dA); TAP(accA1[1], q.y,q.z,q.w,qn.x, dA);
            TAP(accA1[2], q.z,q.w,qn.x,qn.y, dA); TAP(accA1[3], q.w,qn.x,qn.y,qn.z, dA);
            TAP(accB1[0], q.x,q.y,q.z,q.w, dB); TAP(accB1[1], q.y,q.z,q.w,qn.x, dB);
            TAP(accB1[2], q.z,q.w,qn.x,qn.y, dB); TAP(accB1[3], q.w,qn.x,qn.y,qn.z, dB);
            p = pn; q = qn;
        }
        int lt = tid * 4;
        float bvA0 = -INFINITY, bvA1 = -INFINITY, bvB0 = -INFINITY, bvB1 = -INFINITY;
        int biA0 = 0x7fffffff, biA1 = 0x7fffffff, biB0 = 0x7fffffff, biB1 = 0x7fffffff;
        #pragma unroll
        for (int j = 0; j < 4; j++) {
            int t = t0 + lt + j;
            if (t < TOUT) {
                if (accA0[j] > bvA0) { bvA0 = accA0[j]; biA0 = aA*TOUT + t; }
                if (accB0[j] > bvB0) { bvB0 = accB0[j]; biB0 = aB*TOUT + t; }
            }
            int t1 = t0 + 1024 + lt + j;
            if (t1 < TOUT) {
                if (accA1[j] > bvA1) { bvA1 = accA1[j]; biA1 = aA*TOUT + t1; }
                if (accB1[j] > bvB1) { bvB1 = accB1[j]; biB1 = aB*TOUT + t1; }
            }
        }
        wave_amax(bvA0, biA0); wave_amax(bvA1, biA1);
        wave_amax(bvB0, biB0); wave_amax(bvB1, biB1);
        if (lane == 0) {
            sm.wv[w]    = bvA0; sm.wi[w]    = biA0;
            sm.wv[4+w]  = bvA1; sm.wi[4+w]  = biA1;
            sm.wv[8+w]  = bvB0; sm.wi[8+w]  = biB0;
            sm.wv[12+w] = bvB1; sm.wi[12+w] = biB1;
        }
        __syncthreads();
        if (tid < 4) {
            float v0 = sm.wv[2*tid];   int i0 = sm.wi[2*tid];
            float v1 = sm.wv[2*tid+1]; int i1 = sm.wi[2*tid+1];
            if (v1 > v0 || (v1 == v0 && i1 < i0)) { v0 = v1; i0 = i1; }
            int chunk = tile*4 + tid;
            if (chunk < NCHUNK) {
                segval[((size_t)b*A + aA)*NCP + chunk] = v0;
                segidx[((size_t)b*A + aA)*NCP + chunk] = i0;
            }
        } else if (tid >= 64 && tid < 68) {
            int c = tid - 64;
            float v0 = sm.wv[8+2*c];   int i0 = sm.wi[8+2*c];
            float v1 = sm.wv[8+2*c+1]; int i1 = sm.wi[8+2*c+1];
            if (v1 > v0 || (v1 == v0 && i1 < i0)) { v0 = v1; i0 = i1; }
            int chunk = tile*4 + c;
            if (chunk < NCHUNK) {
                segval[((size_t)b*A + aB)*NCP + chunk] = v0;
                segidx[((size_t)b*A + aB)*NCP + chunk] = i0;
            }
        }
    }
    __syncthreads();
    if (w < 2) {
        int atom = (w == 0) ? aA : aB;
        float bv = -INFINITY; int bi = 0x7fffffff;
        if (lane < NCHUNK) {
            bv = segval[((size_t)b*A + atom)*NCP + lane];
            bi = segidx[((size_t)b*A + atom)*NCP + lane];
        }
        wave_amax(bv, bi);
        if (lane == 0) { abv[b*A + atom] = bv; abi[b*A + atom] = bi; }
    }
}

__device__ void dev_iter(int a0, int b, int tid, int last,
                         const float* __restrict__ avc, const int* __restrict__ aic,
                         float* __restrict__ avn, int* __restrict__ ain,
                         const float* __restrict__ rin, float* __restrict__ rout,
                         float* __restrict__ recon, const float* __restrict__ dn,
                         float* __restrict__ segval, int* __restrict__ segidx, Smem& sm) {
    const int aA = a0*2, aB = a0*2 + 1;
    const int lane = tid & 63, w = tid >> 6;

    float bv0 = avc[b*A + tid]; int bi0 = aic[b*A + tid];
    const float4* rin4 = (const float4*)(rin + (size_t)b*TP);
    const int icopy = a0*256 + tid;
    const bool docopy = (!last) && (icopy < TP/4);
    float4 vcopy = {0.f,0.f,0.f,0.f};
    if (docopy) vcopy = rin4[icopy];
    sm.dnA[tid] = dn[aA*K + tid];
    sm.dnB[tid] = dn[aB*K + tid];

    {
        float bv = bv0; int bi = bi0;
        wave_amax(bv, bi);
        if (lane == 0) { sm.wv[w] = bv; sm.wi[w] = bi; }
        __syncthreads();
        if (tid == 0) {
            bv = sm.wv[0]; bi = sm.wi[0];
            for (int j = 1; j < 4; j++)
                if (sm.wv[j] > bv || (sm.wv[j] == bv && sm.wi[j] < bi)) { bv = sm.wv[j]; bi = sm.wi[j]; }
            sm.fv = bv; sm.fi = bi;
        }
        __syncthreads();
    }
    float val = sm.fv; int idx = sm.fi;
    int atom = idx / TOUT, pos = idx - atom*TOUT;
    sm.dnsel[tid] = dn[atom*K + tid];

    int lo = pos - (K-1); if (lo < 0) lo = 0;
    int c_lo = lo >> 9;
    int tbase = c_lo * CHUNK;

    if (!last) {
        float4* s4 = (float4*)sm.rp;
        for (int i = tid; i < 324; i += 256) {
            int g = tbase/4 + i;
            float4 v = {0.f,0.f,0.f,0.f};
            if (g*4 < TP) v = rin4[g];
            s4[i] = v;
        }
    }
    __syncthreads();
    if (docopy) {
        float4* rout4 = (float4*)(rout + (size_t)b*TP);
        float4 v = vcopy;
        int o = icopy*4 - pos;
        if (o > -4 && o < K) {
            if (o+0 >= 0 && o+0 < K) v.x -= val * sm.dnsel[o+0];
            if (o+1 >= 0 && o+1 < K) v.y -= val * sm.dnsel[o+1];
            if (o+2 >= 0 && o+2 < K) v.z -= val * sm.dnsel[o+2];
            if (o+3 >= 0 && o+3 < K) v.w -= val * sm.dnsel[o+3];
        }
        rout4[icopy] = v;
    }
    if (a0 == 0) {
        recon[(size_t)b*TP + pos + tid] += val * sm.dnsel[tid];
    }
    if (last) return;

    sm.rp[pos + tid - tbase] -= val * sm.dnsel[tid];
    __syncthreads();

    const float4* srp4 = (const float4*)sm.rp;
    const float4* dA4  = (const float4*)sm.dnA;
    const float4* dB4  = (const float4*)sm.dnB;
    float cA[4] = {0,0,0,0}, cB[4] = {0,0,0,0};
    float4 p = srp4[tid];
    #pragma unroll 4
    for (int kq = 0; kq < 64; kq++) {
        float4 dA = dA4[kq];
        float4 dB = dB4[kq];
        float4 pn = srp4[tid + kq + 1];
        TAP(cA[0], p.x,p.y,p.z,p.w, dA); TAP(cA[1], p.y,p.z,p.w,pn.x, dA);
        TAP(cA[2], p.z,p.w,pn.x,pn.y, dA); TAP(cA[3], p.w,pn.x,pn.y,pn.z, dA);
        TAP(cB[0], p.x,p.y,p.z,p.w, dB); TAP(cB[1], p.y,p.z,p.w,pn.x, dB);
        TAP(cB[2], p.z,p.w,pn.x,pn.y, dB); TAP(cB[3], p.w,pn.x,pn.y,pn.z, dB);
        p = pn;
    }
    int lt = tid * 4;
    float bvA = -INFINITY, bvB = -INFINITY;
    int biA = 0x7fffffff, biB = 0x7fffffff;
    #pragma unroll
    for (int j = 0; j < 4; j++) {
        int t = tbase + lt + j;
        if (t < TOUT) {
            if (cA[j] > bvA) { bvA = cA[j]; biA = aA*TOUT + t; }
            if (cB[j] > bvB) { bvB = cB[j]; biB = aB*TOUT + t; }
        }
    }
    wave_amax(bvA, biA); wave_amax(bvB, biB);
    if (lane == 0) { sm.wv[w] = bvA; sm.wi[w] = biA; sm.wv[8+w] = bvB; sm.wi[8+w] = biB; }
    __syncthreads();
    if (tid < 2) {
        float v0 = sm.wv[2*tid];   int i0 = sm.wi[2*tid];
        float v1 = sm.wv[2*tid+1]; int i1 = sm.wi[2*tid+1];
        if (v1 > v0 || (v1 == v0 && i1 < i0)) { v0 = v1; i0 = i1; }
        int chunk = c_lo + tid;
        if (chunk < NCHUNK) {
            segval[((size_t)b*A + aA)*NCP + chunk] = v0;
            segidx[((size_t)b*A + aA)*NCP + chunk] = i0;
        }
    } else if (tid >= 64 && tid < 66) {
        int c = tid - 64;
        float v0 = sm.wv[8+2*c];   int i0 = sm.wi[8+2*c];
        float v1 = sm.wv[8+2*c+1]; int i1 = sm.wi[8+2*c+1];
        if (v1 > v0 || (v1 == v0 && i1 < i0)) { v0 = v1; i0 = i1; }
        int chunk = c_lo + c;
        if (chunk < NCHUNK) {
            segval[((size_t)b*A + aB)*NCP + chunk] = v0;
            segidx[((size_t)b*A + aB)*NCP + chunk] = i0;
        }
    }
    __syncthreads();
    if (w < 2) {
        int at = (w == 0) ? aA : aB;
        float bv = -INFINITY; int bi = 0x7fffffff;
        if (lane < NCHUNK) {
            bv = segval[((size_t)b*A + at)*NCP + lane];
            bi = segidx[((size_t)b*A + at)*NCP + lane];
        }
        wave_amax(bv, bi);
        if (lane == 0) { avn[b*A + at] = bv; ain[b*A + at] = bi; }
    }
}

__global__ void __launch_bounds__(256) k_f_norm_init(const float* x, const float* d,
                                                     float* dn, float* rp0, float* recon) {
    __shared__ Smem sm;
    dev_norm(blockIdx.x & 127, threadIdx.x, d, dn, sm);
    dev_init(blockIdx.x & 127, blockIdx.x >> 7, threadIdx.x, x, rp0, recon);
}
__global__ void __launch_bounds__(256, 2) k_f_conv(const float* rp, const float* dn,
                                                   float* segval, int* segidx,
                                                   float* abv, int* abi) {
    __shared__ Smem sm;
    dev_conv(blockIdx.x & 127, blockIdx.x >> 7, threadIdx.x, rp, dn, segval, segidx, abv, abi, sm);
}
__global__ void __launch_bounds__(256, 2) k_f_iter(int last,
                                                   const float* avc, const int* aic,
                                                   float* avn, int* ain,
                                                   const float* rin, float* rout,
                                                   float* recon, const float* dn,
                                                   float* segval, int* segidx) {
    __shared__ Smem sm;
    dev_iter(blockIdx.x & 127, blockIdx.x >> 7, threadIdx.x, last,
             avc, aic, avn, ain, rin, rout, recon, dn, segval, segidx, sm);
}
__global__ void k_f_out(const float* recon, float* out) {
    int i = blockIdx.x * blockDim.x + threadIdx.x;
    if (i >= B*T) return;
    int b = i / T, t = i - b*T;
    out[i] = recon[(size_t)b*TP + PAD + t];
}

extern "C" void kernel_launch(void* const* d_in, const int* in_sizes, int n_in,
                              void* d_out, int out_size, void* d_ws, size_t ws_size,
                              hipStream_t stream) {
    const float* x = (const float*)d_in[0];
    const float* d = (const float*)d_in[1];
    float* out = (float*)d_out;

    float* ws     = (float*)d_ws;
    float* dn     = ws;                                   // A*K
    float* rp0    = dn  + (size_t)A*K;                    // B*TP (fallback)
    float* rp1    = rp0 + (size_t)B*TP;                   // B*TP (fallback)
    float* recon  = rp1 + (size_t)B*TP;                   // B*TP (fallback)
    float* segval = recon + (size_t)B*TP;                 // B*A*NCP (fallback)
    int*   segidx = (int*)(segval + (size_t)B*A*NCP);     // B*A*NCP (fallback)
    float* abv0   = (float*)(segidx + (size_t)B*A*NCP);   // B*2*A (fallback exchange)
    float* abv1   = abv0 + (size_t)B*2*A;
    int*   abi0   = (int*)(abv1 + (size_t)B*2*A);
    int*   abi1   = abi0 + (size_t)B*2*A;
    unsigned* fbar= (unsigned*)(abi1 + (size_t)B*2*A);    // B x NGRP fence counters
    u64*  slots   = (u64*)(fbar + (size_t)B*BARSTRIDE);   // B x BPB2 slots
    u64*  relay   = slots + (size_t)B*BPB2;               // B x NGRP relay replicas

    // Coop-path feasibility: 512 co-resident blocks at DLDS dynamic LDS
    // (2 blocks/CU). Host queries only.
    (void)hipFuncSetAttribute((const void*)k_coop,
                              hipFuncAttributeMaxDynamicSharedMemorySize, DLDS);
    int nb = 0, ncu = 0;
    hipError_t e1 = hipOccupancyMaxActiveBlocksPerMultiprocessor(&nb, (const void*)k_coop,
                                                                 256, DLDS);
    hipError_t e2 = hipDeviceGetAttribute(&ncu, hipDeviceAttributeMultiprocessorCount, 0);
    bool coop = (e1 == hipSuccess && e2 == hipSuccess && nb > 0 && ncu > 0 &&
                 (long)nb * ncu >= NBLK);
    if (coop) {
        // fbar + slots + relay contiguous: one memset (counters 0, tags 0)
        size_t zbytes = (size_t)B*BARSTRIDE*4 + (size_t)B*BPB2*8
                      + (size_t)B*NGRP*RSTRIDE*8;
        (void)hipMemsetAsync(fbar, 0, zbytes, stream);
        hipLaunchKernelGGL(k_coop, dim3(NBLK), dim3(256), DLDS, stream,
                           x, d, out, dn, slots, relay, fbar);
        return;
    }
    // fallback: separate launches, double-buffered (race-free)
    k_f_norm_init<<<NBLK, 256, 0, stream>>>(x, d, dn, rp0, recon);
    k_f_conv<<<NBLK, 256, 0, stream>>>(rp0, dn, segval, segidx, abv0, abi0);
    float* rbuf[2] = {rp0, rp1};
    float* av[2]   = {abv0, abv1};
    int*   ai[2]   = {abi0, abi1};
    for (int it = 0; it < ITERS; it++) {
        k_f_iter<<<NBLK, 256, 0, stream>>>(it == ITERS-1 ? 1 : 0,
                                           av[it & 1], ai[it & 1],
                                           av[(it + 1) & 1], ai[(it + 1) & 1],
                                           rbuf[it & 1], rbuf[(it + 1) & 1],
                                           recon, dn, segval, segidx);
    }
    k_f_out<<<(B*T + 255)/256, 256, 0, stream>>>(recon, out);
}